// Round 4
// baseline (1253.150 us; speedup 1.0000x reference)
//
#include <hip/hip_runtime.h>
#include <stdint.h>

#define NN 100000      // nodes
#define NE 1600000     // edges
#define INC 128        // in channels
#define HID 256        // hidden
#define MP  100096     // padded rows (128*782)
#define MBLK8 782      // row blocks of 128
#define NBK 391        // dst buckets (dst>>8), 99999>>8 = 390
#define EPB 2048       // edges per bucket-fill block

typedef unsigned short u16;
typedef __attribute__((ext_vector_type(4))) float f32x4;
typedef __attribute__((ext_vector_type(8))) short s16x8;

static __device__ __forceinline__ float bf2f(u16 u){
  union { uint32_t i; float f; } v; v.i = ((uint32_t)u) << 16; return v.f;
}
static __device__ __forceinline__ u16 f2bf(float f){
  union { float f; uint32_t i; } v; v.f = f;
  uint32_t r = v.i + 0x7FFFu + ((v.i >> 16) & 1u);
  return (u16)(r >> 16);
}
static __device__ __forceinline__ void up8(uint4 o, float* v){
  v[0]=bf2f((u16)(o.x&0xffffu)); v[1]=bf2f((u16)(o.x>>16));
  v[2]=bf2f((u16)(o.y&0xffffu)); v[3]=bf2f((u16)(o.y>>16));
  v[4]=bf2f((u16)(o.z&0xffffu)); v[5]=bf2f((u16)(o.z>>16));
  v[6]=bf2f((u16)(o.w&0xffffu)); v[7]=bf2f((u16)(o.w>>16));
}
static __device__ __forceinline__ uint4 pk8(const float* v){
  uint4 o;
  o.x = (uint32_t)f2bf(v[0]) | ((uint32_t)f2bf(v[1])<<16);
  o.y = (uint32_t)f2bf(v[2]) | ((uint32_t)f2bf(v[3])<<16);
  o.z = (uint32_t)f2bf(v[4]) | ((uint32_t)f2bf(v[5])<<16);
  o.w = (uint32_t)f2bf(v[6]) | ((uint32_t)f2bf(v[7])<<16);
  return o;
}

// ---------------- misc small kernels ----------------

__global__ __launch_bounds__(256) void zero_k(int* deg, float* bnacc, int* bcnt){
  int i = blockIdx.x*256 + threadIdx.x;
  if (i < NN) deg[i] = 0;
  if (i < 3*8192) bnacc[i] = 0.f;
  if (i < NBK) bcnt[i] = 0;
}

__global__ __launch_bounds__(256) void cvt_k(const float* __restrict__ src, u16* __restrict__ dst, int n4){
  int i = blockIdx.x*256 + threadIdx.x;
  if (i >= n4) return;
  float4 v = ((const float4*)src)[i];
  uint2 o;
  o.x = (uint32_t)f2bf(v.x) | ((uint32_t)f2bf(v.y)<<16);
  o.y = (uint32_t)f2bf(v.z) | ((uint32_t)f2bf(v.w)<<16);
  ((uint2*)dst)[i] = o;
}

// pack W[K][NC] (f32 row-major) into MFMA B-fragment order:
// frag (ks, nt): lane l, elem j  <-  W[ks*32 + (l>>4)*8 + j][nt*16 + (l&15)]
__global__ __launch_bounds__(256) void pack_k(const float* __restrict__ src, u16* __restrict__ dst,
                                              int K, int NC, int ksoff){
  int t = blockIdx.x*256 + threadIdx.x;
  if (t >= K*NC) return;
  int k = t / NC, n = t % NC;
  int NT = NC >> 4;
  int ks = ksoff + (k >> 5);
  int l  = ((k >> 3) & 3)*16 + (n & 15);
  int j  = k & 7;
  dst[((size_t)(ks*NT + (n>>4))*64 + l)*8 + j] = f2bf(src[(size_t)k*NC + n]);
}

// ---------------- CSR build (bucketed) ----------------

__global__ __launch_bounds__(256) void deg_k(const int* __restrict__ ei, int* __restrict__ deg){
  int e = blockIdx.x*256 + threadIdx.x;
  if (e >= NE) return;
  atomicAdd(&deg[ei[NE + e]], 1);
}

__global__ __launch_bounds__(256) void bhist_k(const int* __restrict__ ei, int* __restrict__ bcnt){
  __shared__ int h[NBK];
  for (int i = threadIdx.x; i < NBK; i += 256) h[i] = 0;
  __syncthreads();
  int e0 = blockIdx.x * EPB;
  #pragma unroll
  for (int j = 0; j < EPB/256; ++j){
    int e = e0 + j*256 + threadIdx.x;
    if (e < NE) atomicAdd(&h[ei[NE + e] >> 8], 1);
  }
  __syncthreads();
  for (int i = threadIdx.x; i < NBK; i += 256)
    if (h[i]) atomicAdd(&bcnt[i], h[i]);
}

__global__ __launch_bounds__(512) void bscan_k(const int* __restrict__ bcnt, int* __restrict__ bcur){
  __shared__ int sd[512];
  int t = threadIdx.x;
  int v = (t < NBK) ? bcnt[t] : 0;
  sd[t] = v; __syncthreads();
  for (int o = 1; o < 512; o <<= 1){
    int x = (t >= o) ? sd[t-o] : 0;
    __syncthreads();
    sd[t] += x;
    __syncthreads();
  }
  if (t < NBK) bcur[t] = sd[t] - v;   // exclusive base, doubles as cursor
}

// per-block counting sort into bucket-grouped (src,dst) pairs
__global__ __launch_bounds__(256) void bfill_k(const int* __restrict__ ei, int* __restrict__ bcur,
                                               uint2* __restrict__ epair){
  __shared__ int cnt[NBK];
  __shared__ int gb[NBK];
  for (int i = threadIdx.x; i < NBK; i += 256) cnt[i] = 0;
  __syncthreads();
  int e0 = blockIdx.x * EPB;
  int srcv[EPB/256], dstv[EPB/256], rnk[EPB/256];
  #pragma unroll
  for (int j = 0; j < EPB/256; ++j){
    int e = e0 + j*256 + threadIdx.x;
    if (e < NE){
      srcv[j] = ei[e];
      dstv[j] = ei[NE + e];
      rnk[j]  = atomicAdd(&cnt[dstv[j] >> 8], 1);
    } else dstv[j] = -1;
  }
  __syncthreads();
  for (int i = threadIdx.x; i < NBK; i += 256){
    int c = cnt[i];
    gb[i] = c ? atomicAdd(&bcur[i], c) : 0;
  }
  __syncthreads();
  #pragma unroll
  for (int j = 0; j < EPB/256; ++j){
    if (dstv[j] >= 0)
      epair[gb[dstv[j] >> 8] + rnk[j]] = make_uint2((unsigned)srcv[j], (unsigned)dstv[j]);
  }
}

__global__ __launch_bounds__(256) void scan1_k(const int* __restrict__ deg, int* __restrict__ bsum){
  __shared__ int sd[256];
  int t = threadIdx.x, i = blockIdx.x*256 + t;
  sd[t] = (i < NN) ? deg[i] : 0;
  __syncthreads();
  for (int o = 128; o > 0; o >>= 1){ if (t < o) sd[t] += sd[t+o]; __syncthreads(); }
  if (t == 0) bsum[blockIdx.x] = sd[0];
}

__global__ __launch_bounds__(512) void scan2_k(const int* __restrict__ bsum, int* __restrict__ boff,
                                               int* __restrict__ rp, int NB){
  __shared__ int sd[512];
  int t = threadIdx.x;
  int v = (t < NB) ? bsum[t] : 0;
  sd[t] = v; __syncthreads();
  for (int o = 1; o < 512; o <<= 1){
    int x = (t >= o) ? sd[t-o] : 0;
    __syncthreads();
    sd[t] += x;
    __syncthreads();
  }
  if (t < NB) boff[t] = sd[t] - v;
  if (t == 511) rp[NN] = sd[511];
}

__global__ __launch_bounds__(256) void scan3_k(const int* __restrict__ deg, const int* __restrict__ boff,
                                               int* __restrict__ rp, int* __restrict__ cur){
  __shared__ int sd[256];
  int t = threadIdx.x, i = blockIdx.x*256 + t;
  int v = (i < NN) ? deg[i] : 0;
  sd[t] = v; __syncthreads();
  for (int o = 1; o < 256; o <<= 1){
    int x = (t >= o) ? sd[t-o] : 0;
    __syncthreads();
    sd[t] += x;
    __syncthreads();
  }
  if (i < NN){
    int ex = boff[blockIdx.x] + sd[t] - v;
    rp[i] = ex; cur[i] = ex;
  }
}

// final fill from bucket-grouped pairs: cur atomics + ci writes are L2-local
__global__ __launch_bounds__(256) void ffill_k(const uint2* __restrict__ epair, int* __restrict__ cur,
                                               int* __restrict__ ci){
  int e = blockIdx.x*256 + threadIdx.x;
  if (e >= NE) return;
  uint2 p = epair[e];
  int pos = atomicAdd(&cur[p.y], 1);
  ci[pos] = (int)p.x;
}

// ---------------- mean aggregation: one wave per node, 4-way MLP ----------------

__global__ __launch_bounds__(256) void agg_k(const int* __restrict__ rp, const int* __restrict__ ci,
                                             const u16* __restrict__ h, u16* __restrict__ ag){
  int w = (int)((blockIdx.x*256u + threadIdx.x) >> 6);
  int lane = threadIdx.x & 63;
  if (w >= NN) return;
  int e0 = rp[w], e1 = rp[w+1];
  const uint2* hu = (const uint2*)h;
  float a0=0.f, a1=0.f, a2=0.f, a3=0.f;
  for (int base = e0; base < e1; base += 64){
    int cnt = e1 - base; if (cnt > 64) cnt = 64;
    int my = ci[base + (lane < cnt ? lane : cnt-1)];
    int i = 0;
    for (; i + 4 <= cnt; i += 4){
      int s0 = __builtin_amdgcn_readlane(my, i);
      int s1 = __builtin_amdgcn_readlane(my, i+1);
      int s2 = __builtin_amdgcn_readlane(my, i+2);
      int s3 = __builtin_amdgcn_readlane(my, i+3);
      uint2 v0 = hu[(size_t)s0*64 + lane];
      uint2 v1 = hu[(size_t)s1*64 + lane];
      uint2 v2 = hu[(size_t)s2*64 + lane];
      uint2 v3 = hu[(size_t)s3*64 + lane];
      a0 += bf2f((u16)(v0.x&0xffffu)) + bf2f((u16)(v1.x&0xffffu)) + bf2f((u16)(v2.x&0xffffu)) + bf2f((u16)(v3.x&0xffffu));
      a1 += bf2f((u16)(v0.x>>16))     + bf2f((u16)(v1.x>>16))     + bf2f((u16)(v2.x>>16))     + bf2f((u16)(v3.x>>16));
      a2 += bf2f((u16)(v0.y&0xffffu)) + bf2f((u16)(v1.y&0xffffu)) + bf2f((u16)(v2.y&0xffffu)) + bf2f((u16)(v3.y&0xffffu));
      a3 += bf2f((u16)(v0.y>>16))     + bf2f((u16)(v1.y>>16))     + bf2f((u16)(v2.y>>16))     + bf2f((u16)(v3.y>>16));
    }
    for (; i < cnt; ++i){
      int s0 = __builtin_amdgcn_readlane(my, i);
      uint2 v = hu[(size_t)s0*64 + lane];
      a0 += bf2f((u16)(v.x&0xffffu));
      a1 += bf2f((u16)(v.x>>16));
      a2 += bf2f((u16)(v.y&0xffffu));
      a3 += bf2f((u16)(v.y>>16));
    }
  }
  int d = e1 - e0;
  float inv = 1.0f / (float)(d > 0 ? d : 1);
  uint2 o;
  o.x = (uint32_t)f2bf(a0*inv) | ((uint32_t)f2bf(a1*inv) << 16);
  o.y = (uint32_t)f2bf(a2*inv) | ((uint32_t)f2bf(a3*inv) << 16);
  ((uint2*)ag)[(size_t)w*64 + lane] = o;
}

// ---------------- MFMA GEMM: C[M,NC] = [A1|A2] @ Wpacked + bias ----------------
// block = 4 waves, MF*16 rows; wave covers NFRAG*16 cols. K-loop fully unrolled
// (KS1/KS2 compile-time) with depth-1 register double-buffer prefetch.
// EPI 0: relu, store bf16.  EPI 1: store bf16 + BN sum/sumsq atomics
//        (block-striped: one cache line per 16-lane atomic instr).

template<int MF, int NFRAG, int EPI, int KS1, int KS2>
__global__ __launch_bounds__(256) void gemm_k(
    const u16* __restrict__ A1, const u16* __restrict__ A2,
    const u16* __restrict__ Wp, const float* __restrict__ bias,
    u16* __restrict__ Cout, int M,
    float* __restrict__ stS)
{
  constexpr int NC  = NFRAG*64;
  constexpr int NT  = NC >> 4;
  constexpr int K1  = KS1*32;
  constexpr int K2  = KS2*32;
  constexpr int KST = KS1 + KS2;

  int lane = threadIdx.x & 63;
  int wv   = threadIdx.x >> 6;
  int rb   = blockIdx.x * (MF*16);
  int col0 = wv * (NFRAG*16);
  int r15  = lane & 15, kg = lane >> 4;

  f32x4 acc[MF][NFRAG];
  #pragma unroll
  for (int m = 0; m < MF; ++m)
    #pragma unroll
    for (int n = 0; n < NFRAG; ++n){ f32x4 z = {0.f,0.f,0.f,0.f}; acc[m][n] = z; }

  const u16* Bp = Wp + ((size_t)((col0 >> 4)*64 + lane))*8;
  constexpr size_t bstep = (size_t)NT*64*8;

  const u16* A1base = A1 + (size_t)(rb + r15)*K1 + kg*8;
  const u16* A2base = (KS2 > 0) ? (A2 + (size_t)(rb + r15)*K2 + kg*8) : A1base;

  s16x8 abuf[2][MF], bbuf[2][NFRAG];

  // prologue: load ks=0
  #pragma unroll
  for (int m = 0; m < MF; ++m) abuf[0][m] = *(const s16x8*)(A1base + (size_t)m*16*K1);
  #pragma unroll
  for (int n = 0; n < NFRAG; ++n) bbuf[0][n] = *(const s16x8*)(Bp + (size_t)n*512);

  #pragma unroll
  for (int ks = 0; ks < KST; ++ks){
    const int cur = ks & 1, nxt = cur ^ 1;
    if (ks + 1 < KST){
      const int ksn = ks + 1;
      if (ksn < KS1){
        const u16* Ab = A1base + ksn*32;
        #pragma unroll
        for (int m = 0; m < MF; ++m) abuf[nxt][m] = *(const s16x8*)(Ab + (size_t)m*16*K1);
      } else {
        const u16* Ab = A2base + (ksn - KS1)*32;
        #pragma unroll
        for (int m = 0; m < MF; ++m) abuf[nxt][m] = *(const s16x8*)(Ab + (size_t)m*16*K2);
      }
      const u16* Bb = Bp + (size_t)ksn*bstep;
      #pragma unroll
      for (int n = 0; n < NFRAG; ++n) bbuf[nxt][n] = *(const s16x8*)(Bb + (size_t)n*512);
    }
    #pragma unroll
    for (int m = 0; m < MF; ++m)
      #pragma unroll
      for (int n = 0; n < NFRAG; ++n)
        acc[m][n] = __builtin_amdgcn_mfma_f32_16x16x32_bf16(abuf[cur][m], bbuf[cur][n], acc[m][n], 0, 0, 0);
  }

  // Cout may alias A1 (out <- agg buffer): wait for ALL waves' reads first.
  __syncthreads();

  #pragma unroll
  for (int n = 0; n < NFRAG; ++n){
    int col = col0 + n*16 + r15;
    float bc = bias[col];
    float s = 0.f, q = 0.f;
    #pragma unroll
    for (int m = 0; m < MF; ++m){
      int rbase = rb + m*16 + kg*4;
      #pragma unroll
      for (int r = 0; r < 4; ++r){
        int row = rbase + r;
        float val = acc[m][n][r] + bc;
        if (EPI == 0) val = fmaxf(val, 0.f);
        bool ok = row < M;
        if (ok) Cout[(size_t)row*NC + col] = f2bf(val);
        if (EPI == 1 && ok){ s += val; q += val*val; }
      }
    }
    if (EPI == 1){
      s += __shfl_xor(s, 16); s += __shfl_xor(s, 32);
      q += __shfl_xor(q, 16); q += __shfl_xor(q, 32);
      if (lane < 16){
        int idx = ((blockIdx.x & 15) << 9) + col;   // stripe*512 + col
        atomicAdd(&stS[idx], s);
        atomicAdd(&stS[idx + 256], q);
      }
    }
  }
}

// ---------------- BN finalize + apply ----------------

__global__ __launch_bounds__(256) void bnfin_k(const float* __restrict__ acc,
                                               const float* __restrict__ g, const float* __restrict__ b,
                                               float* __restrict__ coef){
  int c = threadIdx.x;
  float s = 0.f, q = 0.f;
  #pragma unroll
  for (int j = 0; j < 16; ++j){
    s += acc[j*512 + c];
    q += acc[j*512 + 256 + c];
  }
  float mean = s * (1.0f / (float)NN);
  float var  = q * (1.0f / (float)NN) - mean*mean;
  float sc = g[c] * rsqrtf(var + 1e-5f);
  coef[c] = sc;
  coef[256 + c] = b[c] - mean*sc;
}

__global__ __launch_bounds__(256) void bnapply_k(const uint4* __restrict__ outb, uint4* __restrict__ h,
                                                 const float* __restrict__ coef, int layer){
  int i = blockIdx.x*256 + threadIdx.x;
  if (i >= NN*32) return;
  int col0 = (i & 31) * 8;
  const float4* scp = (const float4*)(coef + col0);
  const float4* shp = (const float4*)(coef + 256 + col0);
  float4 s0 = scp[0], s1 = scp[1], t0 = shp[0], t1 = shp[1];
  float sc[8] = {s0.x,s0.y,s0.z,s0.w,s1.x,s1.y,s1.z,s1.w};
  float sh[8] = {t0.x,t0.y,t0.z,t0.w,t1.x,t1.y,t1.z,t1.w};
  float v[8], r[8];
  up8(outb[i], v);
  #pragma unroll
  for (int j = 0; j < 8; ++j) r[j] = fmaxf(v[j]*sc[j] + sh[j], 0.f);
  if (layer > 0){
    float hv[8];
    up8(h[i], hv);
    #pragma unroll
    for (int j = 0; j < 8; ++j) r[j] += hv[j];
  }
  h[i] = pk8(r);
}

// ---------------- fc2 logits + embeddings copy-out ----------------

__global__ __launch_bounds__(256) void fc2_k(const u16* __restrict__ z, const float* __restrict__ w2,
                                             const float* __restrict__ b2, float* __restrict__ out){
  int w = (int)((blockIdx.x*256u + threadIdx.x) >> 6);
  int lane = threadIdx.x & 63;
  if (w >= NN) return;
  const uint32_t* zu = (const uint32_t*)(z + (size_t)w*128);
  uint32_t p = zu[lane];
  float z0 = bf2f((u16)(p & 0xffffu));
  float z1 = bf2f((u16)(p >> 16));
  float4 wv = ((const float4*)w2)[lane];
  float p0 = z0*wv.x + z1*wv.z;
  float p1 = z0*wv.y + z1*wv.w;
  #pragma unroll
  for (int off = 1; off < 64; off <<= 1){
    p0 += __shfl_xor(p0, off);
    p1 += __shfl_xor(p1, off);
  }
  if (lane == 0){
    out[(size_t)w*2]     = p0 + b2[0];
    out[(size_t)w*2 + 1] = p1 + b2[1];
  }
}

__global__ __launch_bounds__(256) void emb_k(const u16* __restrict__ h, float* __restrict__ out, int n4){
  int i = blockIdx.x*256 + threadIdx.x;
  if (i >= n4) return;
  uint2 v = ((const uint2*)h)[i];
  float4 o;
  o.x = bf2f((u16)(v.x & 0xffffu));
  o.y = bf2f((u16)(v.x >> 16));
  o.z = bf2f((u16)(v.y & 0xffffu));
  o.w = bf2f((u16)(v.y >> 16));
  ((float4*)out)[i] = o;
}

// ---------------- host ----------------

extern "C" void kernel_launch(void* const* d_in, const int* in_sizes, int n_in,
                              void* d_out, int out_size, void* d_ws, size_t ws_size,
                              hipStream_t stream){
  const float* x       = (const float*)d_in[0];
  const int*   ei      = (const int*)d_in[1];
  const float* proj_w  = (const float*)d_in[2];
  const float* proj_b  = (const float*)d_in[3];
  const float* lin_l_w = (const float*)d_in[4];
  const float* lin_l_b = (const float*)d_in[5];
  const float* lin_r_w = (const float*)d_in[6];
  const float* bn_g    = (const float*)d_in[7];
  const float* bn_b    = (const float*)d_in[8];
  const float* fc1_w   = (const float*)d_in[9];
  const float* fc1_b   = (const float*)d_in[10];
  const float* fc2_w   = (const float*)d_in[11];
  const float* fc2_b   = (const float*)d_in[12];
  float* out = (float*)d_out;

  char* ws = (char*)d_ws;
  size_t off = 0;
  auto alloc = [&](size_t b){ size_t o = off; off = (off + b + 255) & ~(size_t)255; return o; };

  u16* bufA    = (u16*)(ws + alloc((size_t)MP*256*2));  // x_bf16 -> agg/out -> z
  u16* hbuf    = (u16*)(ws + alloc((size_t)MP*256*2));
  u16* wp_proj = (u16*)(ws + alloc((size_t)4*16*64*8*2));
  u16* wp_l[3];
  for (int i = 0; i < 3; ++i) wp_l[i] = (u16*)(ws + alloc((size_t)16*16*64*8*2));
  u16* wp_fc1  = (u16*)(ws + alloc((size_t)8*8*64*8*2));
  int* deg   = (int*)(ws + alloc((size_t)NN*4));
  int* cur   = (int*)(ws + alloc((size_t)NN*4));
  int* rp    = (int*)(ws + alloc((size_t)(NN+1)*4));
  int* ci    = (int*)(ws + alloc((size_t)NE*4));
  int* bsum  = (int*)(ws + alloc(512*4));
  int* boff  = (int*)(ws + alloc(512*4));
  int* bcnt  = (int*)(ws + alloc(NBK*4));
  int* bcur  = (int*)(ws + alloc(NBK*4));
  float* bnacc = (float*)(ws + alloc(3*8192*4));
  float* coef  = (float*)(ws + alloc(3*512*4));
  uint2* epair = (uint2*)hbuf;   // hbuf is dead until proj gemm
  (void)ws_size; (void)in_sizes; (void)n_in; (void)out_size;

  const int NB = (NN + 255)/256;  // 391
  const int BFB = (NE + EPB - 1)/EPB;  // 782

  zero_k<<<NB, 256, 0, stream>>>(deg, bnacc, bcnt);

  // CSR build (bucketed fill)
  deg_k<<<NE/256, 256, 0, stream>>>(ei, deg);
  bhist_k<<<BFB, 256, 0, stream>>>(ei, bcnt);
  bscan_k<<<1, 512, 0, stream>>>(bcnt, bcur);
  bfill_k<<<BFB, 256, 0, stream>>>(ei, bcur, epair);
  scan1_k<<<NB, 256, 0, stream>>>(deg, bsum);
  scan2_k<<<1, 512, 0, stream>>>(bsum, boff, rp, NB);
  scan3_k<<<NB, 256, 0, stream>>>(deg, boff, rp, cur);
  ffill_k<<<NE/256, 256, 0, stream>>>(epair, cur, ci);

  // weights + input cvt (after ffill: epair/hbuf alias is dead now)
  cvt_k<<<(NN*INC/4 + 255)/256, 256, 0, stream>>>(x, bufA, NN*INC/4);
  pack_k<<<(128*256 + 255)/256, 256, 0, stream>>>(proj_w, wp_proj, 128, 256, 0);
  for (int i = 0; i < 3; ++i){
    pack_k<<<(256*256 + 255)/256, 256, 0, stream>>>(lin_l_w + (size_t)i*65536, wp_l[i], 256, 256, 0);
    pack_k<<<(256*256 + 255)/256, 256, 0, stream>>>(lin_r_w + (size_t)i*65536, wp_l[i], 256, 256, 8);
  }
  pack_k<<<(256*128 + 255)/256, 256, 0, stream>>>(fc1_w, wp_fc1, 256, 128, 0);

  // proj: h = relu(x @ proj_w + proj_b)
  gemm_k<8,4,0,4,0><<<MBLK8, 256, 0, stream>>>(bufA, nullptr, wp_proj, proj_b,
                                               hbuf, NN, nullptr);

  for (int i = 0; i < 3; ++i){
    agg_k<<<(NN + 3)/4, 256, 0, stream>>>(rp, ci, hbuf, bufA);
    gemm_k<8,4,1,8,8><<<MBLK8, 256, 0, stream>>>(bufA, hbuf, wp_l[i], lin_l_b + (size_t)i*256,
                                                 bufA, NN, bnacc + i*8192);
    bnfin_k<<<1, 256, 0, stream>>>(bnacc + i*8192, bn_g + (size_t)i*256, bn_b + (size_t)i*256, coef + i*512);
    bnapply_k<<<(NN*32 + 255)/256, 256, 0, stream>>>((const uint4*)bufA, (uint4*)hbuf, coef + i*512, i);
  }

  // fc1: z = relu(h @ fc1_w + fc1_b)
  gemm_k<8,2,0,8,0><<<MBLK8, 256, 0, stream>>>(hbuf, nullptr, wp_fc1, fc1_b,
                                               bufA, NN, nullptr);
  fc2_k<<<(NN + 3)/4, 256, 0, stream>>>(bufA, fc2_w, fc2_b, out);
  emb_k<<<(NN*64 + 255)/256, 256, 0, stream>>>(hbuf, out + 200000, NN*64);
}

// Round 5
// 981.578 us; speedup vs baseline: 1.2767x; 1.2767x over previous
//
#include <hip/hip_runtime.h>
#include <stdint.h>

#define NN 100000      // nodes
#define NE 1600000     // edges
#define INC 128        // in channels
#define HID 256        // hidden
#define MP  100096     // padded rows (128*782)
#define MBLK8 782      // row blocks of 128
#define NBK 391        // dst buckets (dst>>8), 99999>>8 = 390
#define EPB 2048       // edges per bucket-fill block

typedef unsigned short u16;
typedef __attribute__((ext_vector_type(4))) float f32x4;
typedef __attribute__((ext_vector_type(8))) short s16x8;

static __device__ __forceinline__ float bf2f(u16 u){
  union { uint32_t i; float f; } v; v.i = ((uint32_t)u) << 16; return v.f;
}
static __device__ __forceinline__ u16 f2bf(float f){
  union { float f; uint32_t i; } v; v.f = f;
  uint32_t r = v.i + 0x7FFFu + ((v.i >> 16) & 1u);
  return (u16)(r >> 16);
}
static __device__ __forceinline__ void up8(uint4 o, float* v){
  v[0]=bf2f((u16)(o.x&0xffffu)); v[1]=bf2f((u16)(o.x>>16));
  v[2]=bf2f((u16)(o.y&0xffffu)); v[3]=bf2f((u16)(o.y>>16));
  v[4]=bf2f((u16)(o.z&0xffffu)); v[5]=bf2f((u16)(o.z>>16));
  v[6]=bf2f((u16)(o.w&0xffffu)); v[7]=bf2f((u16)(o.w>>16));
}
static __device__ __forceinline__ uint4 pk8(const float* v){
  uint4 o;
  o.x = (uint32_t)f2bf(v[0]) | ((uint32_t)f2bf(v[1])<<16);
  o.y = (uint32_t)f2bf(v[2]) | ((uint32_t)f2bf(v[3])<<16);
  o.z = (uint32_t)f2bf(v[4]) | ((uint32_t)f2bf(v[5])<<16);
  o.w = (uint32_t)f2bf(v[6]) | ((uint32_t)f2bf(v[7])<<16);
  return o;
}

// async global -> LDS, 16B per lane; LDS dest = wave-uniform base + lane*16
static __device__ __forceinline__ void gload16(const void* g, void* l){
  __builtin_amdgcn_global_load_lds((const __attribute__((address_space(1))) void*)g,
                                   (__attribute__((address_space(3))) void*)l, 16, 0, 0);
}

// ---------------- misc small kernels ----------------

__global__ __launch_bounds__(256) void zero_k(int* deg, float* bnacc, int* bcnt){
  int i = blockIdx.x*256 + threadIdx.x;
  if (i < NN) deg[i] = 0;
  if (i < 3*8192) bnacc[i] = 0.f;
  if (i < NBK) bcnt[i] = 0;
}

__global__ __launch_bounds__(256) void cvt_k(const float* __restrict__ src, u16* __restrict__ dst, int n4){
  int i = blockIdx.x*256 + threadIdx.x;
  if (i >= n4) return;
  float4 v = ((const float4*)src)[i];
  uint2 o;
  o.x = (uint32_t)f2bf(v.x) | ((uint32_t)f2bf(v.y)<<16);
  o.y = (uint32_t)f2bf(v.z) | ((uint32_t)f2bf(v.w)<<16);
  ((uint2*)dst)[i] = o;
}

// pack W[K][NC] (f32 row-major) into MFMA B-fragment order:
// frag (ks, nt): lane l, elem j  <-  W[ks*32 + (l>>4)*8 + j][nt*16 + (l&15)]
__global__ __launch_bounds__(256) void pack_k(const float* __restrict__ src, u16* __restrict__ dst,
                                              int K, int NC, int ksoff){
  int t = blockIdx.x*256 + threadIdx.x;
  if (t >= K*NC) return;
  int k = t / NC, n = t % NC;
  int NT = NC >> 4;
  int ks = ksoff + (k >> 5);
  int l  = ((k >> 3) & 3)*16 + (n & 15);
  int j  = k & 7;
  dst[((size_t)(ks*NT + (n>>4))*64 + l)*8 + j] = f2bf(src[(size_t)k*NC + n]);
}

// ---------------- CSR build (bucketed) ----------------

__global__ __launch_bounds__(256) void deg_k(const int* __restrict__ ei, int* __restrict__ deg){
  int e = blockIdx.x*256 + threadIdx.x;
  if (e >= NE) return;
  atomicAdd(&deg[ei[NE + e]], 1);
}

__global__ __launch_bounds__(256) void bhist_k(const int* __restrict__ ei, int* __restrict__ bcnt){
  __shared__ int h[NBK];
  for (int i = threadIdx.x; i < NBK; i += 256) h[i] = 0;
  __syncthreads();
  int e0 = blockIdx.x * EPB;
  #pragma unroll
  for (int j = 0; j < EPB/256; ++j){
    int e = e0 + j*256 + threadIdx.x;
    if (e < NE) atomicAdd(&h[ei[NE + e] >> 8], 1);
  }
  __syncthreads();
  for (int i = threadIdx.x; i < NBK; i += 256)
    if (h[i]) atomicAdd(&bcnt[i], h[i]);
}

__global__ __launch_bounds__(512) void bscan_k(const int* __restrict__ bcnt, int* __restrict__ bcur){
  __shared__ int sd[512];
  int t = threadIdx.x;
  int v = (t < NBK) ? bcnt[t] : 0;
  sd[t] = v; __syncthreads();
  for (int o = 1; o < 512; o <<= 1){
    int x = (t >= o) ? sd[t-o] : 0;
    __syncthreads();
    sd[t] += x;
    __syncthreads();
  }
  if (t < NBK) bcur[t] = sd[t] - v;   // exclusive base, doubles as cursor
}

// per-block counting sort into bucket-grouped (src,dst) pairs
__global__ __launch_bounds__(256) void bfill_k(const int* __restrict__ ei, int* __restrict__ bcur,
                                               uint2* __restrict__ epair){
  __shared__ int cnt[NBK];
  __shared__ int gb[NBK];
  for (int i = threadIdx.x; i < NBK; i += 256) cnt[i] = 0;
  __syncthreads();
  int e0 = blockIdx.x * EPB;
  int srcv[EPB/256], dstv[EPB/256], rnk[EPB/256];
  #pragma unroll
  for (int j = 0; j < EPB/256; ++j){
    int e = e0 + j*256 + threadIdx.x;
    if (e < NE){
      srcv[j] = ei[e];
      dstv[j] = ei[NE + e];
      rnk[j]  = atomicAdd(&cnt[dstv[j] >> 8], 1);
    } else dstv[j] = -1;
  }
  __syncthreads();
  for (int i = threadIdx.x; i < NBK; i += 256){
    int c = cnt[i];
    gb[i] = c ? atomicAdd(&bcur[i], c) : 0;
  }
  __syncthreads();
  #pragma unroll
  for (int j = 0; j < EPB/256; ++j){
    if (dstv[j] >= 0)
      epair[gb[dstv[j] >> 8] + rnk[j]] = make_uint2((unsigned)srcv[j], (unsigned)dstv[j]);
  }
}

__global__ __launch_bounds__(256) void scan1_k(const int* __restrict__ deg, int* __restrict__ bsum){
  __shared__ int sd[256];
  int t = threadIdx.x, i = blockIdx.x*256 + t;
  sd[t] = (i < NN) ? deg[i] : 0;
  __syncthreads();
  for (int o = 128; o > 0; o >>= 1){ if (t < o) sd[t] += sd[t+o]; __syncthreads(); }
  if (t == 0) bsum[blockIdx.x] = sd[0];
}

__global__ __launch_bounds__(512) void scan2_k(const int* __restrict__ bsum, int* __restrict__ boff,
                                               int* __restrict__ rp, int NB){
  __shared__ int sd[512];
  int t = threadIdx.x;
  int v = (t < NB) ? bsum[t] : 0;
  sd[t] = v; __syncthreads();
  for (int o = 1; o < 512; o <<= 1){
    int x = (t >= o) ? sd[t-o] : 0;
    __syncthreads();
    sd[t] += x;
    __syncthreads();
  }
  if (t < NB) boff[t] = sd[t] - v;
  if (t == 511) rp[NN] = sd[511];
}

__global__ __launch_bounds__(256) void scan3_k(const int* __restrict__ deg, const int* __restrict__ boff,
                                               int* __restrict__ rp, int* __restrict__ cur){
  __shared__ int sd[256];
  int t = threadIdx.x, i = blockIdx.x*256 + t;
  int v = (i < NN) ? deg[i] : 0;
  sd[t] = v; __syncthreads();
  for (int o = 1; o < 256; o <<= 1){
    int x = (t >= o) ? sd[t-o] : 0;
    __syncthreads();
    sd[t] += x;
    __syncthreads();
  }
  if (i < NN){
    int ex = boff[blockIdx.x] + sd[t] - v;
    rp[i] = ex; cur[i] = ex;
  }
}

// final fill from bucket-grouped pairs: cur atomics + ci writes are L2-local
__global__ __launch_bounds__(256) void ffill_k(const uint2* __restrict__ epair, int* __restrict__ cur,
                                               int* __restrict__ ci){
  int e = blockIdx.x*256 + threadIdx.x;
  if (e >= NE) return;
  uint2 p = epair[e];
  int pos = atomicAdd(&cur[p.y], 1);
  ci[pos] = (int)p.x;
}

// ---------------- mean aggregation: one wave per node, 4-way MLP ----------------

__global__ __launch_bounds__(256) void agg_k(const int* __restrict__ rp, const int* __restrict__ ci,
                                             const u16* __restrict__ h, u16* __restrict__ ag){
  int w = (int)((blockIdx.x*256u + threadIdx.x) >> 6);
  int lane = threadIdx.x & 63;
  if (w >= NN) return;
  int e0 = rp[w], e1 = rp[w+1];
  const uint2* hu = (const uint2*)h;
  float a0=0.f, a1=0.f, a2=0.f, a3=0.f;
  for (int base = e0; base < e1; base += 64){
    int cnt = e1 - base; if (cnt > 64) cnt = 64;
    int my = ci[base + (lane < cnt ? lane : cnt-1)];
    int i = 0;
    for (; i + 4 <= cnt; i += 4){
      int s0 = __builtin_amdgcn_readlane(my, i);
      int s1 = __builtin_amdgcn_readlane(my, i+1);
      int s2 = __builtin_amdgcn_readlane(my, i+2);
      int s3 = __builtin_amdgcn_readlane(my, i+3);
      uint2 v0 = hu[(size_t)s0*64 + lane];
      uint2 v1 = hu[(size_t)s1*64 + lane];
      uint2 v2 = hu[(size_t)s2*64 + lane];
      uint2 v3 = hu[(size_t)s3*64 + lane];
      a0 += bf2f((u16)(v0.x&0xffffu)) + bf2f((u16)(v1.x&0xffffu)) + bf2f((u16)(v2.x&0xffffu)) + bf2f((u16)(v3.x&0xffffu));
      a1 += bf2f((u16)(v0.x>>16))     + bf2f((u16)(v1.x>>16))     + bf2f((u16)(v2.x>>16))     + bf2f((u16)(v3.x>>16));
      a2 += bf2f((u16)(v0.y&0xffffu)) + bf2f((u16)(v1.y&0xffffu)) + bf2f((u16)(v2.y&0xffffu)) + bf2f((u16)(v3.y&0xffffu));
      a3 += bf2f((u16)(v0.y>>16))     + bf2f((u16)(v1.y>>16))     + bf2f((u16)(v2.y>>16))     + bf2f((u16)(v3.y>>16));
    }
    for (; i < cnt; ++i){
      int s0 = __builtin_amdgcn_readlane(my, i);
      uint2 v = hu[(size_t)s0*64 + lane];
      a0 += bf2f((u16)(v.x&0xffffu));
      a1 += bf2f((u16)(v.x>>16));
      a2 += bf2f((u16)(v.y&0xffffu));
      a3 += bf2f((u16)(v.y>>16));
    }
  }
  int d = e1 - e0;
  float inv = 1.0f / (float)(d > 0 ? d : 1);
  uint2 o;
  o.x = (uint32_t)f2bf(a0*inv) | ((uint32_t)f2bf(a1*inv) << 16);
  o.y = (uint32_t)f2bf(a2*inv) | ((uint32_t)f2bf(a3*inv) << 16);
  ((uint2*)ag)[(size_t)w*64 + lane] = o;
}

// ---------------- 2-phase LDS-pipelined MFMA GEMM ----------------
// C[M,NCC] = [A1 | A2] @ Wpacked + bias.  Tile 128x128, BK=64, 256 thr = 4 waves
// (2x2 wave grid, 64x64 per wave).  Double-buffered LDS staged via
// global_load_lds (width 16); A uses XOR swizzle (inverse-swizzled global src,
// swizzled ds_read).  B staged from fragment-packed weights (dense reads).
// EPI 0: relu.  EPI 1: no relu + block-striped BN sum/sumsq atomics.

template<int KS1, int KS2, int NCC, int EPI>
__global__ __launch_bounds__(256, 2) void gemm2_k(
    const u16* __restrict__ A1, const u16* __restrict__ A2,
    const u16* __restrict__ Wp, const float* __restrict__ bias,
    u16* __restrict__ Cout, int M, float* __restrict__ stS)
{
  constexpr int NT    = NCC >> 4;
  constexpr int NS1   = KS1 / 2;           // BK-steps in A1
  constexpr int NSTEP = (KS1 + KS2) / 2;   // total BK-steps

  __shared__ u16 Al[2][128*64];    // 16KB per buffer, [row][64 k-elems] + swizzle
  __shared__ u16 Bl[2][2*8*64*8];  // 16KB per buffer: [slice][nt_local][lane][8]

  const int t    = threadIdx.x;
  const int lane = t & 63;
  const int wv   = t >> 6;
  const int wr   = wv >> 1, wc = wv & 1;
  const int r15  = lane & 15, kg = lane >> 4;
  const int rb   = blockIdx.x * 128;
  const int nh   = blockIdx.y;             // column half (always 0 if NCC==128)
  const int nt0  = nh * 8;

  f32x4 acc[4][4];
  #pragma unroll
  for (int m = 0; m < 4; ++m)
    #pragma unroll
    for (int n = 0; n < 4; ++n){ f32x4 z = {0.f,0.f,0.f,0.f}; acc[m][n] = z; }

  // ---- staging lambda: one BK-step into dbuf slot bsel ----
  auto stage = [&](int step, int bsel){
    const bool inA1 = (step < NS1);
    const u16* Ab   = inA1 ? A1 : A2;
    const int  Krow = (inA1 ? KS1 : KS2) * 32;     // row length in u16
    const int  kloc = (inA1 ? step : step - NS1) * 64; // k-start (u16) in this matrix
    #pragma unroll
    for (int c = 0; c < 4; ++c){
      int row = c*32 + wv*8 + (lane >> 3);
      int gc  = (lane & 7) ^ (row & 7);            // inverse swizzle on global src
      const u16* g = Ab + (size_t)(rb + row)*Krow + kloc + gc*8;
      gload16(g, &Al[bsel][c*2048 + wv*512]);
    }
    const int s0 = step * 2;                        // global k-slice base in Wp
    #pragma unroll
    for (int c = 0; c < 4; ++c){
      int base = c*4096 + wv*1024;                  // byte offset in Bl buffer
      int sl   = base >> 13;
      int ntl  = (base >> 10) & 7;
      const u16* g = Wp + ((size_t)((s0 + sl)*NT + nt0 + ntl)*64)*8 + lane*8;
      gload16(g, &Bl[bsel][base >> 1]);
    }
  };

  // prologue
  stage(0, 0);
  __syncthreads();   // drains vmcnt

  #pragma unroll
  for (int step = 0; step < NSTEP; ++step){
    const int cur = step & 1;
    if (step + 1 < NSTEP) stage(step + 1, cur ^ 1);

    s16x8 af[2][4], bf[2][4];
    const char* Ab = (const char*)&Al[cur][0];
    const char* Bb = (const char*)&Bl[cur][0];
    #pragma unroll
    for (int sl = 0; sl < 2; ++sl){
      #pragma unroll
      for (int m = 0; m < 4; ++m){
        int row = wr*64 + m*16 + r15;
        int c16 = (sl*4 + kg) ^ (row & 7);          // swizzled read
        af[sl][m] = *(const s16x8*)(Ab + row*128 + c16*16);
      }
      #pragma unroll
      for (int n = 0; n < 4; ++n)
        bf[sl][n] = *(const s16x8*)(Bb + sl*8192 + (wc*4 + n)*1024 + lane*16);
    }
    #pragma unroll
    for (int sl = 0; sl < 2; ++sl)
      #pragma unroll
      for (int m = 0; m < 4; ++m)
        #pragma unroll
        for (int n = 0; n < 4; ++n)
          acc[m][n] = __builtin_amdgcn_mfma_f32_16x16x32_bf16(af[sl][m], bf[sl][n], acc[m][n], 0, 0, 0);

    __syncthreads();  // drains staging of step+1 AND closes reads of buf[cur]
  }

  // ---- epilogue ----
  #pragma unroll
  for (int n = 0; n < 4; ++n){
    int col = nh*128 + wc*64 + n*16 + r15;
    float bc = bias[col];
    float s = 0.f, q = 0.f;
    #pragma unroll
    for (int m = 0; m < 4; ++m){
      int rbase = rb + wr*64 + m*16 + kg*4;
      #pragma unroll
      for (int r = 0; r < 4; ++r){
        int row = rbase + r;
        float val = acc[m][n][r] + bc;
        if (EPI == 0) val = fmaxf(val, 0.f);
        bool ok = row < M;
        if (ok) Cout[(size_t)row*NCC + col] = f2bf(val);
        if (EPI == 1 && ok){ s += val; q += val*val; }
      }
    }
    if (EPI == 1){
      s += __shfl_xor(s, 16); s += __shfl_xor(s, 32);
      q += __shfl_xor(q, 16); q += __shfl_xor(q, 32);
      if (lane < 16){
        int idx = ((blockIdx.x & 15) << 9) + col;   // stripe*512 + col
        atomicAdd(&stS[idx], s);
        atomicAdd(&stS[idx + 256], q);
      }
    }
  }
}

// ---------------- BN finalize + apply ----------------

__global__ __launch_bounds__(256) void bnfin_k(const float* __restrict__ acc,
                                               const float* __restrict__ g, const float* __restrict__ b,
                                               float* __restrict__ coef){
  int c = threadIdx.x;
  float s = 0.f, q = 0.f;
  #pragma unroll
  for (int j = 0; j < 16; ++j){
    s += acc[j*512 + c];
    q += acc[j*512 + 256 + c];
  }
  float mean = s * (1.0f / (float)NN);
  float var  = q * (1.0f / (float)NN) - mean*mean;
  float sc = g[c] * rsqrtf(var + 1e-5f);
  coef[c] = sc;
  coef[256 + c] = b[c] - mean*sc;
}

__global__ __launch_bounds__(256) void bnapply_k(const uint4* __restrict__ outb, uint4* __restrict__ h,
                                                 const float* __restrict__ coef, int layer){
  int i = blockIdx.x*256 + threadIdx.x;
  if (i >= NN*32) return;
  int col0 = (i & 31) * 8;
  const float4* scp = (const float4*)(coef + col0);
  const float4* shp = (const float4*)(coef + 256 + col0);
  float4 s0 = scp[0], s1 = scp[1], t0 = shp[0], t1 = shp[1];
  float sc[8] = {s0.x,s0.y,s0.z,s0.w,s1.x,s1.y,s1.z,s1.w};
  float sh[8] = {t0.x,t0.y,t0.z,t0.w,t1.x,t1.y,t1.z,t1.w};
  float v[8], r[8];
  up8(outb[i], v);
  #pragma unroll
  for (int j = 0; j < 8; ++j) r[j] = fmaxf(v[j]*sc[j] + sh[j], 0.f);
  if (layer > 0){
    float hv[8];
    up8(h[i], hv);
    #pragma unroll
    for (int j = 0; j < 8; ++j) r[j] += hv[j];
  }
  h[i] = pk8(r);
}

// ---------------- fc2 logits + embeddings copy-out ----------------

__global__ __launch_bounds__(256) void fc2_k(const u16* __restrict__ z, const float* __restrict__ w2,
                                             const float* __restrict__ b2, float* __restrict__ out){
  int w = (int)((blockIdx.x*256u + threadIdx.x) >> 6);
  int lane = threadIdx.x & 63;
  if (w >= NN) return;
  const uint32_t* zu = (const uint32_t*)(z + (size_t)w*128);
  uint32_t p = zu[lane];
  float z0 = bf2f((u16)(p & 0xffffu));
  float z1 = bf2f((u16)(p >> 16));
  float4 wv = ((const float4*)w2)[lane];
  float p0 = z0*wv.x + z1*wv.z;
  float p1 = z0*wv.y + z1*wv.w;
  #pragma unroll
  for (int off = 1; off < 64; off <<= 1){
    p0 += __shfl_xor(p0, off);
    p1 += __shfl_xor(p1, off);
  }
  if (lane == 0){
    out[(size_t)w*2]     = p0 + b2[0];
    out[(size_t)w*2 + 1] = p1 + b2[1];
  }
}

__global__ __launch_bounds__(256) void emb_k(const u16* __restrict__ h, float* __restrict__ out, int n4){
  int i = blockIdx.x*256 + threadIdx.x;
  if (i >= n4) return;
  uint2 v = ((const uint2*)h)[i];
  float4 o;
  o.x = bf2f((u16)(v.x & 0xffffu));
  o.y = bf2f((u16)(v.x >> 16));
  o.z = bf2f((u16)(v.y & 0xffffu));
  o.w = bf2f((u16)(v.y >> 16));
  ((float4*)out)[i] = o;
}

// ---------------- host ----------------

extern "C" void kernel_launch(void* const* d_in, const int* in_sizes, int n_in,
                              void* d_out, int out_size, void* d_ws, size_t ws_size,
                              hipStream_t stream){
  const float* x       = (const float*)d_in[0];
  const int*   ei      = (const int*)d_in[1];
  const float* proj_w  = (const float*)d_in[2];
  const float* proj_b  = (const float*)d_in[3];
  const float* lin_l_w = (const float*)d_in[4];
  const float* lin_l_b = (const float*)d_in[5];
  const float* lin_r_w = (const float*)d_in[6];
  const float* bn_g    = (const float*)d_in[7];
  const float* bn_b    = (const float*)d_in[8];
  const float* fc1_w   = (const float*)d_in[9];
  const float* fc1_b   = (const float*)d_in[10];
  const float* fc2_w   = (const float*)d_in[11];
  const float* fc2_b   = (const float*)d_in[12];
  float* out = (float*)d_out;

  char* ws = (char*)d_ws;
  size_t off = 0;
  auto alloc = [&](size_t b){ size_t o = off; off = (off + b + 255) & ~(size_t)255; return o; };

  u16* bufA    = (u16*)(ws + alloc((size_t)MP*256*2));  // x_bf16 -> agg -> z
  u16* hbuf    = (u16*)(ws + alloc((size_t)MP*256*2));  // h
  u16* bufC    = (u16*)(ws + alloc((size_t)MP*256*2));  // layer gemm out
  u16* wp_proj = (u16*)(ws + alloc((size_t)4*16*64*8*2));
  u16* wp_l[3];
  for (int i = 0; i < 3; ++i) wp_l[i] = (u16*)(ws + alloc((size_t)16*16*64*8*2));
  u16* wp_fc1  = (u16*)(ws + alloc((size_t)8*8*64*8*2));
  int* deg   = (int*)(ws + alloc((size_t)NN*4));
  int* cur   = (int*)(ws + alloc((size_t)NN*4));
  int* rp    = (int*)(ws + alloc((size_t)(NN+1)*4));
  int* ci    = (int*)(ws + alloc((size_t)NE*4));
  int* bsum  = (int*)(ws + alloc(512*4));
  int* boff  = (int*)(ws + alloc(512*4));
  int* bcnt  = (int*)(ws + alloc(NBK*4));
  int* bcur  = (int*)(ws + alloc(NBK*4));
  float* bnacc = (float*)(ws + alloc(3*8192*4));
  float* coef  = (float*)(ws + alloc(3*512*4));
  uint2* epair = (uint2*)bufC;   // bufC is dead until first layer gemm
  (void)ws_size; (void)in_sizes; (void)n_in; (void)out_size;

  const int NB = (NN + 255)/256;  // 391
  const int BFB = (NE + EPB - 1)/EPB;  // 782

  zero_k<<<NB, 256, 0, stream>>>(deg, bnacc, bcnt);

  // CSR build (bucketed fill)
  deg_k<<<NE/256, 256, 0, stream>>>(ei, deg);
  bhist_k<<<BFB, 256, 0, stream>>>(ei, bcnt);
  bscan_k<<<1, 512, 0, stream>>>(bcnt, bcur);
  bfill_k<<<BFB, 256, 0, stream>>>(ei, bcur, epair);
  scan1_k<<<NB, 256, 0, stream>>>(deg, bsum);
  scan2_k<<<1, 512, 0, stream>>>(bsum, boff, rp, NB);
  scan3_k<<<NB, 256, 0, stream>>>(deg, boff, rp, cur);
  ffill_k<<<NE/256, 256, 0, stream>>>(epair, cur, ci);

  // weights + input cvt
  cvt_k<<<(NN*INC/4 + 255)/256, 256, 0, stream>>>(x, bufA, NN*INC/4);
  pack_k<<<(128*256 + 255)/256, 256, 0, stream>>>(proj_w, wp_proj, 128, 256, 0);
  for (int i = 0; i < 3; ++i){
    pack_k<<<(256*256 + 255)/256, 256, 0, stream>>>(lin_l_w + (size_t)i*65536, wp_l[i], 256, 256, 0);
    pack_k<<<(256*256 + 255)/256, 256, 0, stream>>>(lin_r_w + (size_t)i*65536, wp_l[i], 256, 256, 8);
  }
  pack_k<<<(256*128 + 255)/256, 256, 0, stream>>>(fc1_w, wp_fc1, 256, 128, 0);

  // proj: h = relu(x @ proj_w + proj_b)   [K=128, NC=256]
  gemm2_k<4,0,256,0><<<dim3(MBLK8,2), 256, 0, stream>>>(bufA, nullptr, wp_proj, proj_b,
                                                        hbuf, NN, nullptr);

  for (int i = 0; i < 3; ++i){
    agg_k<<<(NN + 3)/4, 256, 0, stream>>>(rp, ci, hbuf, bufA);
    // out = agg @ lin_l + b + h @ lin_r   [K=256+256, NC=256] -> bufC
    gemm2_k<8,8,256,1><<<dim3(MBLK8,2), 256, 0, stream>>>(bufA, hbuf, wp_l[i], lin_l_b + (size_t)i*256,
                                                          bufC, NN, bnacc + i*8192);
    bnfin_k<<<1, 256, 0, stream>>>(bnacc + i*8192, bn_g + (size_t)i*256, bn_b + (size_t)i*256, coef + i*512);
    bnapply_k<<<(NN*32 + 255)/256, 256, 0, stream>>>((const uint4*)bufC, (uint4*)hbuf, coef + i*512, i);
  }

  // fc1: z = relu(h @ fc1_w + fc1_b)   [K=256, NC=128]
  gemm2_k<8,0,128,0><<<dim3(MBLK8,1), 256, 0, stream>>>(hbuf, nullptr, wp_fc1, fc1_b,
                                                        bufA, NN, nullptr);
  fc2_k<<<(NN + 3)/4, 256, 0, stream>>>(bufA, fc2_w, fc2_b, out);
  emb_k<<<(NN*64 + 255)/256, 256, 0, stream>>>(hbuf, out + 200000, NN*64);
}

// Round 7
// 897.157 us; speedup vs baseline: 1.3968x; 1.0941x over previous
//
#include <hip/hip_runtime.h>
#include <stdint.h>

#define NN 100000      // nodes
#define NE 1600000     // edges
#define INC 128        // in channels
#define HID 256        // hidden
#define MP  100096     // padded rows (128*782)
#define MBLK8 782      // row blocks of 128
#define NBK 391        // dst buckets (dst>>8), 99999>>8 = 390
#define EPB 2048       // edges per bucket-fill block

typedef unsigned short u16;
typedef __attribute__((ext_vector_type(2))) float f32x2;
typedef __attribute__((ext_vector_type(4))) float f32x4;
typedef __attribute__((ext_vector_type(8))) short s16x8;

static __device__ __forceinline__ float bf2f(u16 u){
  union { uint32_t i; float f; } v; v.i = ((uint32_t)u) << 16; return v.f;
}
static __device__ __forceinline__ u16 f2bf(float f){
  union { float f; uint32_t i; } v; v.f = f;
  uint32_t r = v.i + 0x7FFFu + ((v.i >> 16) & 1u);
  return (u16)(r >> 16);
}
static __device__ __forceinline__ void up8(uint4 o, float* v){
  v[0]=bf2f((u16)(o.x&0xffffu)); v[1]=bf2f((u16)(o.x>>16));
  v[2]=bf2f((u16)(o.y&0xffffu)); v[3]=bf2f((u16)(o.y>>16));
  v[4]=bf2f((u16)(o.z&0xffffu)); v[5]=bf2f((u16)(o.z>>16));
  v[6]=bf2f((u16)(o.w&0xffffu)); v[7]=bf2f((u16)(o.w>>16));
}
static __device__ __forceinline__ uint4 pk8(const float* v){
  uint4 o;
  o.x = (uint32_t)f2bf(v[0]) | ((uint32_t)f2bf(v[1])<<16);
  o.y = (uint32_t)f2bf(v[2]) | ((uint32_t)f2bf(v[3])<<16);
  o.z = (uint32_t)f2bf(v[4]) | ((uint32_t)f2bf(v[5])<<16);
  o.w = (uint32_t)f2bf(v[6]) | ((uint32_t)f2bf(v[7])<<16);
  return o;
}
// pack 8 f32 -> 8 fp8 e4m3 (2 u32)
static __device__ __forceinline__ uint2 pkf8(const float* r){
  uint32_t lo = __builtin_amdgcn_cvt_pk_fp8_f32(r[0], r[1], 0u, false);
  lo = __builtin_amdgcn_cvt_pk_fp8_f32(r[2], r[3], lo, true);
  uint32_t hi = __builtin_amdgcn_cvt_pk_fp8_f32(r[4], r[5], 0u, false);
  hi = __builtin_amdgcn_cvt_pk_fp8_f32(r[6], r[7], hi, true);
  return make_uint2(lo, hi);
}

// async global -> LDS, 16B per lane; LDS dest = wave-uniform base + lane*16
static __device__ __forceinline__ void gload16(const void* g, void* l){
  __builtin_amdgcn_global_load_lds((const __attribute__((address_space(1))) void*)g,
                                   (__attribute__((address_space(3))) void*)l, 16, 0, 0);
}

// ---------------- misc small kernels ----------------

__global__ __launch_bounds__(256) void zero_k(int* deg, float* bnacc, int* bcnt){
  int i = blockIdx.x*256 + threadIdx.x;
  if (i < NN) deg[i] = 0;
  if (i < 3*8192) bnacc[i] = 0.f;
  if (i < NBK) bcnt[i] = 0;
}

__global__ __launch_bounds__(256) void cvt_k(const float* __restrict__ src, u16* __restrict__ dst, int n4){
  int i = blockIdx.x*256 + threadIdx.x;
  if (i >= n4) return;
  float4 v = ((const float4*)src)[i];
  uint2 o;
  o.x = (uint32_t)f2bf(v.x) | ((uint32_t)f2bf(v.y)<<16);
  o.y = (uint32_t)f2bf(v.z) | ((uint32_t)f2bf(v.w)<<16);
  ((uint2*)dst)[i] = o;
}

// bf16 h -> fp8 shadow (8 ch / thread)
__global__ __launch_bounds__(256) void cvt8_k(const uint4* __restrict__ h, uint2* __restrict__ h8, int n){
  int i = blockIdx.x*256 + threadIdx.x;
  if (i >= n) return;
  float v[8];
  up8(h[i], v);
  h8[i] = pkf8(v);
}

// pack W[K][NC] (f32 row-major) into MFMA B-fragment order:
// frag (ks, nt): lane l, elem j  <-  W[ks*32 + (l>>4)*8 + j][nt*16 + (l&15)]
__global__ __launch_bounds__(256) void pack_k(const float* __restrict__ src, u16* __restrict__ dst,
                                              int K, int NC, int ksoff){
  int t = blockIdx.x*256 + threadIdx.x;
  if (t >= K*NC) return;
  int k = t / NC, n = t % NC;
  int NT = NC >> 4;
  int ks = ksoff + (k >> 5);
  int l  = ((k >> 3) & 3)*16 + (n & 15);
  int j  = k & 7;
  dst[((size_t)(ks*NT + (n>>4))*64 + l)*8 + j] = f2bf(src[(size_t)k*NC + n]);
}

// ---------------- CSR build (bucketed) ----------------

__global__ __launch_bounds__(256) void deg_k(const int* __restrict__ ei, int* __restrict__ deg){
  int e = blockIdx.x*256 + threadIdx.x;
  if (e >= NE) return;
  atomicAdd(&deg[ei[NE + e]], 1);
}

__global__ __launch_bounds__(256) void bhist_k(const int* __restrict__ ei, int* __restrict__ bcnt){
  __shared__ int h[NBK];
  for (int i = threadIdx.x; i < NBK; i += 256) h[i] = 0;
  __syncthreads();
  int e0 = blockIdx.x * EPB;
  #pragma unroll
  for (int j = 0; j < EPB/256; ++j){
    int e = e0 + j*256 + threadIdx.x;
    if (e < NE) atomicAdd(&h[ei[NE + e] >> 8], 1);
  }
  __syncthreads();
  for (int i = threadIdx.x; i < NBK; i += 256)
    if (h[i]) atomicAdd(&bcnt[i], h[i]);
}

__global__ __launch_bounds__(512) void bscan_k(const int* __restrict__ bcnt, int* __restrict__ bcur){
  __shared__ int sd[512];
  int t = threadIdx.x;
  int v = (t < NBK) ? bcnt[t] : 0;
  sd[t] = v; __syncthreads();
  for (int o = 1; o < 512; o <<= 1){
    int x = (t >= o) ? sd[t-o] : 0;
    __syncthreads();
    sd[t] += x;
    __syncthreads();
  }
  if (t < NBK) bcur[t] = sd[t] - v;   // exclusive base, doubles as cursor
}

// per-block counting sort into bucket-grouped (src,dst) pairs
__global__ __launch_bounds__(256) void bfill_k(const int* __restrict__ ei, int* __restrict__ bcur,
                                               uint2* __restrict__ epair){
  __shared__ int cnt[NBK];
  __shared__ int gb[NBK];
  for (int i = threadIdx.x; i < NBK; i += 256) cnt[i] = 0;
  __syncthreads();
  int e0 = blockIdx.x * EPB;
  int srcv[EPB/256], dstv[EPB/256], rnk[EPB/256];
  #pragma unroll
  for (int j = 0; j < EPB/256; ++j){
    int e = e0 + j*256 + threadIdx.x;
    if (e < NE){
      srcv[j] = ei[e];
      dstv[j] = ei[NE + e];
      rnk[j]  = atomicAdd(&cnt[dstv[j] >> 8], 1);
    } else dstv[j] = -1;
  }
  __syncthreads();
  for (int i = threadIdx.x; i < NBK; i += 256){
    int c = cnt[i];
    gb[i] = c ? atomicAdd(&bcur[i], c) : 0;
  }
  __syncthreads();
  #pragma unroll
  for (int j = 0; j < EPB/256; ++j){
    if (dstv[j] >= 0)
      epair[gb[dstv[j] >> 8] + rnk[j]] = make_uint2((unsigned)srcv[j], (unsigned)dstv[j]);
  }
}

__global__ __launch_bounds__(256) void scan1_k(const int* __restrict__ deg, int* __restrict__ bsum){
  __shared__ int sd[256];
  int t = threadIdx.x, i = blockIdx.x*256 + t;
  sd[t] = (i < NN) ? deg[i] : 0;
  __syncthreads();
  for (int o = 128; o > 0; o >>= 1){ if (t < o) sd[t] += sd[t+o]; __syncthreads(); }
  if (t == 0) bsum[blockIdx.x] = sd[0];
}

__global__ __launch_bounds__(512) void scan2_k(const int* __restrict__ bsum, int* __restrict__ boff,
                                               int* __restrict__ rp, int NB){
  __shared__ int sd[512];
  int t = threadIdx.x;
  int v = (t < NB) ? bsum[t] : 0;
  sd[t] = v; __syncthreads();
  for (int o = 1; o < 512; o <<= 1){
    int x = (t >= o) ? sd[t-o] : 0;
    __syncthreads();
    sd[t] += x;
    __syncthreads();
  }
  if (t < NB) boff[t] = sd[t] - v;
  if (t == 511) rp[NN] = sd[511];
}

__global__ __launch_bounds__(256) void scan3_k(const int* __restrict__ deg, const int* __restrict__ boff,
                                               int* __restrict__ rp, int* __restrict__ cur){
  __shared__ int sd[256];
  int t = threadIdx.x, i = blockIdx.x*256 + t;
  int v = (i < NN) ? deg[i] : 0;
  sd[t] = v; __syncthreads();
  for (int o = 1; o < 256; o <<= 1){
    int x = (t >= o) ? sd[t-o] : 0;
    __syncthreads();
    sd[t] += x;
    __syncthreads();
  }
  if (i < NN){
    int ex = boff[blockIdx.x] + sd[t] - v;
    rp[i] = ex; cur[i] = ex;
  }
}

// final fill from bucket-grouped pairs: cur atomics + ci writes are L2-local
__global__ __launch_bounds__(256) void ffill_k(const uint2* __restrict__ epair, int* __restrict__ cur,
                                               int* __restrict__ ci){
  int e = blockIdx.x*256 + threadIdx.x;
  if (e >= NE) return;
  uint2 p = epair[e];
  int pos = atomicAdd(&cur[p.y], 1);
  ci[pos] = (int)p.x;
}

// ---------------- mean aggregation over fp8 shadow: 4 nodes per wave ----------------
// h8 row = 256B; quarter q (16 lanes) owns node wid*4+q; lane ql owns 16 channels.

__global__ __launch_bounds__(256) void agg8_k(const int* __restrict__ rp, const int* __restrict__ ci,
                                              const uint4* __restrict__ h8, u16* __restrict__ ag){
  int wid  = (int)((blockIdx.x*256u + threadIdx.x) >> 6);
  int lane = threadIdx.x & 63;
  int ql   = lane & 15;
  int w    = wid*4 + (lane >> 4);
  bool act = (w < NN);
  int e0 = 0, e1 = 0;
  if (act){ e0 = rp[w]; e1 = rp[w+1]; }
  int cnt = e1 - e0;

  float a[16];
  #pragma unroll
  for (int k = 0; k < 16; ++k) a[k] = 0.f;

  for (int base = 0; __any(base < cnt); base += 16){
    int rem = cnt - base;
    int my = 0;
    if (ql < rem) my = ci[e0 + base + ql];
    for (int j0 = 0; j0 < 16 && __any(j0 < rem); j0 += 4){
      uint4 v[4];
      #pragma unroll
      for (int jj = 0; jj < 4; ++jj){
        int j = j0 + jj;
        int s = __shfl(my, (lane & 48) + j);
        v[jj] = make_uint4(0,0,0,0);
        if (j < rem) v[jj] = h8[(size_t)s*16 + ql];
      }
      #pragma unroll
      for (int jj = 0; jj < 4; ++jj){
        uint32_t wd[4] = {v[jj].x, v[jj].y, v[jj].z, v[jj].w};
        #pragma unroll
        for (int p = 0; p < 4; ++p){
          f32x2 lo = __builtin_amdgcn_cvt_pk_f32_fp8(wd[p], false);
          f32x2 hi = __builtin_amdgcn_cvt_pk_f32_fp8(wd[p], true);
          a[p*4+0] += lo[0]; a[p*4+1] += lo[1];
          a[p*4+2] += hi[0]; a[p*4+3] += hi[1];
        }
      }
    }
  }

  if (act){
    float inv = 1.0f / (float)(cnt > 0 ? cnt : 1);
    float r0[8], r1[8];
    #pragma unroll
    for (int k = 0; k < 8; ++k){ r0[k] = a[k]*inv; r1[k] = a[8+k]*inv; }
    uint4* agu = (uint4*)ag;
    agu[(size_t)w*32 + ql*2]     = pk8(r0);
    agu[(size_t)w*32 + ql*2 + 1] = pk8(r1);
  }
}

// ---------------- mean aggregation over bf16 h: one wave per node (proven r5) ----

__global__ __launch_bounds__(256) void aggb_k(const int* __restrict__ rp, const int* __restrict__ ci,
                                              const u16* __restrict__ h, u16* __restrict__ ag){
  int w = (int)((blockIdx.x*256u + threadIdx.x) >> 6);
  int lane = threadIdx.x & 63;
  if (w >= NN) return;
  int e0 = rp[w], e1 = rp[w+1];
  const uint2* hu = (const uint2*)h;
  float a0=0.f, a1=0.f, a2=0.f, a3=0.f;
  for (int base = e0; base < e1; base += 64){
    int cnt = e1 - base; if (cnt > 64) cnt = 64;
    int my = ci[base + (lane < cnt ? lane : cnt-1)];
    int i = 0;
    for (; i + 4 <= cnt; i += 4){
      int s0 = __builtin_amdgcn_readlane(my, i);
      int s1 = __builtin_amdgcn_readlane(my, i+1);
      int s2 = __builtin_amdgcn_readlane(my, i+2);
      int s3 = __builtin_amdgcn_readlane(my, i+3);
      uint2 v0 = hu[(size_t)s0*64 + lane];
      uint2 v1 = hu[(size_t)s1*64 + lane];
      uint2 v2 = hu[(size_t)s2*64 + lane];
      uint2 v3 = hu[(size_t)s3*64 + lane];
      a0 += bf2f((u16)(v0.x&0xffffu)) + bf2f((u16)(v1.x&0xffffu)) + bf2f((u16)(v2.x&0xffffu)) + bf2f((u16)(v3.x&0xffffu));
      a1 += bf2f((u16)(v0.x>>16))     + bf2f((u16)(v1.x>>16))     + bf2f((u16)(v2.x>>16))     + bf2f((u16)(v3.x>>16));
      a2 += bf2f((u16)(v0.y&0xffffu)) + bf2f((u16)(v1.y&0xffffu)) + bf2f((u16)(v2.y&0xffffu)) + bf2f((u16)(v3.y&0xffffu));
      a3 += bf2f((u16)(v0.y>>16))     + bf2f((u16)(v1.y>>16))     + bf2f((u16)(v2.y>>16))     + bf2f((u16)(v3.y>>16));
    }
    for (; i < cnt; ++i){
      int s0 = __builtin_amdgcn_readlane(my, i);
      uint2 v = hu[(size_t)s0*64 + lane];
      a0 += bf2f((u16)(v.x&0xffffu));
      a1 += bf2f((u16)(v.x>>16));
      a2 += bf2f((u16)(v.y&0xffffu));
      a3 += bf2f((u16)(v.y>>16));
    }
  }
  int d = e1 - e0;
  float inv = 1.0f / (float)(d > 0 ? d : 1);
  uint2 o;
  o.x = (uint32_t)f2bf(a0*inv) | ((uint32_t)f2bf(a1*inv) << 16);
  o.y = (uint32_t)f2bf(a2*inv) | ((uint32_t)f2bf(a3*inv) << 16);
  ((uint2*)ag)[(size_t)w*64 + lane] = o;
}

// ---------------- 2-phase LDS-pipelined MFMA GEMM ----------------
// C[M,NCC] = [A1 | A2] @ Wpacked + bias.  Tile 128x128, BK=64, 256 thr = 4 waves
// (2x2 wave grid, 64x64 per wave).  Double-buffered LDS staged via
// global_load_lds (width 16); A uses XOR swizzle (inverse-swizzled global src,
// swizzled ds_read).  B staged from fragment-packed weights (dense reads).
// EPI 0: relu.  EPI 1: no relu + block-striped BN sum/sumsq atomics.

template<int KS1, int KS2, int NCC, int EPI>
__global__ __launch_bounds__(256, 2) void gemm2_k(
    const u16* __restrict__ A1, const u16* __restrict__ A2,
    const u16* __restrict__ Wp, const float* __restrict__ bias,
    u16* __restrict__ Cout, int M, float* __restrict__ stS)
{
  constexpr int NT    = NCC >> 4;
  constexpr int NS1   = KS1 / 2;           // BK-steps in A1
  constexpr int NSTEP = (KS1 + KS2) / 2;   // total BK-steps

  __shared__ u16 Al[2][128*64];    // 16KB per buffer, [row][64 k-elems] + swizzle
  __shared__ u16 Bl[2][2*8*64*8];  // 16KB per buffer: [slice][nt_local][lane][8]

  const int t    = threadIdx.x;
  const int lane = t & 63;
  const int wv   = t >> 6;
  const int wr   = wv >> 1, wc = wv & 1;
  const int r15  = lane & 15, kg = lane >> 4;
  const int rb   = blockIdx.x * 128;
  const int nh   = blockIdx.y;             // column half (always 0 if NCC==128)
  const int nt0  = nh * 8;

  f32x4 acc[4][4];
  #pragma unroll
  for (int m = 0; m < 4; ++m)
    #pragma unroll
    for (int n = 0; n < 4; ++n){ f32x4 z = {0.f,0.f,0.f,0.f}; acc[m][n] = z; }

  // ---- staging lambda: one BK-step into dbuf slot bsel ----
  auto stage = [&](int step, int bsel){
    const bool inA1 = (step < NS1);
    const u16* Ab   = inA1 ? A1 : A2;
    const int  Krow = (inA1 ? KS1 : KS2) * 32;     // row length in u16
    const int  kloc = (inA1 ? step : step - NS1) * 64; // k-start (u16) in this matrix
    #pragma unroll
    for (int c = 0; c < 4; ++c){
      int row = c*32 + wv*8 + (lane >> 3);
      int gc  = (lane & 7) ^ (row & 7);            // inverse swizzle on global src
      const u16* g = Ab + (size_t)(rb + row)*Krow + kloc + gc*8;
      gload16(g, &Al[bsel][c*2048 + wv*512]);
    }
    const int s0 = step * 2;                        // global k-slice base in Wp
    #pragma unroll
    for (int c = 0; c < 4; ++c){
      int base = c*4096 + wv*1024;                  // byte offset in Bl buffer
      int sl   = base >> 13;
      int ntl  = (base >> 10) & 7;
      const u16* g = Wp + ((size_t)((s0 + sl)*NT + nt0 + ntl)*64)*8 + lane*8;
      gload16(g, &Bl[bsel][base >> 1]);
    }
  };

  // prologue
  stage(0, 0);
  __syncthreads();   // drains vmcnt

  #pragma unroll
  for (int step = 0; step < NSTEP; ++step){
    const int cur = step & 1;
    if (step + 1 < NSTEP) stage(step + 1, cur ^ 1);

    s16x8 af[2][4], bf[2][4];
    const char* Ab = (const char*)&Al[cur][0];
    const char* Bb = (const char*)&Bl[cur][0];
    #pragma unroll
    for (int sl = 0; sl < 2; ++sl){
      #pragma unroll
      for (int m = 0; m < 4; ++m){
        int row = wr*64 + m*16 + r15;
        int c16 = (sl*4 + kg) ^ (row & 7);          // swizzled read
        af[sl][m] = *(const s16x8*)(Ab + row*128 + c16*16);
      }
      #pragma unroll
      for (int n = 0; n < 4; ++n)
        bf[sl][n] = *(const s16x8*)(Bb + sl*8192 + (wc*4 + n)*1024 + lane*16);
    }
    #pragma unroll
    for (int sl = 0; sl < 2; ++sl)
      #pragma unroll
      for (int m = 0; m < 4; ++m)
        #pragma unroll
        for (int n = 0; n < 4; ++n)
          acc[m][n] = __builtin_amdgcn_mfma_f32_16x16x32_bf16(af[sl][m], bf[sl][n], acc[m][n], 0, 0, 0);

    __syncthreads();  // drains staging of step+1 AND closes reads of buf[cur]
  }

  // ---- epilogue ----
  #pragma unroll
  for (int n = 0; n < 4; ++n){
    int col = nh*128 + wc*64 + n*16 + r15;
    float bc = bias[col];
    float s = 0.f, q = 0.f;
    #pragma unroll
    for (int m = 0; m < 4; ++m){
      int rbase = rb + wr*64 + m*16 + kg*4;
      #pragma unroll
      for (int r = 0; r < 4; ++r){
        int row = rbase + r;
        float val = acc[m][n][r] + bc;
        if (EPI == 0) val = fmaxf(val, 0.f);
        bool ok = row < M;
        if (ok) Cout[(size_t)row*NCC + col] = f2bf(val);
        if (EPI == 1 && ok){ s += val; q += val*val; }
      }
    }
    if (EPI == 1){
      s += __shfl_xor(s, 16); s += __shfl_xor(s, 32);
      q += __shfl_xor(q, 16); q += __shfl_xor(q, 32);
      if (lane < 16){
        int idx = ((blockIdx.x & 15) << 9) + col;   // stripe*512 + col
        atomicAdd(&stS[idx], s);
        atomicAdd(&stS[idx + 256], q);
      }
    }
  }
}

// ---------------- BN finalize + apply ----------------

__global__ __launch_bounds__(256) void bnfin_k(const float* __restrict__ acc,
                                               const float* __restrict__ g, const float* __restrict__ b,
                                               float* __restrict__ coef){
  int c = threadIdx.x;
  float s = 0.f, q = 0.f;
  #pragma unroll
  for (int j = 0; j < 16; ++j){
    s += acc[j*512 + c];
    q += acc[j*512 + 256 + c];
  }
  float mean = s * (1.0f / (float)NN);
  float var  = q * (1.0f / (float)NN) - mean*mean;
  float sc = g[c] * rsqrtf(var + 1e-5f);
  coef[c] = sc;
  coef[256 + c] = b[c] - mean*sc;
}

__global__ __launch_bounds__(256) void bnapply_k(const uint4* __restrict__ outb, uint4* __restrict__ h,
                                                 uint2* __restrict__ h8,
                                                 const float* __restrict__ coef, int layer, int wr8){
  int i = blockIdx.x*256 + threadIdx.x;
  if (i >= NN*32) return;
  int col0 = (i & 31) * 8;
  const float4* scp = (const float4*)(coef + col0);
  const float4* shp = (const float4*)(coef + 256 + col0);
  float4 s0 = scp[0], s1 = scp[1], t0 = shp[0], t1 = shp[1];
  float sc[8] = {s0.x,s0.y,s0.z,s0.w,s1.x,s1.y,s1.z,s1.w};
  float sh[8] = {t0.x,t0.y,t0.z,t0.w,t1.x,t1.y,t1.z,t1.w};
  float v[8], r[8];
  up8(outb[i], v);
  #pragma unroll
  for (int j = 0; j < 8; ++j) r[j] = fmaxf(v[j]*sc[j] + sh[j], 0.f);
  if (layer > 0){
    float hv[8];
    up8(h[i], hv);
    #pragma unroll
    for (int j = 0; j < 8; ++j) r[j] += hv[j];
  }
  h[i] = pk8(r);
  if (wr8) h8[i] = pkf8(r);
}

// ---------------- fc2 logits + embeddings copy-out ----------------

__global__ __launch_bounds__(256) void fc2_k(const u16* __restrict__ z, const float* __restrict__ w2,
                                             const float* __restrict__ b2, float* __restrict__ out){
  int w = (int)((blockIdx.x*256u + threadIdx.x) >> 6);
  int lane = threadIdx.x & 63;
  if (w >= NN) return;
  const uint32_t* zu = (const uint32_t*)(z + (size_t)w*128);
  uint32_t p = zu[lane];
  float z0 = bf2f((u16)(p & 0xffffu));
  float z1 = bf2f((u16)(p >> 16));
  float4 wv = ((const float4*)w2)[lane];
  float p0 = z0*wv.x + z1*wv.z;
  float p1 = z0*wv.y + z1*wv.w;
  #pragma unroll
  for (int off = 1; off < 64; off <<= 1){
    p0 += __shfl_xor(p0, off);
    p1 += __shfl_xor(p1, off);
  }
  if (lane == 0){
    out[(size_t)w*2]     = p0 + b2[0];
    out[(size_t)w*2 + 1] = p1 + b2[1];
  }
}

__global__ __launch_bounds__(256) void emb_k(const u16* __restrict__ h, float* __restrict__ out, int n4){
  int i = blockIdx.x*256 + threadIdx.x;
  if (i >= n4) return;
  uint2 v = ((const uint2*)h)[i];
  float4 o;
  o.x = bf2f((u16)(v.x & 0xffffu));
  o.y = bf2f((u16)(v.x >> 16));
  o.z = bf2f((u16)(v.y & 0xffffu));
  o.w = bf2f((u16)(v.y >> 16));
  ((float4*)out)[i] = o;
}

// ---------------- host ----------------

extern "C" void kernel_launch(void* const* d_in, const int* in_sizes, int n_in,
                              void* d_out, int out_size, void* d_ws, size_t ws_size,
                              hipStream_t stream){
  const float* x       = (const float*)d_in[0];
  const int*   ei      = (const int*)d_in[1];
  const float* proj_w  = (const float*)d_in[2];
  const float* proj_b  = (const float*)d_in[3];
  const float* lin_l_w = (const float*)d_in[4];
  const float* lin_l_b = (const float*)d_in[5];
  const float* lin_r_w = (const float*)d_in[6];
  const float* bn_g    = (const float*)d_in[7];
  const float* bn_b    = (const float*)d_in[8];
  const float* fc1_w   = (const float*)d_in[9];
  const float* fc1_b   = (const float*)d_in[10];
  const float* fc2_w   = (const float*)d_in[11];
  const float* fc2_b   = (const float*)d_in[12];
  float* out = (float*)d_out;

  char* ws = (char*)d_ws;
  size_t off = 0;
  auto alloc = [&](size_t b){ size_t o = off; off = (off + b + 255) & ~(size_t)255; return o; };

  u16* bufA    = (u16*)(ws + alloc((size_t)MP*256*2));  // x_bf16 -> agg -> z
  u16* hbuf    = (u16*)(ws + alloc((size_t)MP*256*2));  // h
  u16* bufC    = (u16*)(ws + alloc((size_t)MP*256*2));  // layer gemm out
  uint8_t* h8  = (uint8_t*)(ws + alloc((size_t)MP*256));// fp8 shadow of h
  u16* wp_proj = (u16*)(ws + alloc((size_t)4*16*64*8*2));
  u16* wp_l[3];
  for (int i = 0; i < 3; ++i) wp_l[i] = (u16*)(ws + alloc((size_t)16*16*64*8*2));
  u16* wp_fc1  = (u16*)(ws + alloc((size_t)8*8*64*8*2));
  int* deg   = (int*)(ws + alloc((size_t)NN*4));
  int* cur   = (int*)(ws + alloc((size_t)NN*4));
  int* rp    = (int*)(ws + alloc((size_t)(NN+1)*4));
  int* ci    = (int*)(ws + alloc((size_t)NE*4));
  int* bsum  = (int*)(ws + alloc(512*4));
  int* boff  = (int*)(ws + alloc(512*4));
  int* bcnt  = (int*)(ws + alloc(NBK*4));
  int* bcur  = (int*)(ws + alloc(NBK*4));
  float* bnacc = (float*)(ws + alloc(3*8192*4));
  float* coef  = (float*)(ws + alloc(3*512*4));
  uint2* epair = (uint2*)bufC;   // bufC is dead until first layer gemm
  (void)ws_size; (void)in_sizes; (void)n_in; (void)out_size;

  const int NB = (NN + 255)/256;  // 391
  const int BFB = (NE + EPB - 1)/EPB;  // 782

  zero_k<<<NB, 256, 0, stream>>>(deg, bnacc, bcnt);

  // CSR build (bucketed fill)
  deg_k<<<NE/256, 256, 0, stream>>>(ei, deg);
  bhist_k<<<BFB, 256, 0, stream>>>(ei, bcnt);
  bscan_k<<<1, 512, 0, stream>>>(bcnt, bcur);
  bfill_k<<<BFB, 256, 0, stream>>>(ei, bcur, epair);
  scan1_k<<<NB, 256, 0, stream>>>(deg, bsum);
  scan2_k<<<1, 512, 0, stream>>>(bsum, boff, rp, NB);
  scan3_k<<<NB, 256, 0, stream>>>(deg, boff, rp, cur);
  ffill_k<<<NE/256, 256, 0, stream>>>(epair, cur, ci);

  // weights + input cvt
  cvt_k<<<(NN*INC/4 + 255)/256, 256, 0, stream>>>(x, bufA, NN*INC/4);
  pack_k<<<(128*256 + 255)/256, 256, 0, stream>>>(proj_w, wp_proj, 128, 256, 0);
  for (int i = 0; i < 3; ++i){
    pack_k<<<(256*256 + 255)/256, 256, 0, stream>>>(lin_l_w + (size_t)i*65536, wp_l[i], 256, 256, 0);
    pack_k<<<(256*256 + 255)/256, 256, 0, stream>>>(lin_r_w + (size_t)i*65536, wp_l[i], 256, 256, 8);
  }
  pack_k<<<(256*128 + 255)/256, 256, 0, stream>>>(fc1_w, wp_fc1, 256, 128, 0);

  // proj: h = relu(x @ proj_w + proj_b)   [K=128, NC=256]
  gemm2_k<4,0,256,0><<<dim3(MBLK8,2), 256, 0, stream>>>(bufA, nullptr, wp_proj, proj_b,
                                                        hbuf, NN, nullptr);
  cvt8_k<<<(NN*32 + 255)/256, 256, 0, stream>>>((const uint4*)hbuf, (uint2*)h8, NN*32);

  for (int i = 0; i < 3; ++i){
    if (i < 2)
      agg8_k<<<((NN + 3)/4*64 + 255)/256, 256, 0, stream>>>(rp, ci, (const uint4*)h8, bufA);
    else
      aggb_k<<<(NN + 3)/4, 256, 0, stream>>>(rp, ci, hbuf, bufA);
    // out = agg @ lin_l + b + h @ lin_r   [K=256+256, NC=256] -> bufC
    gemm2_k<8,8,256,1><<<dim3(MBLK8,2), 256, 0, stream>>>(bufA, hbuf, wp_l[i], lin_l_b + (size_t)i*256,
                                                          bufC, NN, bnacc + i*8192);
    bnfin_k<<<1, 256, 0, stream>>>(bnacc + i*8192, bn_g + (size_t)i*256, bn_b + (size_t)i*256, coef + i*512);
    // h8 only needed for layer i+1's fp8 gather (i.e. after layer 0)
    bnapply_k<<<(NN*32 + 255)/256, 256, 0, stream>>>((const uint4*)bufC, (uint4*)hbuf, (uint2*)h8,
                                                     coef + i*512, i, (i == 0) ? 1 : 0);
  }

  // fc1: z = relu(h @ fc1_w + fc1_b)   [K=256, NC=128]
  gemm2_k<8,0,128,0><<<dim3(MBLK8,1), 256, 0, stream>>>(hbuf, nullptr, wp_fc1, fc1_b,
                                                        bufA, NN, nullptr);
  fc2_k<<<(NN + 3)/4, 256, 0, stream>>>(bufA, fc2_w, fc2_b, out);
  emb_k<<<(NN*64 + 255)/256, 256, 0, stream>>>(hbuf, out + 200000, NN*64);
}

// Round 8
// 779.263 us; speedup vs baseline: 1.6081x; 1.1513x over previous
//
#include <hip/hip_runtime.h>
#include <stdint.h>

#define NN 100000      // nodes
#define NE 1600000     // edges
#define INC 128        // in channels
#define HID 256        // hidden
#define MP  100096     // padded rows (64*1564)
#define NBK 391        // dst buckets (dst>>8), 99999>>8 = 390
#define EPB 2048       // edges per bucket-fill block

typedef unsigned short u16;
typedef __attribute__((ext_vector_type(2))) float f32x2;
typedef __attribute__((ext_vector_type(4))) float f32x4;
typedef __attribute__((ext_vector_type(8))) short s16x8;

static __device__ __forceinline__ float bf2f(u16 u){
  union { uint32_t i; float f; } v; v.i = ((uint32_t)u) << 16; return v.f;
}
static __device__ __forceinline__ u16 f2bf(float f){
  union { float f; uint32_t i; } v; v.f = f;
  uint32_t r = v.i + 0x7FFFu + ((v.i >> 16) & 1u);
  return (u16)(r >> 16);
}
static __device__ __forceinline__ void up8(uint4 o, float* v){
  v[0]=bf2f((u16)(o.x&0xffffu)); v[1]=bf2f((u16)(o.x>>16));
  v[2]=bf2f((u16)(o.y&0xffffu)); v[3]=bf2f((u16)(o.y>>16));
  v[4]=bf2f((u16)(o.z&0xffffu)); v[5]=bf2f((u16)(o.z>>16));
  v[6]=bf2f((u16)(o.w&0xffffu)); v[7]=bf2f((u16)(o.w>>16));
}
static __device__ __forceinline__ uint4 pk8(const float* v){
  uint4 o;
  o.x = (uint32_t)f2bf(v[0]) | ((uint32_t)f2bf(v[1])<<16);
  o.y = (uint32_t)f2bf(v[2]) | ((uint32_t)f2bf(v[3])<<16);
  o.z = (uint32_t)f2bf(v[4]) | ((uint32_t)f2bf(v[5])<<16);
  o.w = (uint32_t)f2bf(v[6]) | ((uint32_t)f2bf(v[7])<<16);
  return o;
}
// pack 8 f32 -> 8 fp8 e4m3 (2 u32)
static __device__ __forceinline__ uint2 pkf8(const float* r){
  uint32_t lo = __builtin_amdgcn_cvt_pk_fp8_f32(r[0], r[1], 0u, false);
  lo = __builtin_amdgcn_cvt_pk_fp8_f32(r[2], r[3], lo, true);
  uint32_t hi = __builtin_amdgcn_cvt_pk_fp8_f32(r[4], r[5], 0u, false);
  hi = __builtin_amdgcn_cvt_pk_fp8_f32(r[6], r[7], hi, true);
  return make_uint2(lo, hi);
}

// async global -> LDS, 16B per lane; LDS dest = wave-uniform base + lane*16
static __device__ __forceinline__ void gload16(const void* g, void* l){
  __builtin_amdgcn_global_load_lds((const __attribute__((address_space(1))) void*)g,
                                   (__attribute__((address_space(3))) void*)l, 16, 0, 0);
}

// ---------------- misc small kernels ----------------

__global__ __launch_bounds__(256) void zero_k(float* bnacc, int* bcnt){
  int i = blockIdx.x*256 + threadIdx.x;
  if (i < 3*8192) bnacc[i] = 0.f;
  if (i < NBK) bcnt[i] = 0;
}

__global__ __launch_bounds__(256) void cvt_k(const float* __restrict__ src, u16* __restrict__ dst, int n4){
  int i = blockIdx.x*256 + threadIdx.x;
  if (i >= n4) return;
  float4 v = ((const float4*)src)[i];
  uint2 o;
  o.x = (uint32_t)f2bf(v.x) | ((uint32_t)f2bf(v.y)<<16);
  o.y = (uint32_t)f2bf(v.z) | ((uint32_t)f2bf(v.w)<<16);
  ((uint2*)dst)[i] = o;
}

// bf16 h -> fp8 shadow (8 ch / thread)
__global__ __launch_bounds__(256) void cvt8_k(const uint4* __restrict__ h, uint2* __restrict__ h8, int n){
  int i = blockIdx.x*256 + threadIdx.x;
  if (i >= n) return;
  float v[8];
  up8(h[i], v);
  h8[i] = pkf8(v);
}

// pack W[K][NC] (f32 row-major) into MFMA B-fragment order:
// frag (ks, nt): lane l, elem j  <-  W[ks*32 + (l>>4)*8 + j][nt*16 + (l&15)]
__global__ __launch_bounds__(256) void pack_k(const float* __restrict__ src, u16* __restrict__ dst,
                                              int K, int NC, int ksoff){
  int t = blockIdx.x*256 + threadIdx.x;
  if (t >= K*NC) return;
  int k = t / NC, n = t % NC;
  int NT = NC >> 4;
  int ks = ksoff + (k >> 5);
  int l  = ((k >> 3) & 3)*16 + (n & 15);
  int j  = k & 7;
  dst[((size_t)(ks*NT + (n>>4))*64 + l)*8 + j] = f2bf(src[(size_t)k*NC + n]);
}

// ---------------- CSR build (bucketed, 4 kernels) ----------------

__global__ __launch_bounds__(256) void bhist_k(const int* __restrict__ ei, int* __restrict__ bcnt){
  __shared__ int h[NBK];
  for (int i = threadIdx.x; i < NBK; i += 256) h[i] = 0;
  __syncthreads();
  int e0 = blockIdx.x * EPB;
  #pragma unroll
  for (int j = 0; j < EPB/256; ++j){
    int e = e0 + j*256 + threadIdx.x;
    if (e < NE) atomicAdd(&h[ei[NE + e] >> 8], 1);
  }
  __syncthreads();
  for (int i = threadIdx.x; i < NBK; i += 256)
    if (h[i]) atomicAdd(&bcnt[i], h[i]);
}

__global__ __launch_bounds__(512) void bscan_k(const int* __restrict__ bcnt, int* __restrict__ bcur){
  __shared__ int sd[512];
  int t = threadIdx.x;
  int v = (t < NBK) ? bcnt[t] : 0;
  sd[t] = v; __syncthreads();
  for (int o = 1; o < 512; o <<= 1){
    int x = (t >= o) ? sd[t-o] : 0;
    __syncthreads();
    sd[t] += x;
    __syncthreads();
  }
  if (t < NBK) bcur[t] = sd[t] - v;   // exclusive base, doubles as cursor
}

// per-block counting sort into bucket-grouped (src,dst) pairs
__global__ __launch_bounds__(256) void bfill_k(const int* __restrict__ ei, int* __restrict__ bcur,
                                               uint2* __restrict__ epair){
  __shared__ int cnt[NBK];
  __shared__ int gb[NBK];
  for (int i = threadIdx.x; i < NBK; i += 256) cnt[i] = 0;
  __syncthreads();
  int e0 = blockIdx.x * EPB;
  int srcv[EPB/256], dstv[EPB/256], rnk[EPB/256];
  #pragma unroll
  for (int j = 0; j < EPB/256; ++j){
    int e = e0 + j*256 + threadIdx.x;
    if (e < NE){
      srcv[j] = ei[e];
      dstv[j] = ei[NE + e];
      rnk[j]  = atomicAdd(&cnt[dstv[j] >> 8], 1);
    } else dstv[j] = -1;
  }
  __syncthreads();
  for (int i = threadIdx.x; i < NBK; i += 256){
    int c = cnt[i];
    gb[i] = c ? atomicAdd(&bcur[i], c) : 0;
  }
  __syncthreads();
  #pragma unroll
  for (int j = 0; j < EPB/256; ++j){
    if (dstv[j] >= 0)
      epair[gb[dstv[j] >> 8] + rnk[j]] = make_uint2((unsigned)srcv[j], (unsigned)dstv[j]);
  }
}

// one block per bucket: LDS hist over 256 local dst -> scan -> scatter ci + emit rp.
// Replaces deg + 3 scans + ffill; ci writes land in an L2-local ~16KB window.
__global__ __launch_bounds__(256) void csort_k(const uint2* __restrict__ epair,
                                               const int* __restrict__ bcnt, const int* __restrict__ bcur,
                                               int* __restrict__ ci, int* __restrict__ rp){
  __shared__ int hist[256], pfx[256], cnt2[256];
  int b = blockIdx.x, t = threadIdx.x;
  int cnt  = bcnt[b];
  int base = bcur[b] - cnt;        // bfill advanced bcur to end-of-bucket
  hist[t] = 0; cnt2[t] = 0;
  __syncthreads();
  for (int e = t; e < cnt; e += 256)
    atomicAdd(&hist[epair[base + e].y & 255u], 1);
  __syncthreads();
  int v = hist[t];
  pfx[t] = v;
  __syncthreads();
  for (int o = 1; o < 256; o <<= 1){
    int x = (t >= o) ? pfx[t - o] : 0;
    __syncthreads();
    pfx[t] += x;
    __syncthreads();
  }
  int node = b*256 + t;
  if (node < NN) rp[node] = base + pfx[t] - v;   // exclusive prefix
  if (b == NBK-1 && t == 0) rp[NN] = NE;
  for (int e = t; e < cnt; e += 256){
    uint2 p = epair[base + e];
    int ld = (int)(p.y & 255u);
    int r  = atomicAdd(&cnt2[ld], 1);
    ci[base + pfx[ld] - hist[ld] + r] = (int)p.x;
  }
}

// ---------------- mean aggregation over fp8 shadow: 4 nodes per wave ----------------

__global__ __launch_bounds__(256) void agg8_k(const int* __restrict__ rp, const int* __restrict__ ci,
                                              const uint4* __restrict__ h8, u16* __restrict__ ag){
  int wid  = (int)((blockIdx.x*256u + threadIdx.x) >> 6);
  int lane = threadIdx.x & 63;
  int ql   = lane & 15;
  int w    = wid*4 + (lane >> 4);
  bool act = (w < NN);
  int e0 = 0, e1 = 0;
  if (act){ e0 = rp[w]; e1 = rp[w+1]; }
  int cnt = e1 - e0;

  float a[16];
  #pragma unroll
  for (int k = 0; k < 16; ++k) a[k] = 0.f;

  for (int base = 0; __any(base < cnt); base += 16){
    int rem = cnt - base;
    int my = 0;
    if (ql < rem) my = ci[e0 + base + ql];
    for (int j0 = 0; j0 < 16 && __any(j0 < rem); j0 += 4){
      uint4 v[4];
      #pragma unroll
      for (int jj = 0; jj < 4; ++jj){
        int j = j0 + jj;
        int s = __shfl(my, (lane & 48) + j);
        v[jj] = make_uint4(0,0,0,0);
        if (j < rem) v[jj] = h8[(size_t)s*16 + ql];
      }
      #pragma unroll
      for (int jj = 0; jj < 4; ++jj){
        uint32_t wd[4] = {v[jj].x, v[jj].y, v[jj].z, v[jj].w};
        #pragma unroll
        for (int p = 0; p < 4; ++p){
          f32x2 lo = __builtin_amdgcn_cvt_pk_f32_fp8(wd[p], false);
          f32x2 hi = __builtin_amdgcn_cvt_pk_f32_fp8(wd[p], true);
          a[p*4+0] += lo[0]; a[p*4+1] += lo[1];
          a[p*4+2] += hi[0]; a[p*4+3] += hi[1];
        }
      }
    }
  }

  if (act){
    float inv = 1.0f / (float)(cnt > 0 ? cnt : 1);
    float r0[8], r1[8];
    #pragma unroll
    for (int k = 0; k < 8; ++k){ r0[k] = a[k]*inv; r1[k] = a[8+k]*inv; }
    uint4* agu = (uint4*)ag;
    agu[(size_t)w*32 + ql*2]     = pk8(r0);
    agu[(size_t)w*32 + ql*2 + 1] = pk8(r1);
  }
}

// ---------------- mean aggregation over bf16 h: one wave per node ----------------

__global__ __launch_bounds__(256) void aggb_k(const int* __restrict__ rp, const int* __restrict__ ci,
                                              const u16* __restrict__ h, u16* __restrict__ ag){
  int w = (int)((blockIdx.x*256u + threadIdx.x) >> 6);
  int lane = threadIdx.x & 63;
  if (w >= NN) return;
  int e0 = rp[w], e1 = rp[w+1];
  const uint2* hu = (const uint2*)h;
  float a0=0.f, a1=0.f, a2=0.f, a3=0.f;
  for (int base = e0; base < e1; base += 64){
    int cnt = e1 - base; if (cnt > 64) cnt = 64;
    int my = ci[base + (lane < cnt ? lane : cnt-1)];
    int i = 0;
    for (; i + 4 <= cnt; i += 4){
      int s0 = __builtin_amdgcn_readlane(my, i);
      int s1 = __builtin_amdgcn_readlane(my, i+1);
      int s2 = __builtin_amdgcn_readlane(my, i+2);
      int s3 = __builtin_amdgcn_readlane(my, i+3);
      uint2 v0 = hu[(size_t)s0*64 + lane];
      uint2 v1 = hu[(size_t)s1*64 + lane];
      uint2 v2 = hu[(size_t)s2*64 + lane];
      uint2 v3 = hu[(size_t)s3*64 + lane];
      a0 += bf2f((u16)(v0.x&0xffffu)) + bf2f((u16)(v1.x&0xffffu)) + bf2f((u16)(v2.x&0xffffu)) + bf2f((u16)(v3.x&0xffffu));
      a1 += bf2f((u16)(v0.x>>16))     + bf2f((u16)(v1.x>>16))     + bf2f((u16)(v2.x>>16))     + bf2f((u16)(v3.x>>16));
      a2 += bf2f((u16)(v0.y&0xffffu)) + bf2f((u16)(v1.y&0xffffu)) + bf2f((u16)(v2.y&0xffffu)) + bf2f((u16)(v3.y&0xffffu));
      a3 += bf2f((u16)(v0.y>>16))     + bf2f((u16)(v1.y>>16))     + bf2f((u16)(v2.y>>16))     + bf2f((u16)(v3.y>>16));
    }
    for (; i < cnt; ++i){
      int s0 = __builtin_amdgcn_readlane(my, i);
      uint2 v = hu[(size_t)s0*64 + lane];
      a0 += bf2f((u16)(v.x&0xffffu));
      a1 += bf2f((u16)(v.x>>16));
      a2 += bf2f((u16)(v.y&0xffffu));
      a3 += bf2f((u16)(v.y>>16));
    }
  }
  int d = e1 - e0;
  float inv = 1.0f / (float)(d > 0 ? d : 1);
  uint2 o;
  o.x = (uint32_t)f2bf(a0*inv) | ((uint32_t)f2bf(a1*inv) << 16);
  o.y = (uint32_t)f2bf(a2*inv) | ((uint32_t)f2bf(a3*inv) << 16);
  ((uint2*)ag)[(size_t)w*64 + lane] = o;
}

// ---------------- 2-phase LDS-pipelined MFMA GEMM, tile TR x 128 ----------------
// TR=64: LDS 48KB -> 3 blocks/CU (12 waves/CU, m114 overlap regime).
// 4 waves (2x2), wave owns (TR/2) x 64; MF = TR/32 row-frags.
// EPI 0: relu.  EPI 1: no relu + block-striped BN sum/sumsq atomics.

template<int TR, int KS1, int KS2, int NCC, int EPI>
__global__ __launch_bounds__(256, 3) void gemm2_k(
    const u16* __restrict__ A1, const u16* __restrict__ A2,
    const u16* __restrict__ Wp, const float* __restrict__ bias,
    u16* __restrict__ Cout, int M, float* __restrict__ stS)
{
  constexpr int NT    = NCC >> 4;
  constexpr int MF    = TR / 32;
  constexpr int NS1   = KS1 / 2;           // BK-steps in A1
  constexpr int NSTEP = (KS1 + KS2) / 2;   // total BK-steps

  __shared__ u16 Al[2][TR*64];     // TR*128 B per buffer, [row][64 k] + swizzle
  __shared__ u16 Bl[2][2*8*64*8];  // 16KB per buffer: [slice][nt_local][lane][8]

  const int t    = threadIdx.x;
  const int lane = t & 63;
  const int wv   = t >> 6;
  const int wr   = wv >> 1, wc = wv & 1;
  const int r15  = lane & 15, kg = lane >> 4;
  const int rb   = blockIdx.x * TR;
  const int nh   = blockIdx.y;             // column half (always 0 if NCC==128)
  const int nt0  = nh * 8;

  f32x4 acc[MF][4];
  #pragma unroll
  for (int m = 0; m < MF; ++m)
    #pragma unroll
    for (int n = 0; n < 4; ++n){ f32x4 z = {0.f,0.f,0.f,0.f}; acc[m][n] = z; }

  // ---- staging lambda: one BK-step into dbuf slot bsel ----
  auto stage = [&](int step, int bsel){
    const bool inA1 = (step < NS1);
    const u16* Ab   = inA1 ? A1 : A2;
    const int  Krow = (inA1 ? KS1 : KS2) * 32;         // row length in u16
    const int  kloc = (inA1 ? step : step - NS1) * 64; // k-start (u16)
    #pragma unroll
    for (int c = 0; c < TR/32; ++c){
      int row = c*32 + wv*8 + (lane >> 3);
      int gc  = (lane & 7) ^ (row & 7);                // inverse swizzle on global src
      const u16* g = Ab + (size_t)(rb + row)*Krow + kloc + gc*8;
      gload16(g, &Al[bsel][c*2048 + wv*512]);
    }
    const int s0 = step * 2;                           // global k-slice base in Wp
    #pragma unroll
    for (int c = 0; c < 4; ++c){
      int base = c*4096 + wv*1024;                     // byte offset in Bl buffer
      int sl   = base >> 13;
      int ntl  = (base >> 10) & 7;
      const u16* g = Wp + ((size_t)((s0 + sl)*NT + nt0 + ntl)*64)*8 + lane*8;
      gload16(g, &Bl[bsel][base >> 1]);
    }
  };

  // prologue
  stage(0, 0);
  __syncthreads();   // drains vmcnt

  #pragma unroll
  for (int step = 0; step < NSTEP; ++step){
    const int cur = step & 1;
    if (step + 1 < NSTEP) stage(step + 1, cur ^ 1);

    s16x8 af[2][MF], bf[2][4];
    const char* Ab = (const char*)&Al[cur][0];
    const char* Bb = (const char*)&Bl[cur][0];
    #pragma unroll
    for (int sl = 0; sl < 2; ++sl){
      #pragma unroll
      for (int m = 0; m < MF; ++m){
        int row = wr*(MF*16) + m*16 + r15;
        int c16 = (sl*4 + kg) ^ (row & 7);             // swizzled read
        af[sl][m] = *(const s16x8*)(Ab + row*128 + c16*16);
      }
      #pragma unroll
      for (int n = 0; n < 4; ++n)
        bf[sl][n] = *(const s16x8*)(Bb + sl*8192 + (wc*4 + n)*1024 + lane*16);
    }
    #pragma unroll
    for (int sl = 0; sl < 2; ++sl)
      #pragma unroll
      for (int m = 0; m < MF; ++m)
        #pragma unroll
        for (int n = 0; n < 4; ++n)
          acc[m][n] = __builtin_amdgcn_mfma_f32_16x16x32_bf16(af[sl][m], bf[sl][n], acc[m][n], 0, 0, 0);

    __syncthreads();  // drains staging of step+1 AND closes reads of buf[cur]
  }

  // ---- epilogue ----
  #pragma unroll
  for (int n = 0; n < 4; ++n){
    int col = nh*128 + wc*64 + n*16 + r15;
    float bc = bias[col];
    float s = 0.f, q = 0.f;
    #pragma unroll
    for (int m = 0; m < MF; ++m){
      int rbase = rb + wr*(MF*16) + m*16 + kg*4;
      #pragma unroll
      for (int r = 0; r < 4; ++r){
        int row = rbase + r;
        float val = acc[m][n][r] + bc;
        if (EPI == 0) val = fmaxf(val, 0.f);
        bool ok = row < M;
        if (ok) Cout[(size_t)row*NCC + col] = f2bf(val);
        if (EPI == 1 && ok){ s += val; q += val*val; }
      }
    }
    if (EPI == 1){
      s += __shfl_xor(s, 16); s += __shfl_xor(s, 32);
      q += __shfl_xor(q, 16); q += __shfl_xor(q, 32);
      if (lane < 16){
        int idx = ((blockIdx.x & 15) << 9) + col;   // stripe*512 + col
        atomicAdd(&stS[idx], s);
        atomicAdd(&stS[idx + 256], q);
      }
    }
  }
}

// ---------------- BN finalize + apply ----------------

__global__ __launch_bounds__(256) void bnfin_k(const float* __restrict__ acc,
                                               const float* __restrict__ g, const float* __restrict__ b,
                                               float* __restrict__ coef){
  int c = threadIdx.x;
  float s = 0.f, q = 0.f;
  #pragma unroll
  for (int j = 0; j < 16; ++j){
    s += acc[j*512 + c];
    q += acc[j*512 + 256 + c];
  }
  float mean = s * (1.0f / (float)NN);
  float var  = q * (1.0f / (float)NN) - mean*mean;
  float sc = g[c] * rsqrtf(var + 1e-5f);
  coef[c] = sc;
  coef[256 + c] = b[c] - mean*sc;
}

__global__ __launch_bounds__(256) void bnapply_k(const uint4* __restrict__ outb, uint4* __restrict__ h,
                                                 uint2* __restrict__ h8,
                                                 const float* __restrict__ coef, int layer, int wr8){
  int i = blockIdx.x*256 + threadIdx.x;
  if (i >= NN*32) return;
  int col0 = (i & 31) * 8;
  const float4* scp = (const float4*)(coef + col0);
  const float4* shp = (const float4*)(coef + 256 + col0);
  float4 s0 = scp[0], s1 = scp[1], t0 = shp[0], t1 = shp[1];
  float sc[8] = {s0.x,s0.y,s0.z,s0.w,s1.x,s1.y,s1.z,s1.w};
  float sh[8] = {t0.x,t0.y,t0.z,t0.w,t1.x,t1.y,t1.z,t1.w};
  float v[8], r[8];
  up8(outb[i], v);
  #pragma unroll
  for (int j = 0; j < 8; ++j) r[j] = fmaxf(v[j]*sc[j] + sh[j], 0.f);
  if (layer > 0){
    float hv[8];
    up8(h[i], hv);
    #pragma unroll
    for (int j = 0; j < 8; ++j) r[j] += hv[j];
  }
  h[i] = pk8(r);
  if (wr8) h8[i] = pkf8(r);
}

// ---------------- fc2 logits + embeddings copy-out ----------------

__global__ __launch_bounds__(256) void fc2_k(const u16* __restrict__ z, const float* __restrict__ w2,
                                             const float* __restrict__ b2, float* __restrict__ out){
  int w = (int)((blockIdx.x*256u + threadIdx.x) >> 6);
  int lane = threadIdx.x & 63;
  if (w >= NN) return;
  const uint32_t* zu = (const uint32_t*)(z + (size_t)w*128);
  uint32_t p = zu[lane];
  float z0 = bf2f((u16)(p & 0xffffu));
  float z1 = bf2f((u16)(p >> 16));
  float4 wv = ((const float4*)w2)[lane];
  float p0 = z0*wv.x + z1*wv.z;
  float p1 = z0*wv.y + z1*wv.w;
  #pragma unroll
  for (int off = 1; off < 64; off <<= 1){
    p0 += __shfl_xor(p0, off);
    p1 += __shfl_xor(p1, off);
  }
  if (lane == 0){
    out[(size_t)w*2]     = p0 + b2[0];
    out[(size_t)w*2 + 1] = p1 + b2[1];
  }
}

__global__ __launch_bounds__(256) void emb_k(const u16* __restrict__ h, float* __restrict__ out, int n4){
  int i = blockIdx.x*256 + threadIdx.x;
  if (i >= n4) return;
  uint2 v = ((const uint2*)h)[i];
  float4 o;
  o.x = bf2f((u16)(v.x & 0xffffu));
  o.y = bf2f((u16)(v.x >> 16));
  o.z = bf2f((u16)(v.y & 0xffffu));
  o.w = bf2f((u16)(v.y >> 16));
  ((float4*)out)[i] = o;
}

// ---------------- host ----------------

extern "C" void kernel_launch(void* const* d_in, const int* in_sizes, int n_in,
                              void* d_out, int out_size, void* d_ws, size_t ws_size,
                              hipStream_t stream){
  const float* x       = (const float*)d_in[0];
  const int*   ei      = (const int*)d_in[1];
  const float* proj_w  = (const float*)d_in[2];
  const float* proj_b  = (const float*)d_in[3];
  const float* lin_l_w = (const float*)d_in[4];
  const float* lin_l_b = (const float*)d_in[5];
  const float* lin_r_w = (const float*)d_in[6];
  const float* bn_g    = (const float*)d_in[7];
  const float* bn_b    = (const float*)d_in[8];
  const float* fc1_w   = (const float*)d_in[9];
  const float* fc1_b   = (const float*)d_in[10];
  const float* fc2_w   = (const float*)d_in[11];
  const float* fc2_b   = (const float*)d_in[12];
  float* out = (float*)d_out;

  char* ws = (char*)d_ws;
  size_t off = 0;
  auto alloc = [&](size_t b){ size_t o = off; off = (off + b + 255) & ~(size_t)255; return o; };

  u16* bufA    = (u16*)(ws + alloc((size_t)MP*256*2));  // x_bf16 -> agg -> z
  u16* hbuf    = (u16*)(ws + alloc((size_t)MP*256*2));  // h
  u16* bufC    = (u16*)(ws + alloc((size_t)MP*256*2));  // layer gemm out
  uint8_t* h8  = (uint8_t*)(ws + alloc((size_t)MP*256));// fp8 shadow of h
  u16* wp_proj = (u16*)(ws + alloc((size_t)4*16*64*8*2));
  u16* wp_l[3];
  for (int i = 0; i < 3; ++i) wp_l[i] = (u16*)(ws + alloc((size_t)16*16*64*8*2));
  u16* wp_fc1  = (u16*)(ws + alloc((size_t)8*8*64*8*2));
  int* rp    = (int*)(ws + alloc((size_t)(NN+1)*4));
  int* ci    = (int*)(ws + alloc((size_t)NE*4));
  int* bcnt  = (int*)(ws + alloc(NBK*4));
  int* bcur  = (int*)(ws + alloc(NBK*4));
  float* bnacc = (float*)(ws + alloc(3*8192*4));
  float* coef  = (float*)(ws + alloc(3*512*4));
  uint2* epair = (uint2*)bufC;   // bufC is dead until first layer gemm
  (void)ws_size; (void)in_sizes; (void)n_in; (void)out_size;

  const int BFB = (NE + EPB - 1)/EPB;  // 782
  const int GX = MP/64;                // 1564 row blocks

  zero_k<<<96, 256, 0, stream>>>(bnacc, bcnt);

  // CSR build: hist -> scan -> bucket-grouped pairs -> per-bucket counting sort
  bhist_k<<<BFB, 256, 0, stream>>>(ei, bcnt);
  bscan_k<<<1, 512, 0, stream>>>(bcnt, bcur);
  bfill_k<<<BFB, 256, 0, stream>>>(ei, bcur, epair);
  csort_k<<<NBK, 256, 0, stream>>>(epair, bcnt, bcur, ci, rp);

  // weights + input cvt
  cvt_k<<<(NN*INC/4 + 255)/256, 256, 0, stream>>>(x, bufA, NN*INC/4);
  pack_k<<<(128*256 + 255)/256, 256, 0, stream>>>(proj_w, wp_proj, 128, 256, 0);
  for (int i = 0; i < 3; ++i){
    pack_k<<<(256*256 + 255)/256, 256, 0, stream>>>(lin_l_w + (size_t)i*65536, wp_l[i], 256, 256, 0);
    pack_k<<<(256*256 + 255)/256, 256, 0, stream>>>(lin_r_w + (size_t)i*65536, wp_l[i], 256, 256, 8);
  }
  pack_k<<<(256*128 + 255)/256, 256, 0, stream>>>(fc1_w, wp_fc1, 256, 128, 0);

  // proj: h = relu(x @ proj_w + proj_b)   [K=128, NC=256]
  gemm2_k<64,4,0,256,0><<<dim3(GX,2), 256, 0, stream>>>(bufA, nullptr, wp_proj, proj_b,
                                                        hbuf, NN, nullptr);
  cvt8_k<<<(NN*32 + 255)/256, 256, 0, stream>>>((const uint4*)hbuf, (uint2*)h8, NN*32);

  for (int i = 0; i < 3; ++i){
    if (i < 2)
      agg8_k<<<((NN + 3)/4*64 + 255)/256, 256, 0, stream>>>(rp, ci, (const uint4*)h8, bufA);
    else
      aggb_k<<<(NN + 3)/4, 256, 0, stream>>>(rp, ci, hbuf, bufA);
    // out = agg @ lin_l + b + h @ lin_r   [K=256+256, NC=256] -> bufC
    gemm2_k<64,8,8,256,1><<<dim3(GX,2), 256, 0, stream>>>(bufA, hbuf, wp_l[i], lin_l_b + (size_t)i*256,
                                                          bufC, NN, bnacc + i*8192);
    bnfin_k<<<1, 256, 0, stream>>>(bnacc + i*8192, bn_g + (size_t)i*256, bn_b + (size_t)i*256, coef + i*512);
    // h8 only needed for layer i+1's fp8 gather (i.e. after layer 0)
    bnapply_k<<<(NN*32 + 255)/256, 256, 0, stream>>>((const uint4*)bufC, (uint4*)hbuf, (uint2*)h8,
                                                     coef + i*512, i, (i == 0) ? 1 : 0);
  }

  // fc1: z = relu(h @ fc1_w + fc1_b)   [K=256, NC=128]
  gemm2_k<64,8,0,128,0><<<dim3(GX,1), 256, 0, stream>>>(hbuf, nullptr, wp_fc1, fc1_b,
                                                        bufA, NN, nullptr);
  fc2_k<<<(NN + 3)/4, 256, 0, stream>>>(bufA, fc2_w, fc2_b, out);
  emb_k<<<(NN*64 + 255)/256, 256, 0, stream>>>(hbuf, out + 200000, NN*64);
}

// Round 9
// 692.154 us; speedup vs baseline: 1.8105x; 1.1259x over previous
//
#include <hip/hip_runtime.h>
#include <stdint.h>

#define NN 100000      // nodes
#define NE 1600000     // edges
#define INC 128        // in channels
#define HID 256        // hidden
#define MP  100096     // padded rows (64*1564)
#define NBK 391        // dst buckets (dst>>8), 99999>>8 = 390
#define EPB 2048       // edges per bucket-fill block

typedef unsigned short u16;
typedef __attribute__((ext_vector_type(2))) float f32x2;
typedef __attribute__((ext_vector_type(4))) float f32x4;
typedef __attribute__((ext_vector_type(8))) short s16x8;

static __device__ __forceinline__ float bf2f(u16 u){
  union { uint32_t i; float f; } v; v.i = ((uint32_t)u) << 16; return v.f;
}
static __device__ __forceinline__ u16 f2bf(float f){
  union { float f; uint32_t i; } v; v.f = f;
  uint32_t r = v.i + 0x7FFFu + ((v.i >> 16) & 1u);
  return (u16)(r >> 16);
}
static __device__ __forceinline__ void up8(uint4 o, float* v){
  v[0]=bf2f((u16)(o.x&0xffffu)); v[1]=bf2f((u16)(o.x>>16));
  v[2]=bf2f((u16)(o.y&0xffffu)); v[3]=bf2f((u16)(o.y>>16));
  v[4]=bf2f((u16)(o.z&0xffffu)); v[5]=bf2f((u16)(o.z>>16));
  v[6]=bf2f((u16)(o.w&0xffffu)); v[7]=bf2f((u16)(o.w>>16));
}
static __device__ __forceinline__ uint4 pk8(const float* v){
  uint4 o;
  o.x = (uint32_t)f2bf(v[0]) | ((uint32_t)f2bf(v[1])<<16);
  o.y = (uint32_t)f2bf(v[2]) | ((uint32_t)f2bf(v[3])<<16);
  o.z = (uint32_t)f2bf(v[4]) | ((uint32_t)f2bf(v[5])<<16);
  o.w = (uint32_t)f2bf(v[6]) | ((uint32_t)f2bf(v[7])<<16);
  return o;
}
// pack 8 f32 -> 8 fp8 e4m3 (2 u32)
static __device__ __forceinline__ uint2 pkf8(const float* r){
  uint32_t lo = __builtin_amdgcn_cvt_pk_fp8_f32(r[0], r[1], 0u, false);
  lo = __builtin_amdgcn_cvt_pk_fp8_f32(r[2], r[3], lo, true);
  uint32_t hi = __builtin_amdgcn_cvt_pk_fp8_f32(r[4], r[5], 0u, false);
  hi = __builtin_amdgcn_cvt_pk_fp8_f32(r[6], r[7], hi, true);
  return make_uint2(lo, hi);
}

// async global -> LDS, 16B per lane; LDS dest = wave-uniform base + lane*16
static __device__ __forceinline__ void gload16(const void* g, void* l){
  __builtin_amdgcn_global_load_lds((const __attribute__((address_space(1))) void*)g,
                                   (__attribute__((address_space(3))) void*)l, 16, 0, 0);
}

// ---------------- misc small kernels ----------------

__global__ __launch_bounds__(256) void zero_k(float* bnacc, int* bcnt){
  int i = blockIdx.x*256 + threadIdx.x;
  if (i < 3*8192) bnacc[i] = 0.f;
  if (i < NBK) bcnt[i] = 0;
}

__global__ __launch_bounds__(256) void cvt_k(const float* __restrict__ src, u16* __restrict__ dst, int n4){
  int i = blockIdx.x*256 + threadIdx.x;
  if (i >= n4) return;
  float4 v = ((const float4*)src)[i];
  uint2 o;
  o.x = (uint32_t)f2bf(v.x) | ((uint32_t)f2bf(v.y)<<16);
  o.y = (uint32_t)f2bf(v.z) | ((uint32_t)f2bf(v.w)<<16);
  ((uint2*)dst)[i] = o;
}

// bf16 h -> fp8 shadow (8 ch / thread)
__global__ __launch_bounds__(256) void cvt8_k(const uint4* __restrict__ h, uint2* __restrict__ h8, int n){
  int i = blockIdx.x*256 + threadIdx.x;
  if (i >= n) return;
  float v[8];
  up8(h[i], v);
  h8[i] = pkf8(v);
}

// pack W[K][NC] (f32 row-major) into MFMA B-fragment order:
// frag (ks, nt): lane l, elem j  <-  W[ks*32 + (l>>4)*8 + j][nt*16 + (l&15)]
__global__ __launch_bounds__(256) void pack_k(const float* __restrict__ src, u16* __restrict__ dst,
                                              int K, int NC, int ksoff){
  int t = blockIdx.x*256 + threadIdx.x;
  if (t >= K*NC) return;
  int k = t / NC, n = t % NC;
  int NT = NC >> 4;
  int ks = ksoff + (k >> 5);
  int l  = ((k >> 3) & 3)*16 + (n & 15);
  int j  = k & 7;
  dst[((size_t)(ks*NT + (n>>4))*64 + l)*8 + j] = f2bf(src[(size_t)k*NC + n]);
}

// ---------------- CSR build (bucketed, 4 kernels) ----------------

__global__ __launch_bounds__(256) void bhist_k(const int* __restrict__ ei, int* __restrict__ bcnt){
  __shared__ int h[NBK];
  for (int i = threadIdx.x; i < NBK; i += 256) h[i] = 0;
  __syncthreads();
  int e0 = blockIdx.x * EPB;
  #pragma unroll
  for (int j = 0; j < EPB/256; ++j){
    int e = e0 + j*256 + threadIdx.x;
    if (e < NE) atomicAdd(&h[ei[NE + e] >> 8], 1);
  }
  __syncthreads();
  for (int i = threadIdx.x; i < NBK; i += 256)
    if (h[i]) atomicAdd(&bcnt[i], h[i]);
}

__global__ __launch_bounds__(512) void bscan_k(const int* __restrict__ bcnt, int* __restrict__ bcur){
  __shared__ int sd[512];
  int t = threadIdx.x;
  int v = (t < NBK) ? bcnt[t] : 0;
  sd[t] = v; __syncthreads();
  for (int o = 1; o < 512; o <<= 1){
    int x = (t >= o) ? sd[t-o] : 0;
    __syncthreads();
    sd[t] += x;
    __syncthreads();
  }
  if (t < NBK) bcur[t] = sd[t] - v;   // exclusive base, doubles as cursor
}

// per-block counting sort into bucket-grouped (src,dst) pairs
__global__ __launch_bounds__(256) void bfill_k(const int* __restrict__ ei, int* __restrict__ bcur,
                                               uint2* __restrict__ epair){
  __shared__ int cnt[NBK];
  __shared__ int gb[NBK];
  for (int i = threadIdx.x; i < NBK; i += 256) cnt[i] = 0;
  __syncthreads();
  int e0 = blockIdx.x * EPB;
  int srcv[EPB/256], dstv[EPB/256], rnk[EPB/256];
  #pragma unroll
  for (int j = 0; j < EPB/256; ++j){
    int e = e0 + j*256 + threadIdx.x;
    if (e < NE){
      srcv[j] = ei[e];
      dstv[j] = ei[NE + e];
      rnk[j]  = atomicAdd(&cnt[dstv[j] >> 8], 1);
    } else dstv[j] = -1;
  }
  __syncthreads();
  for (int i = threadIdx.x; i < NBK; i += 256){
    int c = cnt[i];
    gb[i] = c ? atomicAdd(&bcur[i], c) : 0;
  }
  __syncthreads();
  #pragma unroll
  for (int j = 0; j < EPB/256; ++j){
    if (dstv[j] >= 0)
      epair[gb[dstv[j] >> 8] + rnk[j]] = make_uint2((unsigned)srcv[j], (unsigned)dstv[j]);
  }
}

// one block per bucket: LDS hist over 256 local dst -> scan -> scatter ci + emit rp.
__global__ __launch_bounds__(256) void csort_k(const uint2* __restrict__ epair,
                                               const int* __restrict__ bcnt, const int* __restrict__ bcur,
                                               int* __restrict__ ci, int* __restrict__ rp){
  __shared__ int hist[256], pfx[256], cnt2[256];
  int b = blockIdx.x, t = threadIdx.x;
  int cnt  = bcnt[b];
  int base = bcur[b] - cnt;        // bfill advanced bcur to end-of-bucket
  hist[t] = 0; cnt2[t] = 0;
  __syncthreads();
  for (int e = t; e < cnt; e += 256)
    atomicAdd(&hist[epair[base + e].y & 255u], 1);
  __syncthreads();
  int v = hist[t];
  pfx[t] = v;
  __syncthreads();
  for (int o = 1; o < 256; o <<= 1){
    int x = (t >= o) ? pfx[t - o] : 0;
    __syncthreads();
    pfx[t] += x;
    __syncthreads();
  }
  int node = b*256 + t;
  if (node < NN) rp[node] = base + pfx[t] - v;   // exclusive prefix
  if (b == NBK-1 && t == 0) rp[NN] = NE;
  for (int e = t; e < cnt; e += 256){
    uint2 p = epair[base + e];
    int ld = (int)(p.y & 255u);
    int r  = atomicAdd(&cnt2[ld], 1);
    ci[base + pfx[ld] - hist[ld] + r] = (int)p.x;
  }
}

// ---------------- mean aggregation over fp8 shadow: 4 nodes per wave ----------------

__global__ __launch_bounds__(256) void agg8_k(const int* __restrict__ rp, const int* __restrict__ ci,
                                              const uint4* __restrict__ h8, u16* __restrict__ ag){
  int wid  = (int)((blockIdx.x*256u + threadIdx.x) >> 6);
  int lane = threadIdx.x & 63;
  int ql   = lane & 15;
  int w    = wid*4 + (lane >> 4);
  bool act = (w < NN);
  int e0 = 0, e1 = 0;
  if (act){ e0 = rp[w]; e1 = rp[w+1]; }
  int cnt = e1 - e0;

  float a[16];
  #pragma unroll
  for (int k = 0; k < 16; ++k) a[k] = 0.f;

  for (int base = 0; __any(base < cnt); base += 16){
    int rem = cnt - base;
    int my = 0;
    if (ql < rem) my = ci[e0 + base + ql];
    for (int j0 = 0; j0 < 16 && __any(j0 < rem); j0 += 4){
      uint4 v[4];
      #pragma unroll
      for (int jj = 0; jj < 4; ++jj){
        int j = j0 + jj;
        int s = __shfl(my, (lane & 48) + j);
        v[jj] = make_uint4(0,0,0,0);
        if (j < rem) v[jj] = h8[(size_t)s*16 + ql];
      }
      #pragma unroll
      for (int jj = 0; jj < 4; ++jj){
        uint32_t wd[4] = {v[jj].x, v[jj].y, v[jj].z, v[jj].w};
        #pragma unroll
        for (int p = 0; p < 4; ++p){
          f32x2 lo = __builtin_amdgcn_cvt_pk_f32_fp8(wd[p], false);
          f32x2 hi = __builtin_amdgcn_cvt_pk_f32_fp8(wd[p], true);
          a[p*4+0] += lo[0]; a[p*4+1] += lo[1];
          a[p*4+2] += hi[0]; a[p*4+3] += hi[1];
        }
      }
    }
  }

  if (act){
    float inv = 1.0f / (float)(cnt > 0 ? cnt : 1);
    float r0[8], r1[8];
    #pragma unroll
    for (int k = 0; k < 8; ++k){ r0[k] = a[k]*inv; r1[k] = a[8+k]*inv; }
    uint4* agu = (uint4*)ag;
    agu[(size_t)w*32 + ql*2]     = pk8(r0);
    agu[(size_t)w*32 + ql*2 + 1] = pk8(r1);
  }
}

// ---------------- mean aggregation over bf16 h: one wave per node ----------------

__global__ __launch_bounds__(256) void aggb_k(const int* __restrict__ rp, const int* __restrict__ ci,
                                              const u16* __restrict__ h, u16* __restrict__ ag){
  int w = (int)((blockIdx.x*256u + threadIdx.x) >> 6);
  int lane = threadIdx.x & 63;
  if (w >= NN) return;
  int e0 = rp[w], e1 = rp[w+1];
  const uint2* hu = (const uint2*)h;
  float a0=0.f, a1=0.f, a2=0.f, a3=0.f;
  for (int base = e0; base < e1; base += 64){
    int cnt = e1 - base; if (cnt > 64) cnt = 64;
    int my = ci[base + (lane < cnt ? lane : cnt-1)];
    int i = 0;
    for (; i + 4 <= cnt; i += 4){
      int s0 = __builtin_amdgcn_readlane(my, i);
      int s1 = __builtin_amdgcn_readlane(my, i+1);
      int s2 = __builtin_amdgcn_readlane(my, i+2);
      int s3 = __builtin_amdgcn_readlane(my, i+3);
      uint2 v0 = hu[(size_t)s0*64 + lane];
      uint2 v1 = hu[(size_t)s1*64 + lane];
      uint2 v2 = hu[(size_t)s2*64 + lane];
      uint2 v3 = hu[(size_t)s3*64 + lane];
      a0 += bf2f((u16)(v0.x&0xffffu)) + bf2f((u16)(v1.x&0xffffu)) + bf2f((u16)(v2.x&0xffffu)) + bf2f((u16)(v3.x&0xffffu));
      a1 += bf2f((u16)(v0.x>>16))     + bf2f((u16)(v1.x>>16))     + bf2f((u16)(v2.x>>16))     + bf2f((u16)(v3.x>>16));
      a2 += bf2f((u16)(v0.y&0xffffu)) + bf2f((u16)(v1.y&0xffffu)) + bf2f((u16)(v2.y&0xffffu)) + bf2f((u16)(v3.y&0xffffu));
      a3 += bf2f((u16)(v0.y>>16))     + bf2f((u16)(v1.y>>16))     + bf2f((u16)(v2.y>>16))     + bf2f((u16)(v3.y>>16));
    }
    for (; i < cnt; ++i){
      int s0 = __builtin_amdgcn_readlane(my, i);
      uint2 v = hu[(size_t)s0*64 + lane];
      a0 += bf2f((u16)(v.x&0xffffu));
      a1 += bf2f((u16)(v.x>>16));
      a2 += bf2f((u16)(v.y&0xffffu));
      a3 += bf2f((u16)(v.y>>16));
    }
  }
  int d = e1 - e0;
  float inv = 1.0f / (float)(d > 0 ? d : 1);
  uint2 o;
  o.x = (uint32_t)f2bf(a0*inv) | ((uint32_t)f2bf(a1*inv) << 16);
  o.y = (uint32_t)f2bf(a2*inv) | ((uint32_t)f2bf(a3*inv) << 16);
  ((uint2*)ag)[(size_t)w*64 + lane] = o;
}

// ---------------- MFMA GEMM v3: A-only LDS, B direct from L2 ----------------
// C[M,NCC] = [A1 | A2] @ Wpacked + bias.  Block = 64 rows x NCC cols, 4 waves
// (1x4 col split, wave = 64 x NCC/4).  A double-buffered in LDS (16KB, XOR
// swizzle) via global_load_lds; B fragments read straight from the packed
// (L2-resident) weights with a 1-slice register prefetch bb[2][NFRAG].
// EPI 0: relu.  EPI 1: no relu + block-striped BN sum/sumsq atomics.

template<int KS1, int KS2, int NCC, int EPI>
__global__ __launch_bounds__(256, 3) void gemm3_k(
    const u16* __restrict__ A1, const u16* __restrict__ A2,
    const u16* __restrict__ Wp, const float* __restrict__ bias,
    u16* __restrict__ Cout, int M, float* __restrict__ stS)
{
  constexpr int NT    = NCC >> 4;
  constexpr int NFRAG = NCC / 64;          // frags per wave (4 or 2)
  constexpr int NS1   = KS1 / 2;           // BK-steps in A1
  constexpr int NSTEP = (KS1 + KS2) / 2;   // total BK-steps (BK=64)

  __shared__ u16 Al[2][64*64];             // 8KB per buffer: [row][64 k] + swizzle

  const int t    = threadIdx.x;
  const int lane = t & 63;
  const int wv   = t >> 6;
  const int r15  = lane & 15, kg = lane >> 4;
  const int rb   = blockIdx.x * 64;
  const int nt0w = wv * NFRAG;             // wave's first 16-col tile

  f32x4 acc[4][NFRAG];
  #pragma unroll
  for (int m = 0; m < 4; ++m)
    #pragma unroll
    for (int n = 0; n < NFRAG; ++n){ f32x4 z = {0.f,0.f,0.f,0.f}; acc[m][n] = z; }

  // stage one BK-step of A into dbuf slot bsel (8 rows per gload16 issue)
  auto stageA = [&](int step, int bsel){
    const bool inA1 = (step < NS1);
    const u16* Ab   = inA1 ? A1 : A2;
    const int  Krow = (inA1 ? KS1 : KS2) * 32;
    const int  kloc = (inA1 ? step : step - NS1) * 64;
    #pragma unroll
    for (int c = 0; c < 2; ++c){
      int row = c*32 + wv*8 + (lane >> 3);
      int gc  = (lane & 7) ^ (row & 7);              // inverse swizzle on global src
      const u16* g = Ab + (size_t)(rb + row)*Krow + kloc + gc*8;
      gload16(g, &Al[bsel][c*2048 + wv*512]);
    }
  };
  // load B fragments for global k-slice ss into dst[NFRAG]
  auto loadB = [&](int ss, s16x8* dst){
    const u16* g = Wp + ((size_t)(ss*NT + nt0w)*64 + lane)*8;
    #pragma unroll
    for (int n = 0; n < NFRAG; ++n)
      dst[n] = *(const s16x8*)(g + (size_t)n*512);
  };

  s16x8 bb[2][NFRAG];
  stageA(0, 0);
  loadB(0, bb[0]);
  __syncthreads();   // drains vmcnt (A staging of step 0)

  #pragma unroll
  for (int step = 0; step < NSTEP; ++step){
    const int cur = step & 1;
    if (step + 1 < NSTEP) stageA(step + 1, cur ^ 1);
    #pragma unroll
    for (int sl = 0; sl < 2; ++sl){
      const int ss = step*2 + sl;
      const int p  = ss & 1;
      if (ss + 1 < NSTEP*2) loadB(ss + 1, bb[p ^ 1]);
      s16x8 af[4];
      const char* Ab = (const char*)&Al[cur][0];
      #pragma unroll
      for (int m = 0; m < 4; ++m){
        int row = m*16 + r15;
        int c16 = (sl*4 + kg) ^ (row & 7);           // swizzled read
        af[m] = *(const s16x8*)(Ab + row*128 + c16*16);
      }
      #pragma unroll
      for (int m = 0; m < 4; ++m)
        #pragma unroll
        for (int n = 0; n < NFRAG; ++n)
          acc[m][n] = __builtin_amdgcn_mfma_f32_16x16x32_bf16(af[m], bb[p][n], acc[m][n], 0, 0, 0);
    }
    __syncthreads();  // closes reads of Al[cur]; drains staging of step+1
  }

  // ---- epilogue ----
  #pragma unroll
  for (int n = 0; n < NFRAG; ++n){
    int col = (nt0w + n)*16 + r15;
    float bc = bias[col];
    float s = 0.f, q = 0.f;
    #pragma unroll
    for (int m = 0; m < 4; ++m){
      int rbase = rb + m*16 + kg*4;
      #pragma unroll
      for (int r = 0; r < 4; ++r){
        int row = rbase + r;
        float val = acc[m][n][r] + bc;
        if (EPI == 0) val = fmaxf(val, 0.f);
        bool ok = row < M;
        if (ok) Cout[(size_t)row*NCC + col] = f2bf(val);
        if (EPI == 1 && ok){ s += val; q += val*val; }
      }
    }
    if (EPI == 1){
      s += __shfl_xor(s, 16); s += __shfl_xor(s, 32);
      q += __shfl_xor(q, 16); q += __shfl_xor(q, 32);
      if (lane < 16){
        int idx = ((blockIdx.x & 15) << 9) + col;   // stripe*512 + col
        atomicAdd(&stS[idx], s);
        atomicAdd(&stS[idx + 256], q);
      }
    }
  }
}

// ---------------- BN finalize + apply ----------------

__global__ __launch_bounds__(256) void bnfin_k(const float* __restrict__ acc,
                                               const float* __restrict__ g, const float* __restrict__ b,
                                               float* __restrict__ coef){
  int c = threadIdx.x;
  float s = 0.f, q = 0.f;
  #pragma unroll
  for (int j = 0; j < 16; ++j){
    s += acc[j*512 + c];
    q += acc[j*512 + 256 + c];
  }
  float mean = s * (1.0f / (float)NN);
  float var  = q * (1.0f / (float)NN) - mean*mean;
  float sc = g[c] * rsqrtf(var + 1e-5f);
  coef[c] = sc;
  coef[256 + c] = b[c] - mean*sc;
}

__global__ __launch_bounds__(256) void bnapply_k(const uint4* __restrict__ outb, uint4* __restrict__ h,
                                                 uint2* __restrict__ h8,
                                                 const float* __restrict__ coef, int layer, int wr8){
  int i = blockIdx.x*256 + threadIdx.x;
  if (i >= NN*32) return;
  int col0 = (i & 31) * 8;
  const float4* scp = (const float4*)(coef + col0);
  const float4* shp = (const float4*)(coef + 256 + col0);
  float4 s0 = scp[0], s1 = scp[1], t0 = shp[0], t1 = shp[1];
  float sc[8] = {s0.x,s0.y,s0.z,s0.w,s1.x,s1.y,s1.z,s1.w};
  float sh[8] = {t0.x,t0.y,t0.z,t0.w,t1.x,t1.y,t1.z,t1.w};
  float v[8], r[8];
  up8(outb[i], v);
  #pragma unroll
  for (int j = 0; j < 8; ++j) r[j] = fmaxf(v[j]*sc[j] + sh[j], 0.f);
  if (layer > 0){
    float hv[8];
    up8(h[i], hv);
    #pragma unroll
    for (int j = 0; j < 8; ++j) r[j] += hv[j];
  }
  h[i] = pk8(r);
  if (wr8) h8[i] = pkf8(r);
}

// ---------------- fc2 logits + embeddings copy-out ----------------

__global__ __launch_bounds__(256) void fc2_k(const u16* __restrict__ z, const float* __restrict__ w2,
                                             const float* __restrict__ b2, float* __restrict__ out){
  int w = (int)((blockIdx.x*256u + threadIdx.x) >> 6);
  int lane = threadIdx.x & 63;
  if (w >= NN) return;
  const uint32_t* zu = (const uint32_t*)(z + (size_t)w*128);
  uint32_t p = zu[lane];
  float z0 = bf2f((u16)(p & 0xffffu));
  float z1 = bf2f((u16)(p >> 16));
  float4 wv = ((const float4*)w2)[lane];
  float p0 = z0*wv.x + z1*wv.z;
  float p1 = z0*wv.y + z1*wv.w;
  #pragma unroll
  for (int off = 1; off < 64; off <<= 1){
    p0 += __shfl_xor(p0, off);
    p1 += __shfl_xor(p1, off);
  }
  if (lane == 0){
    out[(size_t)w*2]     = p0 + b2[0];
    out[(size_t)w*2 + 1] = p1 + b2[1];
  }
}

__global__ __launch_bounds__(256) void emb_k(const u16* __restrict__ h, float* __restrict__ out, int n4){
  int i = blockIdx.x*256 + threadIdx.x;
  if (i >= n4) return;
  uint2 v = ((const uint2*)h)[i];
  float4 o;
  o.x = bf2f((u16)(v.x & 0xffffu));
  o.y = bf2f((u16)(v.x >> 16));
  o.z = bf2f((u16)(v.y & 0xffffu));
  o.w = bf2f((u16)(v.y >> 16));
  ((float4*)out)[i] = o;
}

// ---------------- host ----------------

extern "C" void kernel_launch(void* const* d_in, const int* in_sizes, int n_in,
                              void* d_out, int out_size, void* d_ws, size_t ws_size,
                              hipStream_t stream){
  const float* x       = (const float*)d_in[0];
  const int*   ei      = (const int*)d_in[1];
  const float* proj_w  = (const float*)d_in[2];
  const float* proj_b  = (const float*)d_in[3];
  const float* lin_l_w = (const float*)d_in[4];
  const float* lin_l_b = (const float*)d_in[5];
  const float* lin_r_w = (const float*)d_in[6];
  const float* bn_g    = (const float*)d_in[7];
  const float* bn_b    = (const float*)d_in[8];
  const float* fc1_w   = (const float*)d_in[9];
  const float* fc1_b   = (const float*)d_in[10];
  const float* fc2_w   = (const float*)d_in[11];
  const float* fc2_b   = (const float*)d_in[12];
  float* out = (float*)d_out;

  char* ws = (char*)d_ws;
  size_t off = 0;
  auto alloc = [&](size_t b){ size_t o = off; off = (off + b + 255) & ~(size_t)255; return o; };

  u16* bufA    = (u16*)(ws + alloc((size_t)MP*256*2));  // x_bf16 -> agg -> z
  u16* hbuf    = (u16*)(ws + alloc((size_t)MP*256*2));  // h
  u16* bufC    = (u16*)(ws + alloc((size_t)MP*256*2));  // layer gemm out
  uint8_t* h8  = (uint8_t*)(ws + alloc((size_t)MP*256));// fp8 shadow of h
  u16* wp_proj = (u16*)(ws + alloc((size_t)4*16*64*8*2));
  u16* wp_l[3];
  for (int i = 0; i < 3; ++i) wp_l[i] = (u16*)(ws + alloc((size_t)16*16*64*8*2));
  u16* wp_fc1  = (u16*)(ws + alloc((size_t)8*8*64*8*2));
  int* rp    = (int*)(ws + alloc((size_t)(NN+1)*4));
  int* ci    = (int*)(ws + alloc((size_t)NE*4));
  int* bcnt  = (int*)(ws + alloc(NBK*4));
  int* bcur  = (int*)(ws + alloc(NBK*4));
  float* bnacc = (float*)(ws + alloc(3*8192*4));
  float* coef  = (float*)(ws + alloc(3*512*4));
  uint2* epair = (uint2*)bufC;   // bufC is dead until first layer gemm
  (void)ws_size; (void)in_sizes; (void)n_in; (void)out_size;

  const int BFB = (NE + EPB - 1)/EPB;  // 782
  const int GX = MP/64;                // 1564 row blocks

  zero_k<<<96, 256, 0, stream>>>(bnacc, bcnt);

  // CSR build: hist -> scan -> bucket-grouped pairs -> per-bucket counting sort
  bhist_k<<<BFB, 256, 0, stream>>>(ei, bcnt);
  bscan_k<<<1, 512, 0, stream>>>(bcnt, bcur);
  bfill_k<<<BFB, 256, 0, stream>>>(ei, bcur, epair);
  csort_k<<<NBK, 256, 0, stream>>>(epair, bcnt, bcur, ci, rp);

  // weights + input cvt
  cvt_k<<<(NN*INC/4 + 255)/256, 256, 0, stream>>>(x, bufA, NN*INC/4);
  pack_k<<<(128*256 + 255)/256, 256, 0, stream>>>(proj_w, wp_proj, 128, 256, 0);
  for (int i = 0; i < 3; ++i){
    pack_k<<<(256*256 + 255)/256, 256, 0, stream>>>(lin_l_w + (size_t)i*65536, wp_l[i], 256, 256, 0);
    pack_k<<<(256*256 + 255)/256, 256, 0, stream>>>(lin_r_w + (size_t)i*65536, wp_l[i], 256, 256, 8);
  }
  pack_k<<<(256*128 + 255)/256, 256, 0, stream>>>(fc1_w, wp_fc1, 256, 128, 0);

  // proj: h = relu(x @ proj_w + proj_b)   [K=128, NC=256]
  gemm3_k<4,0,256,0><<<GX, 256, 0, stream>>>(bufA, nullptr, wp_proj, proj_b,
                                             hbuf, NN, nullptr);
  cvt8_k<<<(NN*32 + 255)/256, 256, 0, stream>>>((const uint4*)hbuf, (uint2*)h8, NN*32);

  for (int i = 0; i < 3; ++i){
    if (i < 2)
      agg8_k<<<((NN + 3)/4*64 + 255)/256, 256, 0, stream>>>(rp, ci, (const uint4*)h8, bufA);
    else
      aggb_k<<<(NN + 3)/4, 256, 0, stream>>>(rp, ci, hbuf, bufA);
    // out = agg @ lin_l + b + h @ lin_r   [K=256+256, NC=256] -> bufC
    gemm3_k<8,8,256,1><<<GX, 256, 0, stream>>>(bufA, hbuf, wp_l[i], lin_l_b + (size_t)i*256,
                                               bufC, NN, bnacc + i*8192);
    bnfin_k<<<1, 256, 0, stream>>>(bnacc + i*8192, bn_g + (size_t)i*256, bn_b + (size_t)i*256, coef + i*512);
    // h8 only needed for layer i+1's fp8 gather (i.e. after layer 0)
    bnapply_k<<<(NN*32 + 255)/256, 256, 0, stream>>>((const uint4*)bufC, (uint4*)hbuf, (uint2*)h8,
                                                     coef + i*512, i, (i == 0) ? 1 : 0);
  }

  // fc1: z = relu(h @ fc1_w + fc1_b)   [K=256, NC=128]
  gemm3_k<8,0,128,0><<<GX, 256, 0, stream>>>(hbuf, nullptr, wp_fc1, fc1_b,
                                             bufA, NN, nullptr);
  fc2_k<<<(NN + 3)/4, 256, 0, stream>>>(bufA, fc2_w, fc2_b, out);
  emb_k<<<(NN*64 + 255)/256, 256, 0, stream>>>(hbuf, out + 200000, NN*64);
}

// Round 10
// 689.070 us; speedup vs baseline: 1.8186x; 1.0045x over previous
//
#include <hip/hip_runtime.h>
#include <stdint.h>

#define NN 100000      // nodes
#define NE 1600000     // edges
#define INC 128        // in channels
#define HID 256        // hidden
#define MP  100096     // padded rows (64*1564)
#define NBK 391        // dst buckets (dst>>8), 99999>>8 = 390
#define EPB 2048       // edges per bucket-fill block

typedef unsigned short u16;
typedef __attribute__((ext_vector_type(2))) float f32x2;
typedef __attribute__((ext_vector_type(4))) float f32x4;
typedef __attribute__((ext_vector_type(8))) short s16x8;

static __device__ __forceinline__ float bf2f(u16 u){
  union { uint32_t i; float f; } v; v.i = ((uint32_t)u) << 16; return v.f;
}
static __device__ __forceinline__ u16 f2bf(float f){
  union { float f; uint32_t i; } v; v.f = f;
  uint32_t r = v.i + 0x7FFFu + ((v.i >> 16) & 1u);
  return (u16)(r >> 16);
}
static __device__ __forceinline__ void up8(uint4 o, float* v){
  v[0]=bf2f((u16)(o.x&0xffffu)); v[1]=bf2f((u16)(o.x>>16));
  v[2]=bf2f((u16)(o.y&0xffffu)); v[3]=bf2f((u16)(o.y>>16));
  v[4]=bf2f((u16)(o.z&0xffffu)); v[5]=bf2f((u16)(o.z>>16));
  v[6]=bf2f((u16)(o.w&0xffffu)); v[7]=bf2f((u16)(o.w>>16));
}
static __device__ __forceinline__ uint4 pk8(const float* v){
  uint4 o;
  o.x = (uint32_t)f2bf(v[0]) | ((uint32_t)f2bf(v[1])<<16);
  o.y = (uint32_t)f2bf(v[2]) | ((uint32_t)f2bf(v[3])<<16);
  o.z = (uint32_t)f2bf(v[4]) | ((uint32_t)f2bf(v[5])<<16);
  o.w = (uint32_t)f2bf(v[6]) | ((uint32_t)f2bf(v[7])<<16);
  return o;
}
// pack 8 f32 -> 8 fp8 e4m3 (2 u32)
static __device__ __forceinline__ uint2 pkf8(const float* r){
  uint32_t lo = __builtin_amdgcn_cvt_pk_fp8_f32(r[0], r[1], 0u, false);
  lo = __builtin_amdgcn_cvt_pk_fp8_f32(r[2], r[3], lo, true);
  uint32_t hi = __builtin_amdgcn_cvt_pk_fp8_f32(r[4], r[5], 0u, false);
  hi = __builtin_amdgcn_cvt_pk_fp8_f32(r[6], r[7], hi, true);
  return make_uint2(lo, hi);
}

// async global -> LDS, 16B per lane; LDS dest = wave-uniform base + lane*16
static __device__ __forceinline__ void gload16(const void* g, void* l){
  __builtin_amdgcn_global_load_lds((const __attribute__((address_space(1))) void*)g,
                                   (__attribute__((address_space(3))) void*)l, 16, 0, 0);
}

// ---------------- misc small kernels ----------------

__global__ __launch_bounds__(256) void zero_k(float* bnacc, int* bcnt){
  int i = blockIdx.x*256 + threadIdx.x;
  if (i < 3*8192) bnacc[i] = 0.f;
  if (i < NBK) bcnt[i] = 0;
}

__global__ __launch_bounds__(256) void cvt_k(const float* __restrict__ src, u16* __restrict__ dst, int n4){
  int i = blockIdx.x*256 + threadIdx.x;
  if (i >= n4) return;
  float4 v = ((const float4*)src)[i];
  uint2 o;
  o.x = (uint32_t)f2bf(v.x) | ((uint32_t)f2bf(v.y)<<16);
  o.y = (uint32_t)f2bf(v.z) | ((uint32_t)f2bf(v.w)<<16);
  ((uint2*)dst)[i] = o;
}

// bf16 h -> fp8 shadow (8 ch / thread)
__global__ __launch_bounds__(256) void cvt8_k(const uint4* __restrict__ h, uint2* __restrict__ h8, int n){
  int i = blockIdx.x*256 + threadIdx.x;
  if (i >= n) return;
  float v[8];
  up8(h[i], v);
  h8[i] = pkf8(v);
}

// pack W[K][NC] (f32 row-major) into MFMA B-fragment order:
// frag (ks, nt): lane l, elem j  <-  W[ks*32 + (l>>4)*8 + j][nt*16 + (l&15)]
__global__ __launch_bounds__(256) void pack_k(const float* __restrict__ src, u16* __restrict__ dst,
                                              int K, int NC, int ksoff){
  int t = blockIdx.x*256 + threadIdx.x;
  if (t >= K*NC) return;
  int k = t / NC, n = t % NC;
  int NT = NC >> 4;
  int ks = ksoff + (k >> 5);
  int l  = ((k >> 3) & 3)*16 + (n & 15);
  int j  = k & 7;
  dst[((size_t)(ks*NT + (n>>4))*64 + l)*8 + j] = f2bf(src[(size_t)k*NC + n]);
}

// ---------------- CSR build (bucketed, 4 kernels; epair packed u32) ----------------

__global__ __launch_bounds__(256) void bhist_k(const int* __restrict__ ei, int* __restrict__ bcnt){
  __shared__ int h[NBK];
  for (int i = threadIdx.x; i < NBK; i += 256) h[i] = 0;
  __syncthreads();
  int e0 = blockIdx.x * EPB;
  #pragma unroll
  for (int j = 0; j < EPB/256; ++j){
    int e = e0 + j*256 + threadIdx.x;
    if (e < NE) atomicAdd(&h[ei[NE + e] >> 8], 1);
  }
  __syncthreads();
  for (int i = threadIdx.x; i < NBK; i += 256)
    if (h[i]) atomicAdd(&bcnt[i], h[i]);
}

__global__ __launch_bounds__(512) void bscan_k(const int* __restrict__ bcnt, int* __restrict__ bcur){
  __shared__ int sd[512];
  int t = threadIdx.x;
  int v = (t < NBK) ? bcnt[t] : 0;
  sd[t] = v; __syncthreads();
  for (int o = 1; o < 512; o <<= 1){
    int x = (t >= o) ? sd[t-o] : 0;
    __syncthreads();
    sd[t] += x;
    __syncthreads();
  }
  if (t < NBK) bcur[t] = sd[t] - v;   // exclusive base, doubles as cursor
}

// per-block counting sort into bucket-grouped packed edges: (src<<8)|dst_local
__global__ __launch_bounds__(256) void bfill_k(const int* __restrict__ ei, int* __restrict__ bcur,
                                               unsigned* __restrict__ epair){
  __shared__ int cnt[NBK];
  __shared__ int gb[NBK];
  for (int i = threadIdx.x; i < NBK; i += 256) cnt[i] = 0;
  __syncthreads();
  int e0 = blockIdx.x * EPB;
  unsigned pk[EPB/256];
  int bkt[EPB/256], rnk[EPB/256];
  #pragma unroll
  for (int j = 0; j < EPB/256; ++j){
    int e = e0 + j*256 + threadIdx.x;
    if (e < NE){
      int s = ei[e];
      int d = ei[NE + e];
      bkt[j] = d >> 8;
      pk[j]  = ((unsigned)s << 8) | (unsigned)(d & 255);
      rnk[j] = atomicAdd(&cnt[bkt[j]], 1);
    } else bkt[j] = -1;
  }
  __syncthreads();
  for (int i = threadIdx.x; i < NBK; i += 256){
    int c = cnt[i];
    gb[i] = c ? atomicAdd(&bcur[i], c) : 0;
  }
  __syncthreads();
  #pragma unroll
  for (int j = 0; j < EPB/256; ++j){
    if (bkt[j] >= 0)
      epair[gb[bkt[j]] + rnk[j]] = pk[j];
  }
}

// one block per bucket: LDS hist over 256 local dst -> scan -> scatter ci + emit rp.
__global__ __launch_bounds__(256) void csort_k(const unsigned* __restrict__ epair,
                                               const int* __restrict__ bcnt, const int* __restrict__ bcur,
                                               int* __restrict__ ci, int* __restrict__ rp){
  __shared__ int hist[256], pfx[256], cnt2[256];
  int b = blockIdx.x, t = threadIdx.x;
  int cnt  = bcnt[b];
  int base = bcur[b] - cnt;        // bfill advanced bcur to end-of-bucket
  hist[t] = 0; cnt2[t] = 0;
  __syncthreads();
  for (int e = t; e < cnt; e += 256)
    atomicAdd(&hist[epair[base + e] & 255u], 1);
  __syncthreads();
  int v = hist[t];
  pfx[t] = v;
  __syncthreads();
  for (int o = 1; o < 256; o <<= 1){
    int x = (t >= o) ? pfx[t - o] : 0;
    __syncthreads();
    pfx[t] += x;
    __syncthreads();
  }
  int node = b*256 + t;
  if (node < NN) rp[node] = base + pfx[t] - v;   // exclusive prefix
  if (b == NBK-1 && t == 0) rp[NN] = NE;
  for (int e = t; e < cnt; e += 256){
    unsigned p = epair[base + e];
    int ld = (int)(p & 255u);
    int r  = atomicAdd(&cnt2[ld], 1);
    ci[base + pfx[ld] - hist[ld] + r] = (int)(p >> 8);
  }
}

// ---------------- mean aggregation over fp8 shadow: 4 nodes per wave, 8-deep MLP ----

__global__ __launch_bounds__(256) void agg8_k(const int* __restrict__ rp, const int* __restrict__ ci,
                                              const uint4* __restrict__ h8, u16* __restrict__ ag){
  int wid  = (int)((blockIdx.x*256u + threadIdx.x) >> 6);
  int lane = threadIdx.x & 63;
  int ql   = lane & 15;
  int w    = wid*4 + (lane >> 4);
  bool act = (w < NN);
  int e0 = 0, e1 = 0;
  if (act){ e0 = rp[w]; e1 = rp[w+1]; }
  int cnt = e1 - e0;

  float a[16];
  #pragma unroll
  for (int k = 0; k < 16; ++k) a[k] = 0.f;

  for (int base = 0; __any(base < cnt); base += 16){
    int rem = cnt - base;
    int my = 0;
    if (ql < rem) my = ci[e0 + base + ql];
    #pragma unroll
    for (int j0 = 0; j0 < 16; j0 += 8){
      if (!__any(j0 < rem)) break;
      uint4 v[8];
      #pragma unroll
      for (int jj = 0; jj < 8; ++jj){
        int j = j0 + jj;
        int s = __shfl(my, (lane & 48) + j);
        v[jj] = make_uint4(0,0,0,0);
        if (j < rem) v[jj] = h8[(size_t)s*16 + ql];
      }
      #pragma unroll
      for (int jj = 0; jj < 8; ++jj){
        uint32_t wd[4] = {v[jj].x, v[jj].y, v[jj].z, v[jj].w};
        #pragma unroll
        for (int p = 0; p < 4; ++p){
          f32x2 lo = __builtin_amdgcn_cvt_pk_f32_fp8(wd[p], false);
          f32x2 hi = __builtin_amdgcn_cvt_pk_f32_fp8(wd[p], true);
          a[p*4+0] += lo[0]; a[p*4+1] += lo[1];
          a[p*4+2] += hi[0]; a[p*4+3] += hi[1];
        }
      }
    }
  }

  if (act){
    float inv = 1.0f / (float)(cnt > 0 ? cnt : 1);
    float r0[8], r1[8];
    #pragma unroll
    for (int k = 0; k < 8; ++k){ r0[k] = a[k]*inv; r1[k] = a[8+k]*inv; }
    uint4* agu = (uint4*)ag;
    agu[(size_t)w*32 + ql*2]     = pk8(r0);
    agu[(size_t)w*32 + ql*2 + 1] = pk8(r1);
  }
}

// ---------------- mean aggregation over bf16 h: one wave per node, 8-deep MLP ----

__global__ __launch_bounds__(256) void aggb_k(const int* __restrict__ rp, const int* __restrict__ ci,
                                              const u16* __restrict__ h, u16* __restrict__ ag){
  int w = (int)((blockIdx.x*256u + threadIdx.x) >> 6);
  int lane = threadIdx.x & 63;
  if (w >= NN) return;
  int e0 = rp[w], e1 = rp[w+1];
  const uint2* hu = (const uint2*)h;
  float a0=0.f, a1=0.f, a2=0.f, a3=0.f;
  for (int base = e0; base < e1; base += 64){
    int cnt = e1 - base; if (cnt > 64) cnt = 64;
    int my = ci[base + (lane < cnt ? lane : cnt-1)];
    int i = 0;
    for (; i + 8 <= cnt; i += 8){
      int s[8];
      #pragma unroll
      for (int jj = 0; jj < 8; ++jj) s[jj] = __builtin_amdgcn_readlane(my, i + jj);
      uint2 v[8];
      #pragma unroll
      for (int jj = 0; jj < 8; ++jj) v[jj] = hu[(size_t)s[jj]*64 + lane];
      #pragma unroll
      for (int jj = 0; jj < 8; ++jj){
        a0 += bf2f((u16)(v[jj].x & 0xffffu));
        a1 += bf2f((u16)(v[jj].x >> 16));
        a2 += bf2f((u16)(v[jj].y & 0xffffu));
        a3 += bf2f((u16)(v[jj].y >> 16));
      }
    }
    for (; i < cnt; ++i){
      int s0 = __builtin_amdgcn_readlane(my, i);
      uint2 v = hu[(size_t)s0*64 + lane];
      a0 += bf2f((u16)(v.x&0xffffu));
      a1 += bf2f((u16)(v.x>>16));
      a2 += bf2f((u16)(v.y&0xffffu));
      a3 += bf2f((u16)(v.y>>16));
    }
  }
  int d = e1 - e0;
  float inv = 1.0f / (float)(d > 0 ? d : 1);
  uint2 o;
  o.x = (uint32_t)f2bf(a0*inv) | ((uint32_t)f2bf(a1*inv) << 16);
  o.y = (uint32_t)f2bf(a2*inv) | ((uint32_t)f2bf(a3*inv) << 16);
  ((uint2*)ag)[(size_t)w*64 + lane] = o;
}

// ---------------- MFMA GEMM v3: A-only LDS, B direct from L2 ----------------

template<int KS1, int KS2, int NCC, int EPI>
__global__ __launch_bounds__(256, 3) void gemm3_k(
    const u16* __restrict__ A1, const u16* __restrict__ A2,
    const u16* __restrict__ Wp, const float* __restrict__ bias,
    u16* __restrict__ Cout, int M, float* __restrict__ stS)
{
  constexpr int NT    = NCC >> 4;
  constexpr int NFRAG = NCC / 64;          // frags per wave (4 or 2)
  constexpr int NS1   = KS1 / 2;           // BK-steps in A1
  constexpr int NSTEP = (KS1 + KS2) / 2;   // total BK-steps (BK=64)

  __shared__ u16 Al[2][64*64];             // 8KB per buffer: [row][64 k] + swizzle

  const int t    = threadIdx.x;
  const int lane = t & 63;
  const int wv   = t >> 6;
  const int r15  = lane & 15, kg = lane >> 4;
  const int rb   = blockIdx.x * 64;
  const int nt0w = wv * NFRAG;             // wave's first 16-col tile

  f32x4 acc[4][NFRAG];
  #pragma unroll
  for (int m = 0; m < 4; ++m)
    #pragma unroll
    for (int n = 0; n < NFRAG; ++n){ f32x4 z = {0.f,0.f,0.f,0.f}; acc[m][n] = z; }

  // stage one BK-step of A into dbuf slot bsel (8 rows per gload16 issue)
  auto stageA = [&](int step, int bsel){
    const bool inA1 = (step < NS1);
    const u16* Ab   = inA1 ? A1 : A2;
    const int  Krow = (inA1 ? KS1 : KS2) * 32;
    const int  kloc = (inA1 ? step : step - NS1) * 64;
    #pragma unroll
    for (int c = 0; c < 2; ++c){
      int row = c*32 + wv*8 + (lane >> 3);
      int gc  = (lane & 7) ^ (row & 7);              // inverse swizzle on global src
      const u16* g = Ab + (size_t)(rb + row)*Krow + kloc + gc*8;
      gload16(g, &Al[bsel][c*2048 + wv*512]);
    }
  };
  // load B fragments for global k-slice ss into dst[NFRAG]
  auto loadB = [&](int ss, s16x8* dst){
    const u16* g = Wp + ((size_t)(ss*NT + nt0w)*64 + lane)*8;
    #pragma unroll
    for (int n = 0; n < NFRAG; ++n)
      dst[n] = *(const s16x8*)(g + (size_t)n*512);
  };

  s16x8 bb[2][NFRAG];
  stageA(0, 0);
  loadB(0, bb[0]);
  __syncthreads();   // drains vmcnt (A staging of step 0)

  #pragma unroll
  for (int step = 0; step < NSTEP; ++step){
    const int cur = step & 1;
    if (step + 1 < NSTEP) stageA(step + 1, cur ^ 1);
    #pragma unroll
    for (int sl = 0; sl < 2; ++sl){
      const int ss = step*2 + sl;
      const int p  = ss & 1;
      if (ss + 1 < NSTEP*2) loadB(ss + 1, bb[p ^ 1]);
      s16x8 af[4];
      const char* Ab = (const char*)&Al[cur][0];
      #pragma unroll
      for (int m = 0; m < 4; ++m){
        int row = m*16 + r15;
        int c16 = (sl*4 + kg) ^ (row & 7);           // swizzled read
        af[m] = *(const s16x8*)(Ab + row*128 + c16*16);
      }
      #pragma unroll
      for (int m = 0; m < 4; ++m)
        #pragma unroll
        for (int n = 0; n < NFRAG; ++n)
          acc[m][n] = __builtin_amdgcn_mfma_f32_16x16x32_bf16(af[m], bb[p][n], acc[m][n], 0, 0, 0);
    }
    __syncthreads();  // closes reads of Al[cur]; drains staging of step+1
  }

  // ---- epilogue ----
  #pragma unroll
  for (int n = 0; n < NFRAG; ++n){
    int col = (nt0w + n)*16 + r15;
    float bc = bias[col];
    float s = 0.f, q = 0.f;
    #pragma unroll
    for (int m = 0; m < 4; ++m){
      int rbase = rb + m*16 + kg*4;
      #pragma unroll
      for (int r = 0; r < 4; ++r){
        int row = rbase + r;
        float val = acc[m][n][r] + bc;
        if (EPI == 0) val = fmaxf(val, 0.f);
        bool ok = row < M;
        if (ok) Cout[(size_t)row*NCC + col] = f2bf(val);
        if (EPI == 1 && ok){ s += val; q += val*val; }
      }
    }
    if (EPI == 1){
      s += __shfl_xor(s, 16); s += __shfl_xor(s, 32);
      q += __shfl_xor(q, 16); q += __shfl_xor(q, 32);
      if (lane < 16){
        int idx = ((blockIdx.x & 15) << 9) + col;   // stripe*512 + col
        atomicAdd(&stS[idx], s);
        atomicAdd(&stS[idx + 256], q);
      }
    }
  }
}

// ---------------- BN finalize + apply ----------------

__global__ __launch_bounds__(256) void bnfin_k(const float* __restrict__ acc,
                                               const float* __restrict__ g, const float* __restrict__ b,
                                               float* __restrict__ coef){
  int c = threadIdx.x;
  float s = 0.f, q = 0.f;
  #pragma unroll
  for (int j = 0; j < 16; ++j){
    s += acc[j*512 + c];
    q += acc[j*512 + 256 + c];
  }
  float mean = s * (1.0f / (float)NN);
  float var  = q * (1.0f / (float)NN) - mean*mean;
  float sc = g[c] * rsqrtf(var + 1e-5f);
  coef[c] = sc;
  coef[256 + c] = b[c] - mean*sc;
}

// BN apply + residual; optional fp8 shadow write; optional fused f32 embeddings out
__global__ __launch_bounds__(256) void bnapply_k(const uint4* __restrict__ outb, uint4* __restrict__ h,
                                                 uint2* __restrict__ h8,
                                                 const float* __restrict__ coef, int layer, int wr8,
                                                 float* __restrict__ embout){
  int i = blockIdx.x*256 + threadIdx.x;
  if (i >= NN*32) return;
  int col0 = (i & 31) * 8;
  const float4* scp = (const float4*)(coef + col0);
  const float4* shp = (const float4*)(coef + 256 + col0);
  float4 s0 = scp[0], s1 = scp[1], t0 = shp[0], t1 = shp[1];
  float sc[8] = {s0.x,s0.y,s0.z,s0.w,s1.x,s1.y,s1.z,s1.w};
  float sh[8] = {t0.x,t0.y,t0.z,t0.w,t1.x,t1.y,t1.z,t1.w};
  float v[8], r[8];
  up8(outb[i], v);
  #pragma unroll
  for (int j = 0; j < 8; ++j) r[j] = fmaxf(v[j]*sc[j] + sh[j], 0.f);
  if (layer > 0){
    float hv[8];
    up8(h[i], hv);
    #pragma unroll
    for (int j = 0; j < 8; ++j) r[j] += hv[j];
  }
  h[i] = pk8(r);
  if (wr8) h8[i] = pkf8(r);
  if (embout){
    int row = i >> 5;
    float4* ep = (float4*)(embout + (size_t)row*256 + col0);
    ep[0] = make_float4(r[0], r[1], r[2], r[3]);
    ep[1] = make_float4(r[4], r[5], r[6], r[7]);
  }
}

// ---------------- fc2 logits ----------------

__global__ __launch_bounds__(256) void fc2_k(const u16* __restrict__ z, const float* __restrict__ w2,
                                             const float* __restrict__ b2, float* __restrict__ out){
  int w = (int)((blockIdx.x*256u + threadIdx.x) >> 6);
  int lane = threadIdx.x & 63;
  if (w >= NN) return;
  const uint32_t* zu = (const uint32_t*)(z + (size_t)w*128);
  uint32_t p = zu[lane];
  float z0 = bf2f((u16)(p & 0xffffu));
  float z1 = bf2f((u16)(p >> 16));
  float4 wv = ((const float4*)w2)[lane];
  float p0 = z0*wv.x + z1*wv.z;
  float p1 = z0*wv.y + z1*wv.w;
  #pragma unroll
  for (int off = 1; off < 64; off <<= 1){
    p0 += __shfl_xor(p0, off);
    p1 += __shfl_xor(p1, off);
  }
  if (lane == 0){
    out[(size_t)w*2]     = p0 + b2[0];
    out[(size_t)w*2 + 1] = p1 + b2[1];
  }
}

// ---------------- host ----------------

extern "C" void kernel_launch(void* const* d_in, const int* in_sizes, int n_in,
                              void* d_out, int out_size, void* d_ws, size_t ws_size,
                              hipStream_t stream){
  const float* x       = (const float*)d_in[0];
  const int*   ei      = (const int*)d_in[1];
  const float* proj_w  = (const float*)d_in[2];
  const float* proj_b  = (const float*)d_in[3];
  const float* lin_l_w = (const float*)d_in[4];
  const float* lin_l_b = (const float*)d_in[5];
  const float* lin_r_w = (const float*)d_in[6];
  const float* bn_g    = (const float*)d_in[7];
  const float* bn_b    = (const float*)d_in[8];
  const float* fc1_w   = (const float*)d_in[9];
  const float* fc1_b   = (const float*)d_in[10];
  const float* fc2_w   = (const float*)d_in[11];
  const float* fc2_b   = (const float*)d_in[12];
  float* out = (float*)d_out;

  char* ws = (char*)d_ws;
  size_t off = 0;
  auto alloc = [&](size_t b){ size_t o = off; off = (off + b + 255) & ~(size_t)255; return o; };

  u16* bufA    = (u16*)(ws + alloc((size_t)MP*256*2));  // x_bf16 -> agg -> z
  u16* hbuf    = (u16*)(ws + alloc((size_t)MP*256*2));  // h
  u16* bufC    = (u16*)(ws + alloc((size_t)MP*256*2));  // layer gemm out
  uint8_t* h8  = (uint8_t*)(ws + alloc((size_t)MP*256));// fp8 shadow of h
  u16* wp_proj = (u16*)(ws + alloc((size_t)4*16*64*8*2));
  u16* wp_l[3];
  for (int i = 0; i < 3; ++i) wp_l[i] = (u16*)(ws + alloc((size_t)16*16*64*8*2));
  u16* wp_fc1  = (u16*)(ws + alloc((size_t)8*8*64*8*2));
  int* rp    = (int*)(ws + alloc((size_t)(NN+1)*4));
  int* ci    = (int*)(ws + alloc((size_t)NE*4));
  int* bcnt  = (int*)(ws + alloc(NBK*4));
  int* bcur  = (int*)(ws + alloc(NBK*4));
  float* bnacc = (float*)(ws + alloc(3*8192*4));
  float* coef  = (float*)(ws + alloc(3*512*4));
  unsigned* epair = (unsigned*)bufC;   // bufC is dead until first layer gemm
  (void)ws_size; (void)in_sizes; (void)n_in; (void)out_size;

  const int BFB = (NE + EPB - 1)/EPB;  // 782
  const int GX = MP/64;                // 1564 row blocks

  zero_k<<<96, 256, 0, stream>>>(bnacc, bcnt);

  // CSR build: hist -> scan -> bucket-grouped packed edges -> per-bucket counting sort
  bhist_k<<<BFB, 256, 0, stream>>>(ei, bcnt);
  bscan_k<<<1, 512, 0, stream>>>(bcnt, bcur);
  bfill_k<<<BFB, 256, 0, stream>>>(ei, bcur, epair);
  csort_k<<<NBK, 256, 0, stream>>>(epair, bcnt, bcur, ci, rp);

  // weights + input cvt
  cvt_k<<<(NN*INC/4 + 255)/256, 256, 0, stream>>>(x, bufA, NN*INC/4);
  pack_k<<<(128*256 + 255)/256, 256, 0, stream>>>(proj_w, wp_proj, 128, 256, 0);
  for (int i = 0; i < 3; ++i){
    pack_k<<<(256*256 + 255)/256, 256, 0, stream>>>(lin_l_w + (size_t)i*65536, wp_l[i], 256, 256, 0);
    pack_k<<<(256*256 + 255)/256, 256, 0, stream>>>(lin_r_w + (size_t)i*65536, wp_l[i], 256, 256, 8);
  }
  pack_k<<<(256*128 + 255)/256, 256, 0, stream>>>(fc1_w, wp_fc1, 256, 128, 0);

  // proj: h = relu(x @ proj_w + proj_b)   [K=128, NC=256]
  gemm3_k<4,0,256,0><<<GX, 256, 0, stream>>>(bufA, nullptr, wp_proj, proj_b,
                                             hbuf, NN, nullptr);
  cvt8_k<<<(NN*32 + 255)/256, 256, 0, stream>>>((const uint4*)hbuf, (uint2*)h8, NN*32);

  for (int i = 0; i < 3; ++i){
    if (i < 2)
      agg8_k<<<((NN + 3)/4*64 + 255)/256, 256, 0, stream>>>(rp, ci, (const uint4*)h8, bufA);
    else
      aggb_k<<<(NN + 3)/4, 256, 0, stream>>>(rp, ci, hbuf, bufA);
    // out = agg @ lin_l + b + h @ lin_r   [K=256+256, NC=256] -> bufC
    gemm3_k<8,8,256,1><<<GX, 256, 0, stream>>>(bufA, hbuf, wp_l[i], lin_l_b + (size_t)i*256,
                                               bufC, NN, bnacc + i*8192);
    bnfin_k<<<1, 256, 0, stream>>>(bnacc + i*8192, bn_g + (size_t)i*256, bn_b + (size_t)i*256, coef + i*512);
    // h8 only needed for layer i+1's fp8 gather; layer 2 fuses the f32 embeddings write
    bnapply_k<<<(NN*32 + 255)/256, 256, 0, stream>>>((const uint4*)bufC, (uint4*)hbuf, (uint2*)h8,
                                                     coef + i*512, i, (i == 0) ? 1 : 0,
                                                     (i == 2) ? (out + 200000) : nullptr);
  }

  // fc1: z = relu(h @ fc1_w + fc1_b)   [K=256, NC=128]
  gemm3_k<8,0,128,0><<<GX, 256, 0, stream>>>(hbuf, nullptr, wp_fc1, fc1_b,
                                             bufA, NN, nullptr);
  fc2_k<<<(NN + 3)/4, 256, 0, stream>>>(bufA, fc2_w, fc2_b, out);
}

// Round 11
// 646.306 us; speedup vs baseline: 1.9389x; 1.0662x over previous
//
#include <hip/hip_runtime.h>
#include <stdint.h>

#define NN 100000      // nodes
#define NE 1600000     // edges
#define INC 128        // in channels
#define HID 256        // hidden
#define MP  100096     // padded rows (64*1564)
#define NBK 391        // dst buckets (dst>>8), 99999>>8 = 390
#define EPB 2048       // edges per bucket-fill block

typedef unsigned short u16;
typedef __attribute__((ext_vector_type(2))) float f32x2;
typedef __attribute__((ext_vector_type(4))) float f32x4;
typedef __attribute__((ext_vector_type(8))) short s16x8;

static __device__ __forceinline__ float bf2f(u16 u){
  union { uint32_t i; float f; } v; v.i = ((uint32_t)u) << 16; return v.f;
}
static __device__ __forceinline__ u16 f2bf(float f){
  union { float f; uint32_t i; } v; v.f = f;
  uint32_t r = v.i + 0x7FFFu + ((v.i >> 16) & 1u);
  return (u16)(r >> 16);
}
static __device__ __forceinline__ void up8(uint4 o, float* v){
  v[0]=bf2f((u16)(o.x&0xffffu)); v[1]=bf2f((u16)(o.x>>16));
  v[2]=bf2f((u16)(o.y&0xffffu)); v[3]=bf2f((u16)(o.y>>16));
  v[4]=bf2f((u16)(o.z&0xffffu)); v[5]=bf2f((u16)(o.z>>16));
  v[6]=bf2f((u16)(o.w&0xffffu)); v[7]=bf2f((u16)(o.w>>16));
}
static __device__ __forceinline__ uint4 pk8(const float* v){
  uint4 o;
  o.x = (uint32_t)f2bf(v[0]) | ((uint32_t)f2bf(v[1])<<16);
  o.y = (uint32_t)f2bf(v[2]) | ((uint32_t)f2bf(v[3])<<16);
  o.z = (uint32_t)f2bf(v[4]) | ((uint32_t)f2bf(v[5])<<16);
  o.w = (uint32_t)f2bf(v[6]) | ((uint32_t)f2bf(v[7])<<16);
  return o;
}
// pack 8 f32 -> 8 fp8 e4m3 (2 u32)
static __device__ __forceinline__ uint2 pkf8(const float* r){
  uint32_t lo = __builtin_amdgcn_cvt_pk_fp8_f32(r[0], r[1], 0u, false);
  lo = __builtin_amdgcn_cvt_pk_fp8_f32(r[2], r[3], lo, true);
  uint32_t hi = __builtin_amdgcn_cvt_pk_fp8_f32(r[4], r[5], 0u, false);
  hi = __builtin_amdgcn_cvt_pk_fp8_f32(r[6], r[7], hi, true);
  return make_uint2(lo, hi);
}

// async global -> LDS, 16B per lane; LDS dest = wave-uniform base + lane*16
static __device__ __forceinline__ void gload16(const void* g, void* l){
  __builtin_amdgcn_global_load_lds((const __attribute__((address_space(1))) void*)g,
                                   (__attribute__((address_space(3))) void*)l, 16, 0, 0);
}

// W[K][NC] f32 row-major -> MFMA B-fragment order
static __device__ __forceinline__ void packw(const float* __restrict__ src, u16* __restrict__ dst,
                                             int K, int NC, int ksoff, int t){
  int k = t / NC, n = t % NC;
  int NT = NC >> 4;
  int ks = ksoff + (k >> 5);
  int l  = ((k >> 3) & 3)*16 + (n & 15);
  int j  = k & 7;
  dst[((size_t)(ks*NT + (n>>4))*64 + l)*8 + j] = f2bf(src[(size_t)k*NC + n]);
}

// ---------------- fused prep: x->bf16 cvt, all weight packs, zero ----------------
// block ranges: [0,12500) cvt | proj 128 | 6x256 lin | fc1 128 | zero 96

__global__ __launch_bounds__(256) void prep_k(
    const float* __restrict__ x, u16* __restrict__ xbf,
    const float* __restrict__ proj_w, u16* __restrict__ wp_proj,
    const float* __restrict__ lin_l_w, const float* __restrict__ lin_r_w,
    u16* __restrict__ wp_l0, u16* __restrict__ wp_l1, u16* __restrict__ wp_l2,
    const float* __restrict__ fc1_w, u16* __restrict__ wp_fc1,
    float* __restrict__ bnacc, int* __restrict__ bcnt)
{
  int b = blockIdx.x;
  int tid = threadIdx.x;
  if (b < 12500){                       // cvt: 3.2M float4 exactly
    int i = b*256 + tid;
    float4 v = ((const float4*)x)[i];
    uint2 o;
    o.x = (uint32_t)f2bf(v.x) | ((uint32_t)f2bf(v.y)<<16);
    o.y = (uint32_t)f2bf(v.z) | ((uint32_t)f2bf(v.w)<<16);
    ((uint2*)xbf)[i] = o;
    return;
  }
  b -= 12500;
  if (b < 128){ packw(proj_w, wp_proj, 128, 256, 0, b*256 + tid); return; }
  b -= 128;
  if (b < 1536){                        // 6 x 256 blocks: l0,r0,l1,r1,l2,r2
    int wsel = b >> 8;                  // 0..5
    int t = (b & 255)*256 + tid;        // < 65536
    int i = wsel >> 1;
    u16* dst = (i == 0) ? wp_l0 : (i == 1) ? wp_l1 : wp_l2;
    if (wsel & 1) packw(lin_r_w + (size_t)i*65536, dst, 256, 256, 8, t);
    else          packw(lin_l_w + (size_t)i*65536, dst, 256, 256, 0, t);
    return;
  }
  b -= 1536;
  if (b < 128){ packw(fc1_w, wp_fc1, 256, 128, 0, b*256 + tid); return; }
  b -= 128;
  {                                     // zero: 96 blocks
    int i = b*256 + tid;
    if (i < 3*8192) bnacc[i] = 0.f;
    if (i < NBK) bcnt[i] = 0;
  }
}

// ---------------- CSR build (bucketed; epair packed u32) ----------------

__global__ __launch_bounds__(256) void bhist_k(const int* __restrict__ ei, int* __restrict__ bcnt){
  __shared__ int h[NBK];
  for (int i = threadIdx.x; i < NBK; i += 256) h[i] = 0;
  __syncthreads();
  int e0 = blockIdx.x * EPB;
  #pragma unroll
  for (int j = 0; j < EPB/256; ++j){
    int e = e0 + j*256 + threadIdx.x;
    if (e < NE) atomicAdd(&h[ei[NE + e] >> 8], 1);
  }
  __syncthreads();
  for (int i = threadIdx.x; i < NBK; i += 256)
    if (h[i]) atomicAdd(&bcnt[i], h[i]);
}

__global__ __launch_bounds__(512) void bscan_k(const int* __restrict__ bcnt, int* __restrict__ bcur){
  __shared__ int sd[512];
  int t = threadIdx.x;
  int v = (t < NBK) ? bcnt[t] : 0;
  sd[t] = v; __syncthreads();
  for (int o = 1; o < 512; o <<= 1){
    int x = (t >= o) ? sd[t-o] : 0;
    __syncthreads();
    sd[t] += x;
    __syncthreads();
  }
  if (t < NBK) bcur[t] = sd[t] - v;   // exclusive base, doubles as cursor
}

// per-block counting sort into bucket-grouped packed edges: (src<<8)|dst_local
__global__ __launch_bounds__(256) void bfill_k(const int* __restrict__ ei, int* __restrict__ bcur,
                                               unsigned* __restrict__ epair){
  __shared__ int cnt[NBK];
  __shared__ int gb[NBK];
  for (int i = threadIdx.x; i < NBK; i += 256) cnt[i] = 0;
  __syncthreads();
  int e0 = blockIdx.x * EPB;
  unsigned pk[EPB/256];
  int bkt[EPB/256], rnk[EPB/256];
  #pragma unroll
  for (int j = 0; j < EPB/256; ++j){
    int e = e0 + j*256 + threadIdx.x;
    if (e < NE){
      int s = ei[e];
      int d = ei[NE + e];
      bkt[j] = d >> 8;
      pk[j]  = ((unsigned)s << 8) | (unsigned)(d & 255);
      rnk[j] = atomicAdd(&cnt[bkt[j]], 1);
    } else bkt[j] = -1;
  }
  __syncthreads();
  for (int i = threadIdx.x; i < NBK; i += 256){
    int c = cnt[i];
    gb[i] = c ? atomicAdd(&bcur[i], c) : 0;
  }
  __syncthreads();
  #pragma unroll
  for (int j = 0; j < EPB/256; ++j){
    if (bkt[j] >= 0)
      epair[gb[bkt[j]] + rnk[j]] = pk[j];
  }
}

// one block per bucket: LDS hist over 256 local dst -> scan -> scatter ci + emit rp.
__global__ __launch_bounds__(256) void csort_k(const unsigned* __restrict__ epair,
                                               const int* __restrict__ bcnt, const int* __restrict__ bcur,
                                               int* __restrict__ ci, int* __restrict__ rp){
  __shared__ int hist[256], pfx[256], cnt2[256];
  int b = blockIdx.x, t = threadIdx.x;
  int cnt  = bcnt[b];
  int base = bcur[b] - cnt;        // bfill advanced bcur to end-of-bucket
  hist[t] = 0; cnt2[t] = 0;
  __syncthreads();
  for (int e = t; e < cnt; e += 256)
    atomicAdd(&hist[epair[base + e] & 255u], 1);
  __syncthreads();
  int v = hist[t];
  pfx[t] = v;
  __syncthreads();
  for (int o = 1; o < 256; o <<= 1){
    int x = (t >= o) ? pfx[t - o] : 0;
    __syncthreads();
    pfx[t] += x;
    __syncthreads();
  }
  int node = b*256 + t;
  if (node < NN) rp[node] = base + pfx[t] - v;   // exclusive prefix
  if (b == NBK-1 && t == 0) rp[NN] = NE;
  for (int e = t; e < cnt; e += 256){
    unsigned p = epair[base + e];
    int ld = (int)(p & 255u);
    int r  = atomicAdd(&cnt2[ld], 1);
    ci[base + pfx[ld] - hist[ld] + r] = (int)(p >> 8);
  }
}

// ---------------- mean aggregation over fp8 shadow: 4 nodes per wave ----------------

__global__ __launch_bounds__(256) void agg8_k(const int* __restrict__ rp, const int* __restrict__ ci,
                                              const uint4* __restrict__ h8, u16* __restrict__ ag){
  int wid  = (int)((blockIdx.x*256u + threadIdx.x) >> 6);
  int lane = threadIdx.x & 63;
  int ql   = lane & 15;
  int w    = wid*4 + (lane >> 4);
  bool act = (w < NN);
  int e0 = 0, e1 = 0;
  if (act){ e0 = rp[w]; e1 = rp[w+1]; }
  int cnt = e1 - e0;

  float a[16];
  #pragma unroll
  for (int k = 0; k < 16; ++k) a[k] = 0.f;

  for (int base = 0; __any(base < cnt); base += 16){
    int rem = cnt - base;
    int my = 0;
    if (ql < rem) my = ci[e0 + base + ql];
    #pragma unroll
    for (int j0 = 0; j0 < 16; j0 += 8){
      if (!__any(j0 < rem)) break;
      uint4 v[8];
      #pragma unroll
      for (int jj = 0; jj < 8; ++jj){
        int j = j0 + jj;
        int s = __shfl(my, (lane & 48) + j);
        v[jj] = make_uint4(0,0,0,0);
        if (j < rem) v[jj] = h8[(size_t)s*16 + ql];
      }
      #pragma unroll
      for (int jj = 0; jj < 8; ++jj){
        uint32_t wd[4] = {v[jj].x, v[jj].y, v[jj].z, v[jj].w};
        #pragma unroll
        for (int p = 0; p < 4; ++p){
          f32x2 lo = __builtin_amdgcn_cvt_pk_f32_fp8(wd[p], false);
          f32x2 hi = __builtin_amdgcn_cvt_pk_f32_fp8(wd[p], true);
          a[p*4+0] += lo[0]; a[p*4+1] += lo[1];
          a[p*4+2] += hi[0]; a[p*4+3] += hi[1];
        }
      }
    }
  }

  if (act){
    float inv = 1.0f / (float)(cnt > 0 ? cnt : 1);
    float r0[8], r1[8];
    #pragma unroll
    for (int k = 0; k < 8; ++k){ r0[k] = a[k]*inv; r1[k] = a[8+k]*inv; }
    uint4* agu = (uint4*)ag;
    agu[(size_t)w*32 + ql*2]     = pk8(r0);
    agu[(size_t)w*32 + ql*2 + 1] = pk8(r1);
  }
}

// ---------------- mean aggregation over bf16 h: one wave per node ----------------

__global__ __launch_bounds__(256) void aggb_k(const int* __restrict__ rp, const int* __restrict__ ci,
                                              const u16* __restrict__ h, u16* __restrict__ ag){
  int w = (int)((blockIdx.x*256u + threadIdx.x) >> 6);
  int lane = threadIdx.x & 63;
  if (w >= NN) return;
  int e0 = rp[w], e1 = rp[w+1];
  const uint2* hu = (const uint2*)h;
  float a0=0.f, a1=0.f, a2=0.f, a3=0.f;
  for (int base = e0; base < e1; base += 64){
    int cnt = e1 - base; if (cnt > 64) cnt = 64;
    int my = ci[base + (lane < cnt ? lane : cnt-1)];
    int i = 0;
    for (; i + 8 <= cnt; i += 8){
      int s[8];
      #pragma unroll
      for (int jj = 0; jj < 8; ++jj) s[jj] = __builtin_amdgcn_readlane(my, i + jj);
      uint2 v[8];
      #pragma unroll
      for (int jj = 0; jj < 8; ++jj) v[jj] = hu[(size_t)s[jj]*64 + lane];
      #pragma unroll
      for (int jj = 0; jj < 8; ++jj){
        a0 += bf2f((u16)(v[jj].x & 0xffffu));
        a1 += bf2f((u16)(v[jj].x >> 16));
        a2 += bf2f((u16)(v[jj].y & 0xffffu));
        a3 += bf2f((u16)(v[jj].y >> 16));
      }
    }
    for (; i < cnt; ++i){
      int s0 = __builtin_amdgcn_readlane(my, i);
      uint2 v = hu[(size_t)s0*64 + lane];
      a0 += bf2f((u16)(v.x&0xffffu));
      a1 += bf2f((u16)(v.x>>16));
      a2 += bf2f((u16)(v.y&0xffffu));
      a3 += bf2f((u16)(v.y>>16));
    }
  }
  int d = e1 - e0;
  float inv = 1.0f / (float)(d > 0 ? d : 1);
  uint2 o;
  o.x = (uint32_t)f2bf(a0*inv) | ((uint32_t)f2bf(a1*inv) << 16);
  o.y = (uint32_t)f2bf(a2*inv) | ((uint32_t)f2bf(a3*inv) << 16);
  ((uint2*)ag)[(size_t)w*64 + lane] = o;
}

// ---------------- MFMA GEMM v3: A-only LDS, B direct from L2 ----------------
// EPI 0: relu, store bf16.  EPI 1: store + striped BN stats.
// EPI 2: fused fc2 head — no C store; relu(z) @ fc2_w + fc2_b -> logits.

template<int KS1, int KS2, int NCC, int EPI>
__global__ __launch_bounds__(256, 3) void gemm3_k(
    const u16* __restrict__ A1, const u16* __restrict__ A2,
    const u16* __restrict__ Wp, const float* __restrict__ bias,
    u16* __restrict__ Cout, int M, float* __restrict__ stS,
    const float* __restrict__ w2, const float* __restrict__ b2, float* __restrict__ out2)
{
  constexpr int NT    = NCC >> 4;
  constexpr int NFRAG = NCC / 64;          // frags per wave (4 or 2)
  constexpr int NS1   = KS1 / 2;           // BK-steps in A1
  constexpr int NSTEP = (KS1 + KS2) / 2;   // total BK-steps (BK=64)

  __shared__ u16 Al[2][64*64];             // 8KB per buffer: [row][64 k] + swizzle
  __shared__ float red[4][64][2];          // fc2 cross-wave reduce (EPI==2)

  const int t    = threadIdx.x;
  const int lane = t & 63;
  const int wv   = t >> 6;
  const int r15  = lane & 15, kg = lane >> 4;
  const int rb   = blockIdx.x * 64;
  const int nt0w = wv * NFRAG;             // wave's first 16-col tile

  f32x4 acc[4][NFRAG];
  #pragma unroll
  for (int m = 0; m < 4; ++m)
    #pragma unroll
    for (int n = 0; n < NFRAG; ++n){ f32x4 z = {0.f,0.f,0.f,0.f}; acc[m][n] = z; }

  // stage one BK-step of A into dbuf slot bsel (8 rows per gload16 issue)
  auto stageA = [&](int step, int bsel){
    const bool inA1 = (step < NS1);
    const u16* Ab   = inA1 ? A1 : A2;
    const int  Krow = (inA1 ? KS1 : KS2) * 32;
    const int  kloc = (inA1 ? step : step - NS1) * 64;
    #pragma unroll
    for (int c = 0; c < 2; ++c){
      int row = c*32 + wv*8 + (lane >> 3);
      int gc  = (lane & 7) ^ (row & 7);              // inverse swizzle on global src
      const u16* g = Ab + (size_t)(rb + row)*Krow + kloc + gc*8;
      gload16(g, &Al[bsel][c*2048 + wv*512]);
    }
  };
  // load B fragments for global k-slice ss into dst[NFRAG]
  auto loadB = [&](int ss, s16x8* dst){
    const u16* g = Wp + ((size_t)(ss*NT + nt0w)*64 + lane)*8;
    #pragma unroll
    for (int n = 0; n < NFRAG; ++n)
      dst[n] = *(const s16x8*)(g + (size_t)n*512);
  };

  s16x8 bb[2][NFRAG];
  stageA(0, 0);
  loadB(0, bb[0]);
  __syncthreads();   // drains vmcnt (A staging of step 0)

  #pragma unroll
  for (int step = 0; step < NSTEP; ++step){
    const int cur = step & 1;
    if (step + 1 < NSTEP) stageA(step + 1, cur ^ 1);
    #pragma unroll
    for (int sl = 0; sl < 2; ++sl){
      const int ss = step*2 + sl;
      const int p  = ss & 1;
      if (ss + 1 < NSTEP*2) loadB(ss + 1, bb[p ^ 1]);
      s16x8 af[4];
      const char* Ab = (const char*)&Al[cur][0];
      #pragma unroll
      for (int m = 0; m < 4; ++m){
        int row = m*16 + r15;
        int c16 = (sl*4 + kg) ^ (row & 7);           // swizzled read
        af[m] = *(const s16x8*)(Ab + row*128 + c16*16);
      }
      #pragma unroll
      for (int m = 0; m < 4; ++m)
        #pragma unroll
        for (int n = 0; n < NFRAG; ++n)
          acc[m][n] = __builtin_amdgcn_mfma_f32_16x16x32_bf16(af[m], bb[p][n], acc[m][n], 0, 0, 0);
    }
    __syncthreads();  // closes reads of Al[cur]; drains staging of step+1
  }

  // ---- epilogue ----
  if (EPI == 2){
    // fused fc2: p[m][r][c] = sum over this thread's cols of relu(z)*w2
    float p[4][4][2];
    #pragma unroll
    for (int m = 0; m < 4; ++m)
      #pragma unroll
      for (int r = 0; r < 4; ++r){ p[m][r][0] = 0.f; p[m][r][1] = 0.f; }
    #pragma unroll
    for (int n = 0; n < NFRAG; ++n){
      int col = (nt0w + n)*16 + r15;
      float bc = bias[col];
      float w0 = w2[col*2], w1 = w2[col*2 + 1];
      #pragma unroll
      for (int m = 0; m < 4; ++m)
        #pragma unroll
        for (int r = 0; r < 4; ++r){
          float val = fmaxf(acc[m][n][r] + bc, 0.f);
          p[m][r][0] += val*w0;
          p[m][r][1] += val*w1;
        }
    }
    #pragma unroll
    for (int off = 1; off < 16; off <<= 1)
      #pragma unroll
      for (int m = 0; m < 4; ++m)
        #pragma unroll
        for (int r = 0; r < 4; ++r){
          p[m][r][0] += __shfl_xor(p[m][r][0], off);
          p[m][r][1] += __shfl_xor(p[m][r][1], off);
        }
    if (r15 == 0){
      #pragma unroll
      for (int m = 0; m < 4; ++m)
        #pragma unroll
        for (int r = 0; r < 4; ++r){
          red[wv][m*16 + kg*4 + r][0] = p[m][r][0];
          red[wv][m*16 + kg*4 + r][1] = p[m][r][1];
        }
    }
    __syncthreads();
    if (t < 128){
      int row = t >> 1, c = t & 1;
      float s = red[0][row][c] + red[1][row][c] + red[2][row][c] + red[3][row][c] + b2[c];
      if (rb + row < M) out2[(size_t)(rb + row)*2 + c] = s;
    }
    return;
  }

  #pragma unroll
  for (int n = 0; n < NFRAG; ++n){
    int col = (nt0w + n)*16 + r15;
    float bc = bias[col];
    float s = 0.f, q = 0.f;
    #pragma unroll
    for (int m = 0; m < 4; ++m){
      int rbase = rb + m*16 + kg*4;
      #pragma unroll
      for (int r = 0; r < 4; ++r){
        int row = rbase + r;
        float val = acc[m][n][r] + bc;
        if (EPI == 0) val = fmaxf(val, 0.f);
        bool ok = row < M;
        if (ok) Cout[(size_t)row*NCC + col] = f2bf(val);
        if (EPI == 1 && ok){ s += val; q += val*val; }
      }
    }
    if (EPI == 1){
      s += __shfl_xor(s, 16); s += __shfl_xor(s, 32);
      q += __shfl_xor(q, 16); q += __shfl_xor(q, 32);
      if (lane < 16){
        int idx = ((blockIdx.x & 15) << 9) + col;   // stripe*512 + col
        atomicAdd(&stS[idx], s);
        atomicAdd(&stS[idx + 256], q);
      }
    }
  }
}

// ---------------- BN finalize + apply ----------------

__global__ __launch_bounds__(256) void bnfin_k(const float* __restrict__ acc,
                                               const float* __restrict__ g, const float* __restrict__ b,
                                               float* __restrict__ coef){
  int c = threadIdx.x;
  float s = 0.f, q = 0.f;
  #pragma unroll
  for (int j = 0; j < 16; ++j){
    s += acc[j*512 + c];
    q += acc[j*512 + 256 + c];
  }
  float mean = s * (1.0f / (float)NN);
  float var  = q * (1.0f / (float)NN) - mean*mean;
  float sc = g[c] * rsqrtf(var + 1e-5f);
  coef[c] = sc;
  coef[256 + c] = b[c] - mean*sc;
}

// BN apply + residual; optional fp8 shadow write; optional fused f32 embeddings out
__global__ __launch_bounds__(256) void bnapply_k(const uint4* __restrict__ outb, uint4* __restrict__ h,
                                                 uint2* __restrict__ h8,
                                                 const float* __restrict__ coef, int layer, int wr8,
                                                 float* __restrict__ embout){
  int i = blockIdx.x*256 + threadIdx.x;
  if (i >= NN*32) return;
  int col0 = (i & 31) * 8;
  const float4* scp = (const float4*)(coef + col0);
  const float4* shp = (const float4*)(coef + 256 + col0);
  float4 s0 = scp[0], s1 = scp[1], t0 = shp[0], t1 = shp[1];
  float sc[8] = {s0.x,s0.y,s0.z,s0.w,s1.x,s1.y,s1.z,s1.w};
  float sh[8] = {t0.x,t0.y,t0.z,t0.w,t1.x,t1.y,t1.z,t1.w};
  float v[8], r[8];
  up8(outb[i], v);
  #pragma unroll
  for (int j = 0; j < 8; ++j) r[j] = fmaxf(v[j]*sc[j] + sh[j], 0.f);
  if (layer > 0){
    float hv[8];
    up8(h[i], hv);
    #pragma unroll
    for (int j = 0; j < 8; ++j) r[j] += hv[j];
  }
  h[i] = pk8(r);
  if (wr8) h8[i] = pkf8(r);
  if (embout){
    int row = i >> 5;
    float4* ep = (float4*)(embout + (size_t)row*256 + col0);
    ep[0] = make_float4(r[0], r[1], r[2], r[3]);
    ep[1] = make_float4(r[4], r[5], r[6], r[7]);
  }
}

// bf16 h -> fp8 shadow (8 ch / thread)
__global__ __launch_bounds__(256) void cvt8_k(const uint4* __restrict__ h, uint2* __restrict__ h8, int n){
  int i = blockIdx.x*256 + threadIdx.x;
  if (i >= n) return;
  float v[8];
  up8(h[i], v);
  h8[i] = pkf8(v);
}

// ---------------- host ----------------

extern "C" void kernel_launch(void* const* d_in, const int* in_sizes, int n_in,
                              void* d_out, int out_size, void* d_ws, size_t ws_size,
                              hipStream_t stream){
  const float* x       = (const float*)d_in[0];
  const int*   ei      = (const int*)d_in[1];
  const float* proj_w  = (const float*)d_in[2];
  const float* proj_b  = (const float*)d_in[3];
  const float* lin_l_w = (const float*)d_in[4];
  const float* lin_l_b = (const float*)d_in[5];
  const float* lin_r_w = (const float*)d_in[6];
  const float* bn_g    = (const float*)d_in[7];
  const float* bn_b    = (const float*)d_in[8];
  const float* fc1_w   = (const float*)d_in[9];
  const float* fc1_b   = (const float*)d_in[10];
  const float* fc2_w   = (const float*)d_in[11];
  const float* fc2_b   = (const float*)d_in[12];
  float* out = (float*)d_out;

  char* ws = (char*)d_ws;
  size_t off = 0;
  auto alloc = [&](size_t b){ size_t o = off; off = (off + b + 255) & ~(size_t)255; return o; };

  u16* bufA    = (u16*)(ws + alloc((size_t)MP*256*2));  // x_bf16 -> agg
  u16* hbuf    = (u16*)(ws + alloc((size_t)MP*256*2));  // h
  u16* bufC    = (u16*)(ws + alloc((size_t)MP*256*2));  // layer gemm out
  uint8_t* h8  = (uint8_t*)(ws + alloc((size_t)MP*256));// fp8 shadow of h
  u16* wp_proj = (u16*)(ws + alloc((size_t)4*16*64*8*2));
  u16* wp_l[3];
  for (int i = 0; i < 3; ++i) wp_l[i] = (u16*)(ws + alloc((size_t)16*16*64*8*2));
  u16* wp_fc1  = (u16*)(ws + alloc((size_t)8*8*64*8*2));
  int* rp    = (int*)(ws + alloc((size_t)(NN+1)*4));
  int* ci    = (int*)(ws + alloc((size_t)NE*4));
  int* bcnt  = (int*)(ws + alloc(NBK*4));
  int* bcur  = (int*)(ws + alloc(NBK*4));
  float* bnacc = (float*)(ws + alloc(3*8192*4));
  float* coef  = (float*)(ws + alloc(3*512*4));
  unsigned* epair = (unsigned*)bufC;   // bufC is dead until first layer gemm
  (void)ws_size; (void)in_sizes; (void)n_in; (void)out_size;

  const int BFB = (NE + EPB - 1)/EPB;  // 782
  const int GX = MP/64;                // 1564 row blocks
  const int PREPB = 12500 + 128 + 1536 + 128 + 96;  // 14388

  // fused prep: cvt + all packs + zero (independent of CSR chain)
  prep_k<<<PREPB, 256, 0, stream>>>(x, bufA, proj_w, wp_proj, lin_l_w, lin_r_w,
                                    wp_l[0], wp_l[1], wp_l[2], fc1_w, wp_fc1, bnacc, bcnt);

  // CSR build: hist -> scan -> bucket-grouped packed edges -> per-bucket counting sort
  bhist_k<<<BFB, 256, 0, stream>>>(ei, bcnt);
  bscan_k<<<1, 512, 0, stream>>>(bcnt, bcur);
  bfill_k<<<BFB, 256, 0, stream>>>(ei, bcur, epair);
  csort_k<<<NBK, 256, 0, stream>>>(epair, bcnt, bcur, ci, rp);

  // proj: h = relu(x @ proj_w + proj_b)   [K=128, NC=256]
  gemm3_k<4,0,256,0><<<GX, 256, 0, stream>>>(bufA, nullptr, wp_proj, proj_b,
                                             hbuf, NN, nullptr, nullptr, nullptr, nullptr);
  cvt8_k<<<(NN*32 + 255)/256, 256, 0, stream>>>((const uint4*)hbuf, (uint2*)h8, NN*32);

  for (int i = 0; i < 3; ++i){
    if (i < 2)
      agg8_k<<<((NN + 3)/4*64 + 255)/256, 256, 0, stream>>>(rp, ci, (const uint4*)h8, bufA);
    else
      aggb_k<<<(NN + 3)/4, 256, 0, stream>>>(rp, ci, hbuf, bufA);
    // out = agg @ lin_l + b + h @ lin_r   [K=256+256, NC=256] -> bufC
    gemm3_k<8,8,256,1><<<GX, 256, 0, stream>>>(bufA, hbuf, wp_l[i], lin_l_b + (size_t)i*256,
                                               bufC, NN, bnacc + i*8192, nullptr, nullptr, nullptr);
    bnfin_k<<<1, 256, 0, stream>>>(bnacc + i*8192, bn_g + (size_t)i*256, bn_b + (size_t)i*256, coef + i*512);
    // h8 only needed for layer i+1's fp8 gather; layer 2 fuses the f32 embeddings write
    bnapply_k<<<(NN*32 + 255)/256, 256, 0, stream>>>((const uint4*)bufC, (uint4*)hbuf, (uint2*)h8,
                                                     coef + i*512, i, (i == 0) ? 1 : 0,
                                                     (i == 2) ? (out + 200000) : nullptr);
  }

  // fc1 + fused fc2: logits = relu(h @ fc1_w + fc1_b) @ fc2_w + fc2_b
  gemm3_k<8,0,128,2><<<GX, 256, 0, stream>>>(hbuf, nullptr, wp_fc1, fc1_b,
                                             nullptr, NN, nullptr, fc2_w, fc2_b, out);
}